// Round 11
// baseline (2300.603 us; speedup 1.0000x reference)
//
#include <hip/hip_runtime.h>
#include <stdint.h>

#define NN    200000   // nodes
#define NE    100000   // edges
#define HD    128      // hidden/memory/time dim
#define EFD   64       // edge feat dim
#define NG    384      // 3*HD gates

typedef unsigned long long u64;

// ---- ws layout (bytes) ----
#define OFF_KEY   ((size_t)0)            // u64 * NN = 1,600,000
#define OFF_CNT   ((size_t)1600000)      // int
#define OFF_LIST  ((size_t)1600256)      // int * NN = 800,000
#define OFF_UV    ((size_t)2400256)      // float * NN*128 = 102,400,000
#define OFF_HN    ((size_t)104800256)    // float * NE*32 = 12,800,000
#define OFF_A     ((size_t)117600256)    // float * 2048
#define OFF_B     ((size_t)117608448)    // float * 2048
#define OFF_C0    ((size_t)117616640)    // float * 64 (+pad)
#define WS_NEED   ((size_t)117616896)

__device__ __forceinline__ float frcp(float x){ return __builtin_amdgcn_rcpf(x); }
__device__ __forceinline__ float sigf(float x){ return frcp(1.f + __expf(-x)); }
__device__ __forceinline__ float tanhf_(float x){ return 1.f - 2.f*frcp(__expf(2.f*x) + 1.f); }
__device__ __forceinline__ float4 ld4(const float* p){ return *reinterpret_cast<const float4*>(p); }

// async global->LDS, 16B per lane; LDS dest = (first lane's ptr) + lane*16.
__device__ __forceinline__ void gl16(const float* g, float* l) {
  __builtin_amdgcn_global_load_lds(
      (const __attribute__((address_space(1))) void*)g,
      (__attribute__((address_space(3))) void*)l, 16, 0, 0);
}

// ---------- per-node winner key: max (t, isDst, e) ----------
__global__ void k_scatter(const int* __restrict__ src, const int* __restrict__ dst,
                          const int* __restrict__ t, u64* __restrict__ key) {
  int e = blockIdx.x*256 + threadIdx.x;
  if (e >= NE) return;
  u64 tt = (u64)(unsigned)(t[e] + 1);
  atomicMax(&key[src[e]], (tt<<18) | (u64)(unsigned)e);
  atomicMax(&key[dst[e]], (tt<<18) | (1ULL<<17) | (u64)(unsigned)e);
}

__global__ void k_compact(const u64* __restrict__ key, int* __restrict__ list,
                          int* __restrict__ count) {
  int n = blockIdx.x*256 + threadIdx.x;
  if (n >= NN) return;
  if (key[n] != 0ULL) { int p = atomicAdd(count, 1); list[p] = n; }
}

// ---------- fold W1/W_sp/W_pp/biases: A=W1a@W_sp, B=(W1b+W1c)@W_pp, c0 ----------
__global__ void k_pre(const float* __restrict__ W1, const float* __restrict__ W_sp,
                      const float* __restrict__ W_pp, const float* __restrict__ b_sp,
                      const float* __restrict__ b_pp, const float* __restrict__ b1,
                      float* __restrict__ A, float* __restrict__ B, float* __restrict__ c0)
{
  int tid = blockIdx.x*256 + threadIdx.x;
  if (tid < 2048) {
    int o = tid >> 5, j = tid & 31;
    float s = 0.f;
    for (int k = 0; k < 128; ++k) s = fmaf(W1[o*NG + k], W_sp[k*32 + j], s);
    A[tid] = s;
  } else if (tid < 4096) {
    int q = tid - 2048;
    int o = q >> 5, j = q & 31;
    float s = 0.f;
    for (int k = 0; k < 128; ++k)
      s = fmaf(W1[o*NG + 128 + k] + W1[o*NG + 256 + k], W_pp[k*32 + j], s);
    B[q] = s;
  } else if (tid < 4160) {
    int o = tid - 4096;
    float s = b1[o];
    for (int k = 0; k < 128; ++k) {
      s = fmaf(W1[o*NG + k], b_sp[k], s);
      s = fmaf(W1[o*NG + 128 + k] + W1[o*NG + 256 + k], b_pp[k], s);
    }
    c0[o] = s;
  }
}

// ---------- GRU: 64 nodes/block, 1024 thr, 2 nodes/thread ----------
// r10 crash fix: uv-epilogue W1 staging covers exactly 1024 quads (idx = tid),
// not 2048 (previous version read W1 OOB and clobbered the Mn overlay).
__global__ __launch_bounds__(1024, 1) void k_gru(
    const u64* __restrict__ key, const int* __restrict__ list, const int* __restrict__ count,
    const int* __restrict__ src, const int* __restrict__ dst, const int* __restrict__ t,
    const float* __restrict__ msg, const float* __restrict__ memory,
    const float* __restrict__ last_update,
    const float* __restrict__ w_t, const float* __restrict__ b_t,
    const float* __restrict__ W_ih, const float* __restrict__ b_ih,
    const float* __restrict__ W_hh, const float* __restrict__ b_hh,
    const float* __restrict__ W1, float* __restrict__ uv)
{
  __shared__ float Ws[12288];          // [384 g][32 k], XOR-swizzled quads (48KB)
  __shared__ float Xs[2048];           // [64 node][32 k] chunk (8KB)
  __shared__ int   sn_self[64];
  __shared__ int   sn_other[64];
  __shared__ int   sn_e[64];
  __shared__ float sn_dt[64];

  int cnt = count[0];
  int base = blockIdx.x * 64;
  if (base >= cnt) return;
  int tid = threadIdx.x;
  int tx = tid & 31, ty = tid >> 5;    // ty 0..31

  if (tid < 64) {
    int idx = base + tid;
    int cl = idx < cnt ? idx : (cnt - 1);
    int n = list[cl];
    u64 k = key[n];
    int e   = (int)(k & 0x1FFFFULL);
    int isd = (int)((k >> 17) & 1ULL);
    sn_self[tid]  = n;
    sn_other[tid] = isd ? src[e] : dst[e];
    sn_e[tid]     = e;
    sn_dt[tid]    = (float)t[e] - last_update[n];
  }
  __syncthreads();

  float acc[2][12];
  float accN[2][4];
  #pragma unroll
  for (int a=0;a<2;++a){
    #pragma unroll
    for (int b=0;b<12;++b) acc[a][b]=0.f;
    #pragma unroll
    for (int b=0;b<4;++b) accN[a][b]=0.f;
  }

  for (int ch = 0; ch < 18; ++ch) {
    // W chunk: 3072 quads via global_load_lds (3 calls x 1024 lanes), zero data regs.
    #pragma unroll
    for (int i = 0; i < 3; ++i) {
      int q = i*1024 + tid;
      int g = q >> 3;
      int k4 = (q & 7) ^ (g & 7);
      int k = ch*32 + k4*4;
      const float* srcp = (k < 448) ? (W_ih + (size_t)g*448 + k)
                                    : (W_hh + (size_t)g*HD + (k-448));
      gl16(srcp, &Ws[q*4]);
    }
    // X chunk: 64 nodes x 32 k = 512 float4; threads 0..511 take 1 each
    if (tid < 512) {
      int nodeL = tid >> 3, k4 = tid & 7;
      int k = ch*32 + k4*4;
      int self = sn_self[nodeL], other = sn_other[nodeL], e = sn_e[nodeL];
      float4 vx;
      if (k < 128)      vx = ld4(memory + (size_t)self*HD + k);
      else if (k < 256) vx = ld4(memory + (size_t)other*HD + (k-128));
      else if (k < 320) vx = ld4(msg + (size_t)e*EFD + (k-256));
      else if (k < 448) {
        int kk = k - 320; float dt = sn_dt[nodeL];
        vx.x = cosf(fmaf(dt, w_t[kk],   b_t[kk]));
        vx.y = cosf(fmaf(dt, w_t[kk+1], b_t[kk+1]));
        vx.z = cosf(fmaf(dt, w_t[kk+2], b_t[kk+2]));
        vx.w = cosf(fmaf(dt, w_t[kk+3], b_t[kk+3]));
      } else            vx = ld4(memory + (size_t)self*HD + (k-448));
      *reinterpret_cast<float4*>(&Xs[nodeL*32 + k4*4]) = vx;
    }
    __syncthreads();   // drains vmcnt (global_load_lds) + lgkm

    if (ch < 14) {
      // ---- static path A: all 12 gate-groups -> acc; gg in two 6-quad halves ----
      #pragma unroll
      for (int k4 = 0; k4 < 8; ++k4) {
        float4 xv[2];
        #pragma unroll
        for (int nn = 0; nn < 2; ++nn)
          xv[nn] = *reinterpret_cast<const float4*>(&Xs[(ty + 32*nn)*32 + k4*4]);
        #pragma unroll
        for (int half = 0; half < 2; ++half) {
          #pragma unroll
          for (int g6 = 0; g6 < 6; ++g6) {
            int gg = half*6 + g6;
            int g = tx + 32*gg;
            float4 w = *reinterpret_cast<const float4*>(&Ws[g*32 + ((k4 ^ (g&7))<<2)]);
            #pragma unroll
            for (int nn = 0; nn < 2; ++nn) {
              acc[nn][gg] = fmaf(w.x, xv[nn].x, acc[nn][gg]);
              acc[nn][gg] = fmaf(w.y, xv[nn].y, acc[nn][gg]);
              acc[nn][gg] = fmaf(w.z, xv[nn].z, acc[nn][gg]);
              acc[nn][gg] = fmaf(w.w, xv[nn].w, acc[nn][gg]);
            }
          }
        }
      }
    } else {
      // ---- static path B: gg 0..7 -> acc (two 4-quad halves), gg 8..11 -> accN ----
      #pragma unroll
      for (int k4 = 0; k4 < 8; ++k4) {
        float4 xv[2];
        #pragma unroll
        for (int nn = 0; nn < 2; ++nn)
          xv[nn] = *reinterpret_cast<const float4*>(&Xs[(ty + 32*nn)*32 + k4*4]);
        #pragma unroll
        for (int half = 0; half < 2; ++half) {
          #pragma unroll
          for (int g4 = 0; g4 < 4; ++g4) {
            int gg = half*4 + g4;
            int g = tx + 32*gg;
            float4 w = *reinterpret_cast<const float4*>(&Ws[g*32 + ((k4 ^ (g&7))<<2)]);
            #pragma unroll
            for (int nn = 0; nn < 2; ++nn) {
              acc[nn][gg] = fmaf(w.x, xv[nn].x, acc[nn][gg]);
              acc[nn][gg] = fmaf(w.y, xv[nn].y, acc[nn][gg]);
              acc[nn][gg] = fmaf(w.z, xv[nn].z, acc[nn][gg]);
              acc[nn][gg] = fmaf(w.w, xv[nn].w, acc[nn][gg]);
            }
          }
        }
        #pragma unroll
        for (int gg = 8; gg < 12; ++gg) {
          int g = tx + 32*gg;
          float4 w = *reinterpret_cast<const float4*>(&Ws[g*32 + ((k4 ^ (g&7))<<2)]);
          #pragma unroll
          for (int nn = 0; nn < 2; ++nn) {
            accN[nn][gg-8] = fmaf(w.x, xv[nn].x, accN[nn][gg-8]);
            accN[nn][gg-8] = fmaf(w.y, xv[nn].y, accN[nn][gg-8]);
            accN[nn][gg-8] = fmaf(w.z, xv[nn].z, accN[nn][gg-8]);
            accN[nn][gg-8] = fmaf(w.w, xv[nn].w, accN[nn][gg-8]);
          }
        }
      }
    }
    __syncthreads();
  }

  // epilogue: GRU gates -> mem_new tile in LDS (overlay Ws[4096..12288))
  float* Mn = &Ws[4096];   // [64][128]
  #pragma unroll
  for (int nn = 0; nn < 2; ++nn) {
    int nl = ty + 32*nn;
    int self = sn_self[nl];
    #pragma unroll
    for (int hh = 0; hh < 4; ++hh) {
      int h = tx + 32*hh;
      float r  = sigf(acc[nn][hh]     + b_ih[h]       + b_hh[h]);
      float z  = sigf(acc[nn][4+hh]   + b_ih[128+h]   + b_hh[128+h]);
      float nv = tanhf_(acc[nn][8+hh] + b_ih[256+h] + r*(accN[nn][hh] + b_hh[256+h]));
      float m  = memory[(size_t)self*HD + h];
      Mn[nl*128 + h] = (1.f - z)*nv + z*m;
    }
  }
  __syncthreads();

  // uv = [W1a@mn | W1b@mn] : K=128 chunked by 32; W1 tile = [128 o][8 k4] = 1024
  // quads exactly -> one quad per thread (idx = tid), staged at Ws[0..4096).
  float acc2[2][4];
  #pragma unroll
  for (int a=0;a<2;++a){
    #pragma unroll
    for (int b=0;b<4;++b) acc2[a][b]=0.f;
  }
  for (int ch = 0; ch < 4; ++ch) {
    {
      int o = tid >> 3, k4 = tid & 7;      // o 0..127, exactly 1024 quads
      int k = ch*32 + k4*4;
      float4 w = (o < 64) ? ld4(W1 + (size_t)o*NG + k)
                          : ld4(W1 + (size_t)(o-64)*NG + 128 + k);
      *reinterpret_cast<float4*>(&Ws[o*32 + ((k4 ^ (o&7))<<2)]) = w;
    }
    __syncthreads();
    #pragma unroll
    for (int k4 = 0; k4 < 8; ++k4) {
      float4 xv[2];
      #pragma unroll
      for (int nn = 0; nn < 2; ++nn)
        xv[nn] = *reinterpret_cast<const float4*>(&Mn[(ty+32*nn)*128 + ch*32 + k4*4]);
      #pragma unroll
      for (int og = 0; og < 4; ++og) {
        int o = tx + 32*og;
        float4 w = *reinterpret_cast<const float4*>(&Ws[o*32 + ((k4 ^ (o&7))<<2)]);
        #pragma unroll
        for (int nn = 0; nn < 2; ++nn) {
          acc2[nn][og] = fmaf(w.x, xv[nn].x, acc2[nn][og]);
          acc2[nn][og] = fmaf(w.y, xv[nn].y, acc2[nn][og]);
          acc2[nn][og] = fmaf(w.z, xv[nn].z, acc2[nn][og]);
          acc2[nn][og] = fmaf(w.w, xv[nn].w, acc2[nn][og]);
        }
      }
    }
    __syncthreads();
  }
  #pragma unroll
  for (int nn = 0; nn < 2; ++nn) {
    int nl = ty + 32*nn;
    if (base + nl < cnt) {
      int self = sn_self[nl];
      #pragma unroll
      for (int og = 0; og < 4; ++og)
        uv[(size_t)self*128 + tx + 32*og] = acc2[nn][og];
    }
  }
}

// ---------- price LSTM: thread (g,j) owns hidden unit j of edge g ----------
__global__ __launch_bounds__(256) void k_lstm(
    const float* __restrict__ price, const float* __restrict__ W_ihl,
    const float* __restrict__ W_hhl, const float* __restrict__ b_ihl,
    const float* __restrict__ b_hhl, float* __restrict__ hn_out)
{
  __shared__ float Wsh[4096];     // W_hh row-major [128][32] = 16KB
  __shared__ float ps[8][52];     // price rows (pad to 52)
  __shared__ float hrow[8][36];   // h per edge (stride 36)
  int tid = threadIdx.x;
  int g = tid >> 5;               // edge slot 0..7
  int j = tid & 31;               // hidden unit

  for (int i = tid; i < 1024; i += 256)
    *reinterpret_cast<float4*>(&Wsh[i*4]) = ld4(W_hhl + i*4);
  {
    int ebase = blockIdx.x*8;
    int m = NE - ebase; if (m > 8) m = 8;
    const float* pb = price + (size_t)ebase*50;
    for (int i = tid; i < m*50; i += 256) ps[i/50][i%50] = pb[i];
  }
  __syncthreads();

  float wi[32], wf[32], wg[32], wo[32];
  #pragma unroll
  for (int k = 0; k < 32; ++k) {
    wi[k] = Wsh[j*32 + k];
    wf[k] = Wsh[(32+j)*32 + k];
    wg[k] = Wsh[(64+j)*32 + k];
    wo[k] = Wsh[(96+j)*32 + k];
  }
  float wxi = W_ihl[j],    wxf = W_ihl[32+j], wxg = W_ihl[64+j], wxo = W_ihl[96+j];
  float bi  = b_ihl[j]    + b_hhl[j];
  float bf  = b_ihl[32+j] + b_hhl[32+j];
  float bg  = b_ihl[64+j] + b_hhl[64+j];
  float bo  = b_ihl[96+j] + b_hhl[96+j];

  float c = 0.f, hlast = 0.f;
  hrow[g][j] = 0.f;
  __syncthreads();

  #pragma unroll 1
  for (int s = 0; s < 50; ++s) {
    float x = ps[g][s];
    float ai = fmaf(x, wxi, bi);
    float af = fmaf(x, wxf, bf);
    float ag = fmaf(x, wxg, bg);
    float ao = fmaf(x, wxo, bo);
    #pragma unroll
    for (int k4 = 0; k4 < 8; ++k4) {
      float4 hv = *reinterpret_cast<const float4*>(&hrow[g][k4*4]);
      int b = k4*4;
      ai = fmaf(wi[b],hv.x, fmaf(wi[b+1],hv.y, fmaf(wi[b+2],hv.z, fmaf(wi[b+3],hv.w, ai))));
      af = fmaf(wf[b],hv.x, fmaf(wf[b+1],hv.y, fmaf(wf[b+2],hv.z, fmaf(wf[b+3],hv.w, af))));
      ag = fmaf(wg[b],hv.x, fmaf(wg[b+1],hv.y, fmaf(wg[b+2],hv.z, fmaf(wg[b+3],hv.w, ag))));
      ao = fmaf(wo[b],hv.x, fmaf(wo[b+1],hv.y, fmaf(wo[b+2],hv.z, fmaf(wo[b+3],hv.w, ao))));
    }
    float ig = sigf(ai), fg = sigf(af), gv = tanhf_(ag), og = sigf(ao);
    c = fmaf(fg, c, ig*gv);
    hlast = og * tanhf_(c);
    hrow[g][j] = hlast;
  }

  int e = blockIdx.x*8 + g;
  if (e < NE) hn_out[(size_t)e*32 + j] = hlast;
}

// ---------- fused output: out = W2 @ relu(u[s] + v[d] + A@sf + B@hn + c0) + b2 ----------
__global__ __launch_bounds__(256) void k_final(
    const int* __restrict__ src, const int* __restrict__ dst, const int* __restrict__ xst,
    const float* __restrict__ party, const float* __restrict__ state,
    const float* __restrict__ uv, const float* __restrict__ hn,
    const float* __restrict__ A, const float* __restrict__ B, const float* __restrict__ c0,
    const float* __restrict__ W2, const float* __restrict__ b2, float* __restrict__ out)
{
  __shared__ float As[2048], Bs[2048], c0s[64], W2s[64];
  int tid = threadIdx.x;
  for (int i = tid; i < 2048; i += 256) { As[i] = A[i]; Bs[i] = B[i]; }
  if (tid < 64) { c0s[tid] = c0[tid]; W2s[tid] = W2[tid]; }
  __syncthreads();
  int e = blockIdx.x*256 + tid;
  if (e >= NE) return;
  int s = src[e], d = dst[e];
  int p = xst[2*s], stt = xst[2*s + 1];
  float4 sf4[8], hv4[8];
  #pragma unroll
  for (int i = 0; i < 4; ++i) sf4[i]   = ld4(party + p*16 + i*4);
  #pragma unroll
  for (int i = 0; i < 4; ++i) sf4[4+i] = ld4(state + stt*16 + i*4);
  #pragma unroll
  for (int i = 0; i < 8; ++i) hv4[i] = ld4(hn + (size_t)e*32 + i*4);
  const float* urow = uv + (size_t)s*128;
  const float* vrow = uv + (size_t)d*128 + 64;
  float oacc = b2[0];
  #pragma unroll 4
  for (int o4 = 0; o4 < 16; ++o4) {
    float4 u4 = ld4(urow + o4*4);
    float4 v4 = ld4(vrow + o4*4);
    float4 cc = *reinterpret_cast<const float4*>(&c0s[o4*4]);
    float4 w2 = *reinterpret_cast<const float4*>(&W2s[o4*4]);
    float hh[4] = {u4.x+v4.x+cc.x, u4.y+v4.y+cc.y, u4.z+v4.z+cc.z, u4.w+v4.w+cc.w};
    #pragma unroll
    for (int oo = 0; oo < 4; ++oo) {
      int o = o4*4 + oo;
      float acc = hh[oo];
      #pragma unroll
      for (int j4 = 0; j4 < 8; ++j4) {
        float4 a = *reinterpret_cast<const float4*>(&As[o*32 + j4*4]);
        float4 b = *reinterpret_cast<const float4*>(&Bs[o*32 + j4*4]);
        float4 sfv = sf4[j4], hvv = hv4[j4];
        acc = fmaf(a.x,sfv.x, fmaf(a.y,sfv.y, fmaf(a.z,sfv.z, fmaf(a.w,sfv.w, acc))));
        acc = fmaf(b.x,hvv.x, fmaf(b.y,hvv.y, fmaf(b.z,hvv.z, fmaf(b.w,hvv.w, acc))));
      }
      float w2v = (oo==0) ? w2.x : (oo==1) ? w2.y : (oo==2) ? w2.z : w2.w;
      oacc = fmaf(w2v, fmaxf(acc, 0.f), oacc);
    }
  }
  out[e] = oacc;
}

extern "C" void kernel_launch(void* const* d_in, const int* in_sizes, int n_in,
                              void* d_out, int out_size, void* d_ws, size_t ws_size,
                              hipStream_t stream) {
  const int*   src   = (const int*)d_in[0];
  const int*   dst   = (const int*)d_in[1];
  const int*   t     = (const int*)d_in[2];
  const float* msg   = (const float*)d_in[3];
  const float* price = (const float*)d_in[4];
  // d_in[5] trade_t: unused by reference
  const int*   xst   = (const int*)d_in[6];
  const float* memory= (const float*)d_in[7];
  const float* lu    = (const float*)d_in[8];
  const float* w_t   = (const float*)d_in[9];
  const float* b_t   = (const float*)d_in[10];
  const float* W_ih  = (const float*)d_in[11];
  const float* b_ih  = (const float*)d_in[12];
  const float* W_hh  = (const float*)d_in[13];
  const float* b_hh  = (const float*)d_in[14];
  const float* party = (const float*)d_in[15];
  const float* state = (const float*)d_in[16];
  const float* W_sp  = (const float*)d_in[17];
  const float* b_sp  = (const float*)d_in[18];
  const float* W_ihl = (const float*)d_in[19];
  const float* W_hhl = (const float*)d_in[20];
  const float* b_ihl = (const float*)d_in[21];
  const float* b_hhl = (const float*)d_in[22];
  const float* W_pp  = (const float*)d_in[23];
  const float* b_pp  = (const float*)d_in[24];
  const float* W1    = (const float*)d_in[25];
  const float* b1    = (const float*)d_in[26];
  const float* W2    = (const float*)d_in[27];
  const float* b2    = (const float*)d_in[28];
  float* out = (float*)d_out;

  if (ws_size < WS_NEED) {              // loud failure: zero output
    (void)hipMemsetAsync(d_out, 0, (size_t)out_size*4, stream);
    return;
  }

  char* ws = (char*)d_ws;
  u64*   key  = (u64*)(ws + OFF_KEY);
  int*   cnt  = (int*)(ws + OFF_CNT);
  int*   list = (int*)(ws + OFF_LIST);
  float* uv   = (float*)(ws + OFF_UV);
  float* hn   = (float*)(ws + OFF_HN);
  float* A    = (float*)(ws + OFF_A);
  float* B    = (float*)(ws + OFF_B);
  float* c0   = (float*)(ws + OFF_C0);

  (void)hipMemsetAsync(ws, 0, OFF_LIST, stream);   // zero key[] + count
  k_scatter<<<(NE+255)/256, 256, 0, stream>>>(src, dst, t, key);
  k_compact<<<(NN+255)/256, 256, 0, stream>>>(key, list, cnt);
  k_pre<<<17, 256, 0, stream>>>(W1, W_sp, W_pp, b_sp, b_pp, b1, A, B, c0);
  k_lstm<<<(NE+7)/8, 256, 0, stream>>>(price, W_ihl, W_hhl, b_ihl, b_hhl, hn);
  k_gru<<<(NN+63)/64, 1024, 0, stream>>>(key, list, cnt, src, dst, t, msg, memory, lu,
                                         w_t, b_t, W_ih, b_ih, W_hh, b_hh, W1, uv);
  k_final<<<(NE+255)/256, 256, 0, stream>>>(src, dst, xst, party, state, uv, hn,
                                            A, B, c0, W2, b2, out);
}

// Round 12
// 1962.975 us; speedup vs baseline: 1.1720x; 1.1720x over previous
//
#include <hip/hip_runtime.h>
#include <stdint.h>

#define NN    200000   // nodes
#define NE    100000   // edges
#define HD    128      // hidden/memory/time dim
#define EFD   64       // edge feat dim
#define NG    384      // 3*HD gates

typedef unsigned long long u64;

// ---- ws layout (bytes) ----
#define OFF_KEY   ((size_t)0)            // u64 * NN = 1,600,000
#define OFF_CNT   ((size_t)1600000)      // int
#define OFF_LIST  ((size_t)1600256)      // int * NN = 800,000
#define OFF_UV    ((size_t)2400256)      // float * NN*128 = 102,400,000
#define OFF_HN    ((size_t)104800256)    // float * NE*32 = 12,800,000
#define OFF_A     ((size_t)117600256)    // float * 2048
#define OFF_B     ((size_t)117608448)    // float * 2048
#define OFF_C0    ((size_t)117616640)    // float * 64 (+pad)
#define WS_NEED   ((size_t)117616896)

__device__ __forceinline__ float frcp(float x){ return __builtin_amdgcn_rcpf(x); }
__device__ __forceinline__ float sigf(float x){ return frcp(1.f + __expf(-x)); }
__device__ __forceinline__ float tanhf_(float x){ return 1.f - 2.f*frcp(__expf(2.f*x) + 1.f); }
__device__ __forceinline__ float4 ld4(const float* p){ return *reinterpret_cast<const float4*>(p); }

// async global->LDS, 16B per lane; LDS dest = (first lane's ptr) + lane*16.
__device__ __forceinline__ void gl16(const float* g, float* l) {
  __builtin_amdgcn_global_load_lds(
      (const __attribute__((address_space(1))) void*)g,
      (__attribute__((address_space(3))) void*)l, 16, 0, 0);
}

// ---------- per-node winner key: max (t, isDst, e) ----------
__global__ void k_scatter(const int* __restrict__ src, const int* __restrict__ dst,
                          const int* __restrict__ t, u64* __restrict__ key) {
  int e = blockIdx.x*256 + threadIdx.x;
  if (e >= NE) return;
  u64 tt = (u64)(unsigned)(t[e] + 1);
  atomicMax(&key[src[e]], (tt<<18) | (u64)(unsigned)e);
  atomicMax(&key[dst[e]], (tt<<18) | (1ULL<<17) | (u64)(unsigned)e);
}

__global__ void k_compact(const u64* __restrict__ key, int* __restrict__ list,
                          int* __restrict__ count) {
  int n = blockIdx.x*256 + threadIdx.x;
  if (n >= NN) return;
  if (key[n] != 0ULL) { int p = atomicAdd(count, 1); list[p] = n; }
}

// ---------- fold W1/W_sp/W_pp/biases: A=W1a@W_sp, B=(W1b+W1c)@W_pp, c0 ----------
__global__ void k_pre(const float* __restrict__ W1, const float* __restrict__ W_sp,
                      const float* __restrict__ W_pp, const float* __restrict__ b_sp,
                      const float* __restrict__ b_pp, const float* __restrict__ b1,
                      float* __restrict__ A, float* __restrict__ B, float* __restrict__ c0)
{
  int tid = blockIdx.x*256 + threadIdx.x;
  if (tid < 2048) {
    int o = tid >> 5, j = tid & 31;
    float s = 0.f;
    for (int k = 0; k < 128; ++k) s = fmaf(W1[o*NG + k], W_sp[k*32 + j], s);
    A[tid] = s;
  } else if (tid < 4096) {
    int q = tid - 2048;
    int o = q >> 5, j = q & 31;
    float s = 0.f;
    for (int k = 0; k < 128; ++k)
      s = fmaf(W1[o*NG + 128 + k] + W1[o*NG + 256 + k], W_pp[k*32 + j], s);
    B[q] = s;
  } else if (tid < 4160) {
    int o = tid - 4096;
    float s = b1[o];
    for (int k = 0; k < 128; ++k) {
      s = fmaf(W1[o*NG + k], b_sp[k], s);
      s = fmaf(W1[o*NG + 128 + k] + W1[o*NG + 256 + k], b_pp[k], s);
    }
    c0[o] = s;
  }
}

// ---------- GRU: 64 nodes/block, 512 thr, 4 nodes/thread (R9 geometry) ----------
// R12: R9 + gg-loop split into 6-quad halves -> concurrent Ws temporaries drop from
// 48 to 24 VGPRs, giving R9's marginal spill (~480MB scratch writes) the headroom
// it lacked. Geometry unchanged: (512,2) is the only config yielding 128 VGPRs.
__global__ __launch_bounds__(512, 2) void k_gru(
    const u64* __restrict__ key, const int* __restrict__ list, const int* __restrict__ count,
    const int* __restrict__ src, const int* __restrict__ dst, const int* __restrict__ t,
    const float* __restrict__ msg, const float* __restrict__ memory,
    const float* __restrict__ last_update,
    const float* __restrict__ w_t, const float* __restrict__ b_t,
    const float* __restrict__ W_ih, const float* __restrict__ b_ih,
    const float* __restrict__ W_hh, const float* __restrict__ b_hh,
    const float* __restrict__ W1, float* __restrict__ uv)
{
  __shared__ float Ws[12288];          // [384 g][32 k], XOR-swizzled quads (48KB)
  __shared__ float Xs[2048];           // [64 node][32 k] chunk (8KB)
  __shared__ int   sn_self[64];
  __shared__ int   sn_other[64];
  __shared__ int   sn_e[64];
  __shared__ float sn_dt[64];

  int cnt = count[0];
  int base = blockIdx.x * 64;
  if (base >= cnt) return;
  int tid = threadIdx.x;
  int tx = tid & 31, ty = tid >> 5;    // ty 0..15

  if (tid < 64) {
    int idx = base + tid;
    int cl = idx < cnt ? idx : (cnt - 1);
    int n = list[cl];
    u64 k = key[n];
    int e   = (int)(k & 0x1FFFFULL);
    int isd = (int)((k >> 17) & 1ULL);
    sn_self[tid]  = n;
    sn_other[tid] = isd ? src[e] : dst[e];
    sn_e[tid]     = e;
    sn_dt[tid]    = (float)t[e] - last_update[n];
  }
  __syncthreads();

  float acc[4][12];
  float accN[4][4];
  #pragma unroll
  for (int a=0;a<4;++a){
    #pragma unroll
    for (int b=0;b<12;++b) acc[a][b]=0.f;
    #pragma unroll
    for (int b=0;b<4;++b) accN[a][b]=0.f;
  }

  for (int ch = 0; ch < 18; ++ch) {
    // W chunk: 3072 quads via global_load_lds (6 calls x 512 lanes), zero data regs.
    #pragma unroll
    for (int i = 0; i < 6; ++i) {
      int q = i*512 + tid;
      int g = q >> 3;
      int k4 = (q & 7) ^ (g & 7);
      int k = ch*32 + k4*4;
      const float* srcp = (k < 448) ? (W_ih + (size_t)g*448 + k)
                                    : (W_hh + (size_t)g*HD + (k-448));
      gl16(srcp, &Ws[q*4]);
    }
    // X chunk: 64 nodes x 32 k = 512 float4, 1 per thread
    {
      int nodeL = tid >> 3, k4 = tid & 7;
      int k = ch*32 + k4*4;
      int self = sn_self[nodeL], other = sn_other[nodeL], e = sn_e[nodeL];
      float4 vx;
      if (k < 128)      vx = ld4(memory + (size_t)self*HD + k);
      else if (k < 256) vx = ld4(memory + (size_t)other*HD + (k-128));
      else if (k < 320) vx = ld4(msg + (size_t)e*EFD + (k-256));
      else if (k < 448) {
        int kk = k - 320; float dt = sn_dt[nodeL];
        vx.x = cosf(fmaf(dt, w_t[kk],   b_t[kk]));
        vx.y = cosf(fmaf(dt, w_t[kk+1], b_t[kk+1]));
        vx.z = cosf(fmaf(dt, w_t[kk+2], b_t[kk+2]));
        vx.w = cosf(fmaf(dt, w_t[kk+3], b_t[kk+3]));
      } else            vx = ld4(memory + (size_t)self*HD + (k-448));
      *reinterpret_cast<float4*>(&Xs[nodeL*32 + k4*4]) = vx;
    }
    __syncthreads();   // drains vmcnt (global_load_lds) + lgkm

    if (ch < 14) {
      // ---- static path A: all 12 gate-groups -> acc; gg in two 6-quad halves ----
      #pragma unroll
      for (int k4 = 0; k4 < 8; ++k4) {
        float4 xv[4];
        #pragma unroll
        for (int nn = 0; nn < 4; ++nn)
          xv[nn] = *reinterpret_cast<const float4*>(&Xs[(ty + 16*nn)*32 + k4*4]);
        #pragma unroll
        for (int half = 0; half < 2; ++half) {
          #pragma unroll
          for (int g6 = 0; g6 < 6; ++g6) {
            int gg = half*6 + g6;
            int g = tx + 32*gg;
            float4 w = *reinterpret_cast<const float4*>(&Ws[g*32 + ((k4 ^ (g&7))<<2)]);
            #pragma unroll
            for (int nn = 0; nn < 4; ++nn) {
              acc[nn][gg] = fmaf(w.x, xv[nn].x, acc[nn][gg]);
              acc[nn][gg] = fmaf(w.y, xv[nn].y, acc[nn][gg]);
              acc[nn][gg] = fmaf(w.z, xv[nn].z, acc[nn][gg]);
              acc[nn][gg] = fmaf(w.w, xv[nn].w, acc[nn][gg]);
            }
          }
        }
      }
    } else {
      // ---- static path B: gg 0..7 -> acc (two 4-quad halves), gg 8..11 -> accN ----
      #pragma unroll
      for (int k4 = 0; k4 < 8; ++k4) {
        float4 xv[4];
        #pragma unroll
        for (int nn = 0; nn < 4; ++nn)
          xv[nn] = *reinterpret_cast<const float4*>(&Xs[(ty + 16*nn)*32 + k4*4]);
        #pragma unroll
        for (int half = 0; half < 2; ++half) {
          #pragma unroll
          for (int g4 = 0; g4 < 4; ++g4) {
            int gg = half*4 + g4;
            int g = tx + 32*gg;
            float4 w = *reinterpret_cast<const float4*>(&Ws[g*32 + ((k4 ^ (g&7))<<2)]);
            #pragma unroll
            for (int nn = 0; nn < 4; ++nn) {
              acc[nn][gg] = fmaf(w.x, xv[nn].x, acc[nn][gg]);
              acc[nn][gg] = fmaf(w.y, xv[nn].y, acc[nn][gg]);
              acc[nn][gg] = fmaf(w.z, xv[nn].z, acc[nn][gg]);
              acc[nn][gg] = fmaf(w.w, xv[nn].w, acc[nn][gg]);
            }
          }
        }
        #pragma unroll
        for (int gg = 8; gg < 12; ++gg) {
          int g = tx + 32*gg;
          float4 w = *reinterpret_cast<const float4*>(&Ws[g*32 + ((k4 ^ (g&7))<<2)]);
          #pragma unroll
          for (int nn = 0; nn < 4; ++nn) {
            accN[nn][gg-8] = fmaf(w.x, xv[nn].x, accN[nn][gg-8]);
            accN[nn][gg-8] = fmaf(w.y, xv[nn].y, accN[nn][gg-8]);
            accN[nn][gg-8] = fmaf(w.z, xv[nn].z, accN[nn][gg-8]);
            accN[nn][gg-8] = fmaf(w.w, xv[nn].w, accN[nn][gg-8]);
          }
        }
      }
    }
    __syncthreads();
  }

  // epilogue: GRU gates -> mem_new tile in LDS (overlay Ws[4096..12288))
  float* Mn = &Ws[4096];   // [64][128]
  #pragma unroll
  for (int nn = 0; nn < 4; ++nn) {
    int nl = ty + 16*nn;
    int self = sn_self[nl];
    #pragma unroll
    for (int hh = 0; hh < 4; ++hh) {
      int h = tx + 32*hh;
      float r  = sigf(acc[nn][hh]     + b_ih[h]       + b_hh[h]);
      float z  = sigf(acc[nn][4+hh]   + b_ih[128+h]   + b_hh[128+h]);
      float nv = tanhf_(acc[nn][8+hh] + b_ih[256+h] + r*(accN[nn][hh] + b_hh[256+h]));
      float m  = memory[(size_t)self*HD + h];
      Mn[nl*128 + h] = (1.f - z)*nv + z*m;
    }
  }
  __syncthreads();

  // uv = [W1a@mn | W1b@mn] : K=128 chunked by 32; W1 tile = [128 o][8 k4] = 1024
  // quads -> threads 0..1023? here 512 thr x 2 passes, staged at Ws[0..4096).
  float acc2[4][4];
  #pragma unroll
  for (int a=0;a<4;++a){
    #pragma unroll
    for (int b=0;b<4;++b) acc2[a][b]=0.f;
  }
  for (int ch = 0; ch < 4; ++ch) {
    #pragma unroll
    for (int i = 0; i < 2; ++i) {
      int idx = tid + 512*i;              // 0..1023: exactly the 1024-quad W1 tile
      int o = idx >> 3, k4 = idx & 7;
      int k = ch*32 + k4*4;
      float4 w = (o < 64) ? ld4(W1 + (size_t)o*NG + k)
                          : ld4(W1 + (size_t)(o-64)*NG + 128 + k);
      *reinterpret_cast<float4*>(&Ws[o*32 + ((k4 ^ (o&7))<<2)]) = w;
    }
    __syncthreads();
    #pragma unroll
    for (int k4 = 0; k4 < 8; ++k4) {
      float4 xv[4];
      #pragma unroll
      for (int nn = 0; nn < 4; ++nn)
        xv[nn] = *reinterpret_cast<const float4*>(&Mn[(ty+16*nn)*128 + ch*32 + k4*4]);
      #pragma unroll
      for (int og = 0; og < 4; ++og) {
        int o = tx + 32*og;
        float4 w = *reinterpret_cast<const float4*>(&Ws[o*32 + ((k4 ^ (o&7))<<2)]);
        #pragma unroll
        for (int nn = 0; nn < 4; ++nn) {
          acc2[nn][og] = fmaf(w.x, xv[nn].x, acc2[nn][og]);
          acc2[nn][og] = fmaf(w.y, xv[nn].y, acc2[nn][og]);
          acc2[nn][og] = fmaf(w.z, xv[nn].z, acc2[nn][og]);
          acc2[nn][og] = fmaf(w.w, xv[nn].w, acc2[nn][og]);
        }
      }
    }
    __syncthreads();
  }
  #pragma unroll
  for (int nn = 0; nn < 4; ++nn) {
    int nl = ty + 16*nn;
    if (base + nl < cnt) {
      int self = sn_self[nl];
      #pragma unroll
      for (int og = 0; og < 4; ++og)
        uv[(size_t)self*128 + tx + 32*og] = acc2[nn][og];
    }
  }
}

// ---------- price LSTM: thread (g,j) owns hidden unit j of edge g ----------
__global__ __launch_bounds__(256) void k_lstm(
    const float* __restrict__ price, const float* __restrict__ W_ihl,
    const float* __restrict__ W_hhl, const float* __restrict__ b_ihl,
    const float* __restrict__ b_hhl, float* __restrict__ hn_out)
{
  __shared__ float Wsh[4096];     // W_hh row-major [128][32] = 16KB
  __shared__ float ps[8][52];     // price rows (pad to 52)
  __shared__ float hrow[8][36];   // h per edge (stride 36)
  int tid = threadIdx.x;
  int g = tid >> 5;               // edge slot 0..7
  int j = tid & 31;               // hidden unit

  for (int i = tid; i < 1024; i += 256)
    *reinterpret_cast<float4*>(&Wsh[i*4]) = ld4(W_hhl + i*4);
  {
    int ebase = blockIdx.x*8;
    int m = NE - ebase; if (m > 8) m = 8;
    const float* pb = price + (size_t)ebase*50;
    for (int i = tid; i < m*50; i += 256) ps[i/50][i%50] = pb[i];
  }
  __syncthreads();

  float wi[32], wf[32], wg[32], wo[32];
  #pragma unroll
  for (int k = 0; k < 32; ++k) {
    wi[k] = Wsh[j*32 + k];
    wf[k] = Wsh[(32+j)*32 + k];
    wg[k] = Wsh[(64+j)*32 + k];
    wo[k] = Wsh[(96+j)*32 + k];
  }
  float wxi = W_ihl[j],    wxf = W_ihl[32+j], wxg = W_ihl[64+j], wxo = W_ihl[96+j];
  float bi  = b_ihl[j]    + b_hhl[j];
  float bf  = b_ihl[32+j] + b_hhl[32+j];
  float bg  = b_ihl[64+j] + b_hhl[64+j];
  float bo  = b_ihl[96+j] + b_hhl[96+j];

  float c = 0.f, hlast = 0.f;
  hrow[g][j] = 0.f;
  __syncthreads();

  #pragma unroll 1
  for (int s = 0; s < 50; ++s) {
    float x = ps[g][s];
    float ai = fmaf(x, wxi, bi);
    float af = fmaf(x, wxf, bf);
    float ag = fmaf(x, wxg, bg);
    float ao = fmaf(x, wxo, bo);
    #pragma unroll
    for (int k4 = 0; k4 < 8; ++k4) {
      float4 hv = *reinterpret_cast<const float4*>(&hrow[g][k4*4]);
      int b = k4*4;
      ai = fmaf(wi[b],hv.x, fmaf(wi[b+1],hv.y, fmaf(wi[b+2],hv.z, fmaf(wi[b+3],hv.w, ai))));
      af = fmaf(wf[b],hv.x, fmaf(wf[b+1],hv.y, fmaf(wf[b+2],hv.z, fmaf(wf[b+3],hv.w, af))));
      ag = fmaf(wg[b],hv.x, fmaf(wg[b+1],hv.y, fmaf(wg[b+2],hv.z, fmaf(wg[b+3],hv.w, ag))));
      ao = fmaf(wo[b],hv.x, fmaf(wo[b+1],hv.y, fmaf(wo[b+2],hv.z, fmaf(wo[b+3],hv.w, ao))));
    }
    float ig = sigf(ai), fg = sigf(af), gv = tanhf_(ag), og = sigf(ao);
    c = fmaf(fg, c, ig*gv);
    hlast = og * tanhf_(c);
    hrow[g][j] = hlast;
  }

  int e = blockIdx.x*8 + g;
  if (e < NE) hn_out[(size_t)e*32 + j] = hlast;
}

// ---------- fused output: out = W2 @ relu(u[s] + v[d] + A@sf + B@hn + c0) + b2 ----------
__global__ __launch_bounds__(256) void k_final(
    const int* __restrict__ src, const int* __restrict__ dst, const int* __restrict__ xst,
    const float* __restrict__ party, const float* __restrict__ state,
    const float* __restrict__ uv, const float* __restrict__ hn,
    const float* __restrict__ A, const float* __restrict__ B, const float* __restrict__ c0,
    const float* __restrict__ W2, const float* __restrict__ b2, float* __restrict__ out)
{
  __shared__ float As[2048], Bs[2048], c0s[64], W2s[64];
  int tid = threadIdx.x;
  for (int i = tid; i < 2048; i += 256) { As[i] = A[i]; Bs[i] = B[i]; }
  if (tid < 64) { c0s[tid] = c0[tid]; W2s[tid] = W2[tid]; }
  __syncthreads();
  int e = blockIdx.x*256 + tid;
  if (e >= NE) return;
  int s = src[e], d = dst[e];
  int p = xst[2*s], stt = xst[2*s + 1];
  float4 sf4[8], hv4[8];
  #pragma unroll
  for (int i = 0; i < 4; ++i) sf4[i]   = ld4(party + p*16 + i*4);
  #pragma unroll
  for (int i = 0; i < 4; ++i) sf4[4+i] = ld4(state + stt*16 + i*4);
  #pragma unroll
  for (int i = 0; i < 8; ++i) hv4[i] = ld4(hn + (size_t)e*32 + i*4);
  const float* urow = uv + (size_t)s*128;
  const float* vrow = uv + (size_t)d*128 + 64;
  float oacc = b2[0];
  #pragma unroll 4
  for (int o4 = 0; o4 < 16; ++o4) {
    float4 u4 = ld4(urow + o4*4);
    float4 v4 = ld4(vrow + o4*4);
    float4 cc = *reinterpret_cast<const float4*>(&c0s[o4*4]);
    float4 w2 = *reinterpret_cast<const float4*>(&W2s[o4*4]);
    float hh[4] = {u4.x+v4.x+cc.x, u4.y+v4.y+cc.y, u4.z+v4.z+cc.z, u4.w+v4.w+cc.w};
    #pragma unroll
    for (int oo = 0; oo < 4; ++oo) {
      int o = o4*4 + oo;
      float acc = hh[oo];
      #pragma unroll
      for (int j4 = 0; j4 < 8; ++j4) {
        float4 a = *reinterpret_cast<const float4*>(&As[o*32 + j4*4]);
        float4 b = *reinterpret_cast<const float4*>(&Bs[o*32 + j4*4]);
        float4 sfv = sf4[j4], hvv = hv4[j4];
        acc = fmaf(a.x,sfv.x, fmaf(a.y,sfv.y, fmaf(a.z,sfv.z, fmaf(a.w,sfv.w, acc))));
        acc = fmaf(b.x,hvv.x, fmaf(b.y,hvv.y, fmaf(b.z,hvv.z, fmaf(b.w,hvv.w, acc))));
      }
      float w2v = (oo==0) ? w2.x : (oo==1) ? w2.y : (oo==2) ? w2.z : w2.w;
      oacc = fmaf(w2v, fmaxf(acc, 0.f), oacc);
    }
  }
  out[e] = oacc;
}

extern "C" void kernel_launch(void* const* d_in, const int* in_sizes, int n_in,
                              void* d_out, int out_size, void* d_ws, size_t ws_size,
                              hipStream_t stream) {
  const int*   src   = (const int*)d_in[0];
  const int*   dst   = (const int*)d_in[1];
  const int*   t     = (const int*)d_in[2];
  const float* msg   = (const float*)d_in[3];
  const float* price = (const float*)d_in[4];
  // d_in[5] trade_t: unused by reference
  const int*   xst   = (const int*)d_in[6];
  const float* memory= (const float*)d_in[7];
  const float* lu    = (const float*)d_in[8];
  const float* w_t   = (const float*)d_in[9];
  const float* b_t   = (const float*)d_in[10];
  const float* W_ih  = (const float*)d_in[11];
  const float* b_ih  = (const float*)d_in[12];
  const float* W_hh  = (const float*)d_in[13];
  const float* b_hh  = (const float*)d_in[14];
  const float* party = (const float*)d_in[15];
  const float* state = (const float*)d_in[16];
  const float* W_sp  = (const float*)d_in[17];
  const float* b_sp  = (const float*)d_in[18];
  const float* W_ihl = (const float*)d_in[19];
  const float* W_hhl = (const float*)d_in[20];
  const float* b_ihl = (const float*)d_in[21];
  const float* b_hhl = (const float*)d_in[22];
  const float* W_pp  = (const float*)d_in[23];
  const float* b_pp  = (const float*)d_in[24];
  const float* W1    = (const float*)d_in[25];
  const float* b1    = (const float*)d_in[26];
  const float* W2    = (const float*)d_in[27];
  const float* b2    = (const float*)d_in[28];
  float* out = (float*)d_out;

  if (ws_size < WS_NEED) {              // loud failure: zero output
    (void)hipMemsetAsync(d_out, 0, (size_t)out_size*4, stream);
    return;
  }

  char* ws = (char*)d_ws;
  u64*   key  = (u64*)(ws + OFF_KEY);
  int*   cnt  = (int*)(ws + OFF_CNT);
  int*   list = (int*)(ws + OFF_LIST);
  float* uv   = (float*)(ws + OFF_UV);
  float* hn   = (float*)(ws + OFF_HN);
  float* A    = (float*)(ws + OFF_A);
  float* B    = (float*)(ws + OFF_B);
  float* c0   = (float*)(ws + OFF_C0);

  (void)hipMemsetAsync(ws, 0, OFF_LIST, stream);   // zero key[] + count
  k_scatter<<<(NE+255)/256, 256, 0, stream>>>(src, dst, t, key);
  k_compact<<<(NN+255)/256, 256, 0, stream>>>(key, list, cnt);
  k_pre<<<17, 256, 0, stream>>>(W1, W_sp, W_pp, b_sp, b_pp, b1, A, B, c0);
  k_lstm<<<(NE+7)/8, 256, 0, stream>>>(price, W_ihl, W_hhl, b_ihl, b_hhl, hn);
  k_gru<<<(NN+63)/64, 512, 0, stream>>>(key, list, cnt, src, dst, t, msg, memory, lu,
                                        w_t, b_t, W_ih, b_ih, W_hh, b_hh, W1, uv);
  k_final<<<(NE+255)/256, 256, 0, stream>>>(src, dst, xst, party, state, uv, hn,
                                            A, B, c0, W2, b2, out);
}

// Round 13
// 978.779 us; speedup vs baseline: 2.3505x; 2.0055x over previous
//
#include <hip/hip_runtime.h>
#include <stdint.h>

#define NN    200000   // nodes
#define NE    100000   // edges
#define HD    128      // hidden/memory/time dim
#define EFD   64       // edge feat dim
#define NG    384      // 3*HD gates

typedef unsigned long long u64;
typedef short bf16x8 __attribute__((ext_vector_type(8)));   // 8 bf16 (4 VGPRs)
typedef float f32x4  __attribute__((ext_vector_type(4)));   // MFMA C/D frag

// ---- ws layout (bytes) ----
#define OFF_KEY   ((size_t)0)            // u64 * NN = 1,600,000
#define OFF_CNT   ((size_t)1600000)      // int
#define OFF_LIST  ((size_t)1600256)      // int * NN = 800,000
#define OFF_UV    ((size_t)2400256)      // float * NN*128 = 102,400,000
#define OFF_HN    ((size_t)104800256)    // float * NE*32 = 12,800,000
#define OFF_A     ((size_t)117600256)    // float * 2048
#define OFF_B     ((size_t)117608448)    // float * 2048
#define OFF_C0    ((size_t)117616640)    // float * 64 (+pad)
#define OFF_WBF   ((size_t)117616896)    // short * 9*384*64 = 442,368 B (bf16 W, pre-swizzled)
#define WS_NEED   ((size_t)118059264)

__device__ __forceinline__ float frcp(float x){ return __builtin_amdgcn_rcpf(x); }
__device__ __forceinline__ float sigf(float x){ return frcp(1.f + __expf(-x)); }
__device__ __forceinline__ float tanhf_(float x){ return 1.f - 2.f*frcp(__expf(2.f*x) + 1.f); }
__device__ __forceinline__ float4 ld4(const float* p){ return *reinterpret_cast<const float4*>(p); }

// fp32 -> bf16 RNE (bit math; inputs finite)
__device__ __forceinline__ short f2bf(float f){
  unsigned u = __float_as_uint(f);
  u += 0x7fffu + ((u>>16)&1u);
  return (short)(u>>16);
}

// async global->LDS, 16B per lane; LDS dest = (first lane's ptr) + lane*16.
__device__ __forceinline__ void gl16(const void* g, void* l) {
  __builtin_amdgcn_global_load_lds(
      (const __attribute__((address_space(1))) void*)g,
      (__attribute__((address_space(3))) void*)l, 16, 0, 0);
}

// ---------- per-node winner key: max (t, isDst, e) ----------
__global__ void k_scatter(const int* __restrict__ src, const int* __restrict__ dst,
                          const int* __restrict__ t, u64* __restrict__ key) {
  int e = blockIdx.x*256 + threadIdx.x;
  if (e >= NE) return;
  u64 tt = (u64)(unsigned)(t[e] + 1);
  atomicMax(&key[src[e]], (tt<<18) | (u64)(unsigned)e);
  atomicMax(&key[dst[e]], (tt<<18) | (1ULL<<17) | (u64)(unsigned)e);
}

__global__ void k_compact(const u64* __restrict__ key, int* __restrict__ list,
                          int* __restrict__ count) {
  int n = blockIdx.x*256 + threadIdx.x;
  if (n >= NN) return;
  if (key[n] != 0ULL) { int p = atomicAdd(count, 1); list[p] = n; }
}

// ---------- fold W1/W_sp/W_pp/biases: A=W1a@W_sp, B=(W1b+W1c)@W_pp, c0 ----------
__global__ void k_pre(const float* __restrict__ W1, const float* __restrict__ W_sp,
                      const float* __restrict__ W_pp, const float* __restrict__ b_sp,
                      const float* __restrict__ b_pp, const float* __restrict__ b1,
                      float* __restrict__ A, float* __restrict__ B, float* __restrict__ c0)
{
  int tid = blockIdx.x*256 + threadIdx.x;
  if (tid < 2048) {
    int o = tid >> 5, j = tid & 31;
    float s = 0.f;
    for (int k = 0; k < 128; ++k) s = fmaf(W1[o*NG + k], W_sp[k*32 + j], s);
    A[tid] = s;
  } else if (tid < 4096) {
    int q = tid - 2048;
    int o = q >> 5, j = q & 31;
    float s = 0.f;
    for (int k = 0; k < 128; ++k)
      s = fmaf(W1[o*NG + 128 + k] + W1[o*NG + 256 + k], W_pp[k*32 + j], s);
    B[q] = s;
  } else if (tid < 4160) {
    int o = tid - 4096;
    float s = b1[o];
    for (int k = 0; k < 128; ++k) {
      s = fmaf(W1[o*NG + k], b_sp[k], s);
      s = fmaf(W1[o*NG + 128 + k] + W1[o*NG + 256 + k], b_pp[k], s);
    }
    c0[o] = s;
  }
}

// ---------- pre-convert GRU weights to bf16, pre-swizzled for gl16 staging ----------
// Wbf[ch9][n][slot s] holds k8 = s ^ (n&7); k = ch9*64 + k8*8 + e.
__global__ void k_prew(const float* __restrict__ W_ih, const float* __restrict__ W_hh,
                       short* __restrict__ Wbf)
{
  int idx = blockIdx.x*256 + threadIdx.x;
  if (idx >= 9*384*8) return;
  int s   = idx & 7;
  int n   = (idx >> 3) % 384;
  int ch9 = idx / (384*8);
  int k8  = s ^ (n & 7);
  int k   = ch9*64 + k8*8;
  short v[8];
  #pragma unroll
  for (int e = 0; e < 8; ++e) {
    int kk = k + e;
    float f = (kk < 448) ? W_ih[(size_t)n*448 + kk] : W_hh[(size_t)n*HD + (kk-448)];
    v[e] = f2bf(f);
  }
  *reinterpret_cast<bf16x8*>(Wbf + (size_t)ch9*24576 + n*64 + s*8) =
      *reinterpret_cast<bf16x8*>(v);
}

// ---------- GRU via bf16 MFMA: 64 nodes/block, 512 thr = 8 waves ----------
// Wave w: M-tile = (w&3)*16 nodes, h-slice = (w>>2)*64..+64 (4 h-tiles).
// Per wave owns r,z,n gate tiles for its h-slice -> GRU nonlinearity lane-local.
// K chunked by 64 (9 chunks); chunk>=7 is the self-memory part -> separate accNM
// (n-gate needs r * (hn_mem + b_hh) per reference).
__global__ __launch_bounds__(512, 2) void k_gru(
    const u64* __restrict__ key, const int* __restrict__ list, const int* __restrict__ count,
    const int* __restrict__ src, const int* __restrict__ dst, const int* __restrict__ t,
    const float* __restrict__ msg, const float* __restrict__ memory,
    const float* __restrict__ last_update,
    const float* __restrict__ w_t, const float* __restrict__ b_t,
    const short* __restrict__ Wbf, const float* __restrict__ b_ih,
    const float* __restrict__ b_hh, const float* __restrict__ W1,
    float* __restrict__ uv)
{
  __shared__ short Wsb[24576];    // 48KB: W chunk [384 n][8 slots][8 bf16]
  __shared__ short Xsb[4096];     // 8KB: X chunk [64 node][8 slots][8 bf16]
  __shared__ float bias4[512];    // br|bz|bnx|bnm per h
  __shared__ int   sn_self[64];
  __shared__ int   sn_other[64];
  __shared__ int   sn_e[64];
  __shared__ float sn_dt[64];

  float* Mn  = reinterpret_cast<float*>(&Wsb[8192]);  // [64][128] fp32, bytes 16K..48K
  float* W1s = reinterpret_cast<float*>(&Wsb[0]);     // 4096 floats for uv staging

  int cnt = count[0];
  int base = blockIdx.x * 64;
  if (base >= cnt) return;
  int tid = threadIdx.x;
  int tx = tid & 31, ty = tid >> 5;      // for uv epilogue (16 ty-groups)
  int wid = tid >> 6, lane = tid & 63;
  int lr = lane & 15, lk = lane >> 4;    // fragment row/col & k-group
  int mb = (wid & 3) * 16;               // M-tile node base
  int hb = (wid >> 2) * 4;               // h-tile base (4 tiles = 64 h)

  if (tid < 64) {
    int idx = base + tid;
    int cl = idx < cnt ? idx : (cnt - 1);
    int n = list[cl];
    u64 k = key[n];
    int e   = (int)(k & 0x1FFFFULL);
    int isd = (int)((k >> 17) & 1ULL);
    sn_self[tid]  = n;
    sn_other[tid] = isd ? src[e] : dst[e];
    sn_e[tid]     = e;
    sn_dt[tid]    = (float)t[e] - last_update[n];
  }
  if (tid < 128) {
    int h = tid;
    bias4[h]       = b_ih[h]       + b_hh[h];
    bias4[128 + h] = b_ih[128 + h] + b_hh[128 + h];
    bias4[256 + h] = b_ih[256 + h];
    bias4[384 + h] = b_hh[256 + h];
  }
  __syncthreads();

  f32x4 aR[4], aZ[4], aNX[4], aNM[4];
  #pragma unroll
  for (int j = 0; j < 4; ++j) { aR[j] = (f32x4)0.f; aZ[j] = (f32x4)0.f;
                                aNX[j] = (f32x4)0.f; aNM[j] = (f32x4)0.f; }

  for (int ch9 = 0; ch9 < 9; ++ch9) {
    // W chunk: 3072 x 16B via gl16, linear (global pre-swizzled by k_prew)
    #pragma unroll
    for (int i = 0; i < 6; ++i) {
      int q = i*512 + tid;
      gl16(Wbf + (size_t)ch9*24576 + q*8, &Wsb[q*8]);
    }
    // X chunk: thread -> node=tid>>3, k8=tid&7 (8 consecutive k), convert to bf16
    {
      int node = tid >> 3, k8 = tid & 7;
      int kg = ch9*64 + k8*8;
      int self = sn_self[node], other = sn_other[node], e = sn_e[node];
      float xf[8];
      if (kg < 128) {
        float4 a = ld4(memory + (size_t)self*HD + kg);
        float4 b = ld4(memory + (size_t)self*HD + kg + 4);
        xf[0]=a.x; xf[1]=a.y; xf[2]=a.z; xf[3]=a.w; xf[4]=b.x; xf[5]=b.y; xf[6]=b.z; xf[7]=b.w;
      } else if (kg < 256) {
        float4 a = ld4(memory + (size_t)other*HD + (kg-128));
        float4 b = ld4(memory + (size_t)other*HD + (kg-128) + 4);
        xf[0]=a.x; xf[1]=a.y; xf[2]=a.z; xf[3]=a.w; xf[4]=b.x; xf[5]=b.y; xf[6]=b.z; xf[7]=b.w;
      } else if (kg < 320) {
        float4 a = ld4(msg + (size_t)e*EFD + (kg-256));
        float4 b = ld4(msg + (size_t)e*EFD + (kg-256) + 4);
        xf[0]=a.x; xf[1]=a.y; xf[2]=a.z; xf[3]=a.w; xf[4]=b.x; xf[5]=b.y; xf[6]=b.z; xf[7]=b.w;
      } else if (kg < 448) {
        int kk = kg - 320; float dt = sn_dt[node];
        #pragma unroll
        for (int q = 0; q < 8; ++q) xf[q] = cosf(fmaf(dt, w_t[kk+q], b_t[kk+q]));
      } else {
        float4 a = ld4(memory + (size_t)self*HD + (kg-448));
        float4 b = ld4(memory + (size_t)self*HD + (kg-448) + 4);
        xf[0]=a.x; xf[1]=a.y; xf[2]=a.z; xf[3]=a.w; xf[4]=b.x; xf[5]=b.y; xf[6]=b.z; xf[7]=b.w;
      }
      short xs[8];
      #pragma unroll
      for (int q = 0; q < 8; ++q) xs[q] = f2bf(xf[q]);
      *reinterpret_cast<bf16x8*>(&Xsb[node*64 + ((k8 ^ (node&7))<<3)]) =
          *reinterpret_cast<bf16x8*>(xs);
    }
    __syncthreads();   // drains gl16 vmcnt + ds writes

    int anode = mb + lr;
    if (ch9 < 7) {
      #pragma unroll
      for (int ks = 0; ks < 2; ++ks) {
        int k8 = ks*4 + lk;
        bf16x8 a = *reinterpret_cast<const bf16x8*>(&Xsb[anode*64 + ((k8 ^ (anode&7))<<3)]);
        #pragma unroll
        for (int j = 0; j < 4; ++j) {
          int nR = (hb + j)*16 + lr;
          int nZ = nR + 128;
          int nN = nR + 256;
          bf16x8 bR = *reinterpret_cast<const bf16x8*>(&Wsb[nR*64 + ((k8 ^ (nR&7))<<3)]);
          aR[j] = __builtin_amdgcn_mfma_f32_16x16x32_bf16(a, bR, aR[j], 0, 0, 0);
          bf16x8 bZ = *reinterpret_cast<const bf16x8*>(&Wsb[nZ*64 + ((k8 ^ (nZ&7))<<3)]);
          aZ[j] = __builtin_amdgcn_mfma_f32_16x16x32_bf16(a, bZ, aZ[j], 0, 0, 0);
          bf16x8 bN = *reinterpret_cast<const bf16x8*>(&Wsb[nN*64 + ((k8 ^ (nN&7))<<3)]);
          aNX[j] = __builtin_amdgcn_mfma_f32_16x16x32_bf16(a, bN, aNX[j], 0, 0, 0);
        }
      }
    } else {
      #pragma unroll
      for (int ks = 0; ks < 2; ++ks) {
        int k8 = ks*4 + lk;
        bf16x8 a = *reinterpret_cast<const bf16x8*>(&Xsb[anode*64 + ((k8 ^ (anode&7))<<3)]);
        #pragma unroll
        for (int j = 0; j < 4; ++j) {
          int nR = (hb + j)*16 + lr;
          int nZ = nR + 128;
          int nN = nR + 256;
          bf16x8 bR = *reinterpret_cast<const bf16x8*>(&Wsb[nR*64 + ((k8 ^ (nR&7))<<3)]);
          aR[j] = __builtin_amdgcn_mfma_f32_16x16x32_bf16(a, bR, aR[j], 0, 0, 0);
          bf16x8 bZ = *reinterpret_cast<const bf16x8*>(&Wsb[nZ*64 + ((k8 ^ (nZ&7))<<3)]);
          aZ[j] = __builtin_amdgcn_mfma_f32_16x16x32_bf16(a, bZ, aZ[j], 0, 0, 0);
          bf16x8 bN = *reinterpret_cast<const bf16x8*>(&Wsb[nN*64 + ((k8 ^ (nN&7))<<3)]);
          aNM[j] = __builtin_amdgcn_mfma_f32_16x16x32_bf16(a, bN, aNM[j], 0, 0, 0);
        }
      }
    }
    __syncthreads();   // all reads of Wsb/Xsb done before next stage
  }

  // ---- GRU nonlinearity, fully lane-local; Mn overlays Wsb[16K..48K) ----
  // D mapping (m89-verified): col = lane&15 (gate lr), row = (lane>>4)*4 + i (node).
  #pragma unroll
  for (int j = 0; j < 4; ++j) {
    int h = (hb + j)*16 + lr;
    float br_ = bias4[h], bz_ = bias4[128+h], bnx_ = bias4[256+h], bnm_ = bias4[384+h];
    #pragma unroll
    for (int i = 0; i < 4; ++i) {
      int node = mb + lk*4 + i;
      float r  = sigf(aR[j][i] + br_);
      float z  = sigf(aZ[j][i] + bz_);
      float nv = tanhf_(aNX[j][i] + bnx_ + r*(aNM[j][i] + bnm_));
      float m  = memory[(size_t)sn_self[node]*HD + h];
      Mn[node*128 + h] = (1.f - z)*nv + z*m;
    }
  }
  __syncthreads();

  // ---- uv = [W1a@mn | W1b@mn] fp32: K=128 in 4 chunks; W1 staged at W1s ----
  float acc2[4][4];
  #pragma unroll
  for (int a = 0; a < 4; ++a) {
    #pragma unroll
    for (int b = 0; b < 4; ++b) acc2[a][b] = 0.f;
  }
  for (int ch = 0; ch < 4; ++ch) {
    #pragma unroll
    for (int i = 0; i < 2; ++i) {
      int idx = tid + 512*i;               // exactly the 1024-quad W1 tile
      int o = idx >> 3, k4 = idx & 7;
      int k = ch*32 + k4*4;
      float4 w = (o < 64) ? ld4(W1 + (size_t)o*NG + k)
                          : ld4(W1 + (size_t)(o-64)*NG + 128 + k);
      *reinterpret_cast<float4*>(&W1s[o*32 + ((k4 ^ (o&7))<<2)]) = w;
    }
    __syncthreads();
    #pragma unroll
    for (int k4 = 0; k4 < 8; ++k4) {
      float4 xv[4];
      #pragma unroll
      for (int nn = 0; nn < 4; ++nn)
        xv[nn] = *reinterpret_cast<const float4*>(&Mn[(ty + 16*nn)*128 + ch*32 + k4*4]);
      #pragma unroll
      for (int og = 0; og < 4; ++og) {
        int o = tx + 32*og;
        float4 w = *reinterpret_cast<const float4*>(&W1s[o*32 + ((k4 ^ (o&7))<<2)]);
        #pragma unroll
        for (int nn = 0; nn < 4; ++nn) {
          acc2[nn][og] = fmaf(w.x, xv[nn].x, acc2[nn][og]);
          acc2[nn][og] = fmaf(w.y, xv[nn].y, acc2[nn][og]);
          acc2[nn][og] = fmaf(w.z, xv[nn].z, acc2[nn][og]);
          acc2[nn][og] = fmaf(w.w, xv[nn].w, acc2[nn][og]);
        }
      }
    }
    __syncthreads();
  }
  #pragma unroll
  for (int nn = 0; nn < 4; ++nn) {
    int nl = ty + 16*nn;
    if (base + nl < cnt) {
      int self = sn_self[nl];
      #pragma unroll
      for (int og = 0; og < 4; ++og)
        uv[(size_t)self*128 + tx + 32*og] = acc2[nn][og];
    }
  }
}

// ---------- price LSTM: thread (g,j) owns hidden unit j of edge g ----------
__global__ __launch_bounds__(256) void k_lstm(
    const float* __restrict__ price, const float* __restrict__ W_ihl,
    const float* __restrict__ W_hhl, const float* __restrict__ b_ihl,
    const float* __restrict__ b_hhl, float* __restrict__ hn_out)
{
  __shared__ float Wsh[4096];     // W_hh row-major [128][32] = 16KB
  __shared__ float ps[8][52];     // price rows (pad to 52)
  __shared__ float hrow[8][36];   // h per edge (stride 36)
  int tid = threadIdx.x;
  int g = tid >> 5;               // edge slot 0..7
  int j = tid & 31;               // hidden unit

  for (int i = tid; i < 1024; i += 256)
    *reinterpret_cast<float4*>(&Wsh[i*4]) = ld4(W_hhl + i*4);
  {
    int ebase = blockIdx.x*8;
    int m = NE - ebase; if (m > 8) m = 8;
    const float* pb = price + (size_t)ebase*50;
    for (int i = tid; i < m*50; i += 256) ps[i/50][i%50] = pb[i];
  }
  __syncthreads();

  float wi[32], wf[32], wg[32], wo[32];
  #pragma unroll
  for (int k = 0; k < 32; ++k) {
    wi[k] = Wsh[j*32 + k];
    wf[k] = Wsh[(32+j)*32 + k];
    wg[k] = Wsh[(64+j)*32 + k];
    wo[k] = Wsh[(96+j)*32 + k];
  }
  float wxi = W_ihl[j],    wxf = W_ihl[32+j], wxg = W_ihl[64+j], wxo = W_ihl[96+j];
  float bi  = b_ihl[j]    + b_hhl[j];
  float bf  = b_ihl[32+j] + b_hhl[32+j];
  float bg  = b_ihl[64+j] + b_hhl[64+j];
  float bo  = b_ihl[96+j] + b_hhl[96+j];

  float c = 0.f, hlast = 0.f;
  hrow[g][j] = 0.f;
  __syncthreads();

  #pragma unroll 1
  for (int s = 0; s < 50; ++s) {
    float x = ps[g][s];
    float ai = fmaf(x, wxi, bi);
    float af = fmaf(x, wxf, bf);
    float ag = fmaf(x, wxg, bg);
    float ao = fmaf(x, wxo, bo);
    #pragma unroll
    for (int k4 = 0; k4 < 8; ++k4) {
      float4 hv = *reinterpret_cast<const float4*>(&hrow[g][k4*4]);
      int b = k4*4;
      ai = fmaf(wi[b],hv.x, fmaf(wi[b+1],hv.y, fmaf(wi[b+2],hv.z, fmaf(wi[b+3],hv.w, ai))));
      af = fmaf(wf[b],hv.x, fmaf(wf[b+1],hv.y, fmaf(wf[b+2],hv.z, fmaf(wf[b+3],hv.w, af))));
      ag = fmaf(wg[b],hv.x, fmaf(wg[b+1],hv.y, fmaf(wg[b+2],hv.z, fmaf(wg[b+3],hv.w, ag))));
      ao = fmaf(wo[b],hv.x, fmaf(wo[b+1],hv.y, fmaf(wo[b+2],hv.z, fmaf(wo[b+3],hv.w, ao))));
    }
    float ig = sigf(ai), fg = sigf(af), gv = tanhf_(ag), og = sigf(ao);
    c = fmaf(fg, c, ig*gv);
    hlast = og * tanhf_(c);
    hrow[g][j] = hlast;
  }

  int e = blockIdx.x*8 + g;
  if (e < NE) hn_out[(size_t)e*32 + j] = hlast;
}

// ---------- fused output: out = W2 @ relu(u[s] + v[d] + A@sf + B@hn + c0) + b2 ----------
__global__ __launch_bounds__(256) void k_final(
    const int* __restrict__ src, const int* __restrict__ dst, const int* __restrict__ xst,
    const float* __restrict__ party, const float* __restrict__ state,
    const float* __restrict__ uv, const float* __restrict__ hn,
    const float* __restrict__ A, const float* __restrict__ B, const float* __restrict__ c0,
    const float* __restrict__ W2, const float* __restrict__ b2, float* __restrict__ out)
{
  __shared__ float As[2048], Bs[2048], c0s[64], W2s[64];
  int tid = threadIdx.x;
  for (int i = tid; i < 2048; i += 256) { As[i] = A[i]; Bs[i] = B[i]; }
  if (tid < 64) { c0s[tid] = c0[tid]; W2s[tid] = W2[tid]; }
  __syncthreads();
  int e = blockIdx.x*256 + tid;
  if (e >= NE) return;
  int s = src[e], d = dst[e];
  int p = xst[2*s], stt = xst[2*s + 1];
  float4 sf4[8], hv4[8];
  #pragma unroll
  for (int i = 0; i < 4; ++i) sf4[i]   = ld4(party + p*16 + i*4);
  #pragma unroll
  for (int i = 0; i < 4; ++i) sf4[4+i] = ld4(state + stt*16 + i*4);
  #pragma unroll
  for (int i = 0; i < 8; ++i) hv4[i] = ld4(hn + (size_t)e*32 + i*4);
  const float* urow = uv + (size_t)s*128;
  const float* vrow = uv + (size_t)d*128 + 64;
  float oacc = b2[0];
  #pragma unroll 4
  for (int o4 = 0; o4 < 16; ++o4) {
    float4 u4 = ld4(urow + o4*4);
    float4 v4 = ld4(vrow + o4*4);
    float4 cc = *reinterpret_cast<const float4*>(&c0s[o4*4]);
    float4 w2 = *reinterpret_cast<const float4*>(&W2s[o4*4]);
    float hh[4] = {u4.x+v4.x+cc.x, u4.y+v4.y+cc.y, u4.z+v4.z+cc.z, u4.w+v4.w+cc.w};
    #pragma unroll
    for (int oo = 0; oo < 4; ++oo) {
      int o = o4*4 + oo;
      float acc = hh[oo];
      #pragma unroll
      for (int j4 = 0; j4 < 8; ++j4) {
        float4 a = *reinterpret_cast<const float4*>(&As[o*32 + j4*4]);
        float4 b = *reinterpret_cast<const float4*>(&Bs[o*32 + j4*4]);
        float4 sfv = sf4[j4], hvv = hv4[j4];
        acc = fmaf(a.x,sfv.x, fmaf(a.y,sfv.y, fmaf(a.z,sfv.z, fmaf(a.w,sfv.w, acc))));
        acc = fmaf(b.x,hvv.x, fmaf(b.y,hvv.y, fmaf(b.z,hvv.z, fmaf(b.w,hvv.w, acc))));
      }
      float w2v = (oo==0) ? w2.x : (oo==1) ? w2.y : (oo==2) ? w2.z : w2.w;
      oacc = fmaf(w2v, fmaxf(acc, 0.f), oacc);
    }
  }
  out[e] = oacc;
}

extern "C" void kernel_launch(void* const* d_in, const int* in_sizes, int n_in,
                              void* d_out, int out_size, void* d_ws, size_t ws_size,
                              hipStream_t stream) {
  const int*   src   = (const int*)d_in[0];
  const int*   dst   = (const int*)d_in[1];
  const int*   t     = (const int*)d_in[2];
  const float* msg   = (const float*)d_in[3];
  const float* price = (const float*)d_in[4];
  // d_in[5] trade_t: unused by reference
  const int*   xst   = (const int*)d_in[6];
  const float* memory= (const float*)d_in[7];
  const float* lu    = (const float*)d_in[8];
  const float* w_t   = (const float*)d_in[9];
  const float* b_t   = (const float*)d_in[10];
  const float* W_ih  = (const float*)d_in[11];
  const float* b_ih  = (const float*)d_in[12];
  const float* W_hh  = (const float*)d_in[13];
  const float* b_hh  = (const float*)d_in[14];
  const float* party = (const float*)d_in[15];
  const float* state = (const float*)d_in[16];
  const float* W_sp  = (const float*)d_in[17];
  const float* b_sp  = (const float*)d_in[18];
  const float* W_ihl = (const float*)d_in[19];
  const float* W_hhl = (const float*)d_in[20];
  const float* b_ihl = (const float*)d_in[21];
  const float* b_hhl = (const float*)d_in[22];
  const float* W_pp  = (const float*)d_in[23];
  const float* b_pp  = (const float*)d_in[24];
  const float* W1    = (const float*)d_in[25];
  const float* b1    = (const float*)d_in[26];
  const float* W2    = (const float*)d_in[27];
  const float* b2    = (const float*)d_in[28];
  float* out = (float*)d_out;

  if (ws_size < WS_NEED) {              // loud failure: zero output
    (void)hipMemsetAsync(d_out, 0, (size_t)out_size*4, stream);
    return;
  }

  char* ws = (char*)d_ws;
  u64*   key  = (u64*)(ws + OFF_KEY);
  int*   cnt  = (int*)(ws + OFF_CNT);
  int*   list = (int*)(ws + OFF_LIST);
  float* uv   = (float*)(ws + OFF_UV);
  float* hn   = (float*)(ws + OFF_HN);
  float* A    = (float*)(ws + OFF_A);
  float* B    = (float*)(ws + OFF_B);
  float* c0   = (float*)(ws + OFF_C0);
  short* Wbf  = (short*)(ws + OFF_WBF);

  (void)hipMemsetAsync(ws, 0, OFF_LIST, stream);   // zero key[] + count
  k_scatter<<<(NE+255)/256, 256, 0, stream>>>(src, dst, t, key);
  k_compact<<<(NN+255)/256, 256, 0, stream>>>(key, list, cnt);
  k_pre<<<17, 256, 0, stream>>>(W1, W_sp, W_pp, b_sp, b_pp, b1, A, B, c0);
  k_prew<<<108, 256, 0, stream>>>(W_ih, W_hh, Wbf);
  k_lstm<<<(NE+7)/8, 256, 0, stream>>>(price, W_ihl, W_hhl, b_ihl, b_hhl, hn);
  k_gru<<<(NN+63)/64, 512, 0, stream>>>(key, list, cnt, src, dst, t, msg, memory, lu,
                                        w_t, b_t, Wbf, b_ih, b_hh, W1, uv);
  k_final<<<(NE+255)/256, 256, 0, stream>>>(src, dst, xst, party, state, uv, hn,
                                            A, B, c0, W2, b2, out);
}

// Round 14
// 628.711 us; speedup vs baseline: 3.6592x; 1.5568x over previous
//
#include <hip/hip_runtime.h>
#include <stdint.h>

#define NN    200000   // nodes
#define NE    100000   // edges
#define HD    128      // hidden/memory/time dim
#define EFD   64       // edge feat dim
#define NG    384      // 3*HD gates

typedef unsigned long long u64;
typedef short bf16x8 __attribute__((ext_vector_type(8)));   // 8 bf16 (4 VGPRs)
typedef float f32x4  __attribute__((ext_vector_type(4)));   // MFMA C/D frag

// ---- ws layout (bytes) ----
#define OFF_KEY   ((size_t)0)            // u64 * NN = 1,600,000
#define OFF_CNT   ((size_t)1600000)      // int
#define OFF_LIST  ((size_t)1600256)      // int * NN = 800,000
#define OFF_UV    ((size_t)2400256)      // float * NN*128 = 102,400,000
#define OFF_HN    ((size_t)104800256)    // float * NE*32 = 12,800,000
#define OFF_A     ((size_t)117600256)    // float * 2048
#define OFF_B     ((size_t)117608448)    // float * 2048
#define OFF_C0    ((size_t)117616640)    // float * 64 (+pad)
#define OFF_WBF   ((size_t)117616896)    // short * 9*384*64 = 442,368 B (bf16 W, pre-swizzled)
#define WS_NEED   ((size_t)118059264)

__device__ __forceinline__ float frcp(float x){ return __builtin_amdgcn_rcpf(x); }
__device__ __forceinline__ float sigf(float x){ return frcp(1.f + __expf(-x)); }
__device__ __forceinline__ float tanhf_(float x){ return 1.f - 2.f*frcp(__expf(2.f*x) + 1.f); }
__device__ __forceinline__ float4 ld4(const float* p){ return *reinterpret_cast<const float4*>(p); }

// fp32 -> bf16 RNE (bit math; inputs finite)
__device__ __forceinline__ short f2bf(float f){
  unsigned u = __float_as_uint(f);
  u += 0x7fffu + ((u>>16)&1u);
  return (short)(u>>16);
}

// async global->LDS, 16B per lane; LDS dest = (first lane's ptr) + lane*16.
__device__ __forceinline__ void gl16(const void* g, void* l) {
  __builtin_amdgcn_global_load_lds(
      (const __attribute__((address_space(1))) void*)g,
      (__attribute__((address_space(3))) void*)l, 16, 0, 0);
}

// ---------- per-node winner key: max (t, isDst, e) ----------
__global__ void k_scatter(const int* __restrict__ src, const int* __restrict__ dst,
                          const int* __restrict__ t, u64* __restrict__ key) {
  int e = blockIdx.x*256 + threadIdx.x;
  if (e >= NE) return;
  u64 tt = (u64)(unsigned)(t[e] + 1);
  atomicMax(&key[src[e]], (tt<<18) | (u64)(unsigned)e);
  atomicMax(&key[dst[e]], (tt<<18) | (1ULL<<17) | (u64)(unsigned)e);
}

__global__ void k_compact(const u64* __restrict__ key, int* __restrict__ list,
                          int* __restrict__ count) {
  int n = blockIdx.x*256 + threadIdx.x;
  if (n >= NN) return;
  if (key[n] != 0ULL) { int p = atomicAdd(count, 1); list[p] = n; }
}

// ---------- fold W1/W_sp/W_pp/biases: A=W1a@W_sp, B=(W1b+W1c)@W_pp, c0 ----------
__global__ void k_pre(const float* __restrict__ W1, const float* __restrict__ W_sp,
                      const float* __restrict__ W_pp, const float* __restrict__ b_sp,
                      const float* __restrict__ b_pp, const float* __restrict__ b1,
                      float* __restrict__ A, float* __restrict__ B, float* __restrict__ c0)
{
  int tid = blockIdx.x*256 + threadIdx.x;
  if (tid < 2048) {
    int o = tid >> 5, j = tid & 31;
    float s = 0.f;
    for (int k = 0; k < 128; ++k) s = fmaf(W1[o*NG + k], W_sp[k*32 + j], s);
    A[tid] = s;
  } else if (tid < 4096) {
    int q = tid - 2048;
    int o = q >> 5, j = q & 31;
    float s = 0.f;
    for (int k = 0; k < 128; ++k)
      s = fmaf(W1[o*NG + 128 + k] + W1[o*NG + 256 + k], W_pp[k*32 + j], s);
    B[q] = s;
  } else if (tid < 4160) {
    int o = tid - 4096;
    float s = b1[o];
    for (int k = 0; k < 128; ++k) {
      s = fmaf(W1[o*NG + k], b_sp[k], s);
      s = fmaf(W1[o*NG + 128 + k] + W1[o*NG + 256 + k], b_pp[k], s);
    }
    c0[o] = s;
  }
}

// ---------- pre-convert GRU weights to bf16, pre-swizzled for gl16 staging ----------
__global__ void k_prew(const float* __restrict__ W_ih, const float* __restrict__ W_hh,
                       short* __restrict__ Wbf)
{
  int idx = blockIdx.x*256 + threadIdx.x;
  if (idx >= 9*384*8) return;
  int s   = idx & 7;
  int n   = (idx >> 3) % 384;
  int ch9 = idx / (384*8);
  int k8  = s ^ (n & 7);
  int k   = ch9*64 + k8*8;
  short v[8];
  #pragma unroll
  for (int e = 0; e < 8; ++e) {
    int kk = k + e;
    float f = (kk < 448) ? W_ih[(size_t)n*448 + kk] : W_hh[(size_t)n*HD + (kk-448)];
    v[e] = f2bf(f);
  }
  *reinterpret_cast<bf16x8*>(Wbf + (size_t)ch9*24576 + n*64 + s*8) =
      *reinterpret_cast<bf16x8*>(v);
}

// ---------- GRU via bf16 MFMA: 64 nodes/block, 512 thr = 8 waves (R13, verified) ----------
__global__ __launch_bounds__(512, 2) void k_gru(
    const u64* __restrict__ key, const int* __restrict__ list, const int* __restrict__ count,
    const int* __restrict__ src, const int* __restrict__ dst, const int* __restrict__ t,
    const float* __restrict__ msg, const float* __restrict__ memory,
    const float* __restrict__ last_update,
    const float* __restrict__ w_t, const float* __restrict__ b_t,
    const short* __restrict__ Wbf, const float* __restrict__ b_ih,
    const float* __restrict__ b_hh, const float* __restrict__ W1,
    float* __restrict__ uv)
{
  __shared__ short Wsb[24576];    // 48KB: W chunk [384 n][8 slots][8 bf16]
  __shared__ short Xsb[4096];     // 8KB: X chunk [64 node][8 slots][8 bf16]
  __shared__ float bias4[512];    // br|bz|bnx|bnm per h
  __shared__ int   sn_self[64];
  __shared__ int   sn_other[64];
  __shared__ int   sn_e[64];
  __shared__ float sn_dt[64];

  float* Mn  = reinterpret_cast<float*>(&Wsb[8192]);  // [64][128] fp32, bytes 16K..48K
  float* W1s = reinterpret_cast<float*>(&Wsb[0]);     // 4096 floats for uv staging

  int cnt = count[0];
  int base = blockIdx.x * 64;
  if (base >= cnt) return;
  int tid = threadIdx.x;
  int tx = tid & 31, ty = tid >> 5;      // for uv epilogue (16 ty-groups)
  int wid = tid >> 6, lane = tid & 63;
  int lr = lane & 15, lk = lane >> 4;    // fragment row/col & k-group
  int mb = (wid & 3) * 16;               // M-tile node base
  int hb = (wid >> 2) * 4;               // h-tile base (4 tiles = 64 h)

  if (tid < 64) {
    int idx = base + tid;
    int cl = idx < cnt ? idx : (cnt - 1);
    int n = list[cl];
    u64 k = key[n];
    int e   = (int)(k & 0x1FFFFULL);
    int isd = (int)((k >> 17) & 1ULL);
    sn_self[tid]  = n;
    sn_other[tid] = isd ? src[e] : dst[e];
    sn_e[tid]     = e;
    sn_dt[tid]    = (float)t[e] - last_update[n];
  }
  if (tid < 128) {
    int h = tid;
    bias4[h]       = b_ih[h]       + b_hh[h];
    bias4[128 + h] = b_ih[128 + h] + b_hh[128 + h];
    bias4[256 + h] = b_ih[256 + h];
    bias4[384 + h] = b_hh[256 + h];
  }
  __syncthreads();

  f32x4 aR[4], aZ[4], aNX[4], aNM[4];
  #pragma unroll
  for (int j = 0; j < 4; ++j) { aR[j] = (f32x4)0.f; aZ[j] = (f32x4)0.f;
                                aNX[j] = (f32x4)0.f; aNM[j] = (f32x4)0.f; }

  for (int ch9 = 0; ch9 < 9; ++ch9) {
    #pragma unroll
    for (int i = 0; i < 6; ++i) {
      int q = i*512 + tid;
      gl16(Wbf + (size_t)ch9*24576 + q*8, &Wsb[q*8]);
    }
    {
      int node = tid >> 3, k8 = tid & 7;
      int kg = ch9*64 + k8*8;
      int self = sn_self[node], other = sn_other[node], e = sn_e[node];
      float xf[8];
      if (kg < 128) {
        float4 a = ld4(memory + (size_t)self*HD + kg);
        float4 b = ld4(memory + (size_t)self*HD + kg + 4);
        xf[0]=a.x; xf[1]=a.y; xf[2]=a.z; xf[3]=a.w; xf[4]=b.x; xf[5]=b.y; xf[6]=b.z; xf[7]=b.w;
      } else if (kg < 256) {
        float4 a = ld4(memory + (size_t)other*HD + (kg-128));
        float4 b = ld4(memory + (size_t)other*HD + (kg-128) + 4);
        xf[0]=a.x; xf[1]=a.y; xf[2]=a.z; xf[3]=a.w; xf[4]=b.x; xf[5]=b.y; xf[6]=b.z; xf[7]=b.w;
      } else if (kg < 320) {
        float4 a = ld4(msg + (size_t)e*EFD + (kg-256));
        float4 b = ld4(msg + (size_t)e*EFD + (kg-256) + 4);
        xf[0]=a.x; xf[1]=a.y; xf[2]=a.z; xf[3]=a.w; xf[4]=b.x; xf[5]=b.y; xf[6]=b.z; xf[7]=b.w;
      } else if (kg < 448) {
        int kk = kg - 320; float dt = sn_dt[node];
        #pragma unroll
        for (int q = 0; q < 8; ++q) xf[q] = cosf(fmaf(dt, w_t[kk+q], b_t[kk+q]));
      } else {
        float4 a = ld4(memory + (size_t)self*HD + (kg-448));
        float4 b = ld4(memory + (size_t)self*HD + (kg-448) + 4);
        xf[0]=a.x; xf[1]=a.y; xf[2]=a.z; xf[3]=a.w; xf[4]=b.x; xf[5]=b.y; xf[6]=b.z; xf[7]=b.w;
      }
      short xs[8];
      #pragma unroll
      for (int q = 0; q < 8; ++q) xs[q] = f2bf(xf[q]);
      *reinterpret_cast<bf16x8*>(&Xsb[node*64 + ((k8 ^ (node&7))<<3)]) =
          *reinterpret_cast<bf16x8*>(xs);
    }
    __syncthreads();

    int anode = mb + lr;
    if (ch9 < 7) {
      #pragma unroll
      for (int ks = 0; ks < 2; ++ks) {
        int k8 = ks*4 + lk;
        bf16x8 a = *reinterpret_cast<const bf16x8*>(&Xsb[anode*64 + ((k8 ^ (anode&7))<<3)]);
        #pragma unroll
        for (int j = 0; j < 4; ++j) {
          int nR = (hb + j)*16 + lr;
          int nZ = nR + 128;
          int nN = nR + 256;
          bf16x8 bR = *reinterpret_cast<const bf16x8*>(&Wsb[nR*64 + ((k8 ^ (nR&7))<<3)]);
          aR[j] = __builtin_amdgcn_mfma_f32_16x16x32_bf16(a, bR, aR[j], 0, 0, 0);
          bf16x8 bZ = *reinterpret_cast<const bf16x8*>(&Wsb[nZ*64 + ((k8 ^ (nZ&7))<<3)]);
          aZ[j] = __builtin_amdgcn_mfma_f32_16x16x32_bf16(a, bZ, aZ[j], 0, 0, 0);
          bf16x8 bN = *reinterpret_cast<const bf16x8*>(&Wsb[nN*64 + ((k8 ^ (nN&7))<<3)]);
          aNX[j] = __builtin_amdgcn_mfma_f32_16x16x32_bf16(a, bN, aNX[j], 0, 0, 0);
        }
      }
    } else {
      #pragma unroll
      for (int ks = 0; ks < 2; ++ks) {
        int k8 = ks*4 + lk;
        bf16x8 a = *reinterpret_cast<const bf16x8*>(&Xsb[anode*64 + ((k8 ^ (anode&7))<<3)]);
        #pragma unroll
        for (int j = 0; j < 4; ++j) {
          int nR = (hb + j)*16 + lr;
          int nZ = nR + 128;
          int nN = nR + 256;
          bf16x8 bR = *reinterpret_cast<const bf16x8*>(&Wsb[nR*64 + ((k8 ^ (nR&7))<<3)]);
          aR[j] = __builtin_amdgcn_mfma_f32_16x16x32_bf16(a, bR, aR[j], 0, 0, 0);
          bf16x8 bZ = *reinterpret_cast<const bf16x8*>(&Wsb[nZ*64 + ((k8 ^ (nZ&7))<<3)]);
          aZ[j] = __builtin_amdgcn_mfma_f32_16x16x32_bf16(a, bZ, aZ[j], 0, 0, 0);
          bf16x8 bN = *reinterpret_cast<const bf16x8*>(&Wsb[nN*64 + ((k8 ^ (nN&7))<<3)]);
          aNM[j] = __builtin_amdgcn_mfma_f32_16x16x32_bf16(a, bN, aNM[j], 0, 0, 0);
        }
      }
    }
    __syncthreads();
  }

  #pragma unroll
  for (int j = 0; j < 4; ++j) {
    int h = (hb + j)*16 + lr;
    float br_ = bias4[h], bz_ = bias4[128+h], bnx_ = bias4[256+h], bnm_ = bias4[384+h];
    #pragma unroll
    for (int i = 0; i < 4; ++i) {
      int node = mb + lk*4 + i;
      float r  = sigf(aR[j][i] + br_);
      float z  = sigf(aZ[j][i] + bz_);
      float nv = tanhf_(aNX[j][i] + bnx_ + r*(aNM[j][i] + bnm_));
      float m  = memory[(size_t)sn_self[node]*HD + h];
      Mn[node*128 + h] = (1.f - z)*nv + z*m;
    }
  }
  __syncthreads();

  float acc2[4][4];
  #pragma unroll
  for (int a = 0; a < 4; ++a) {
    #pragma unroll
    for (int b = 0; b < 4; ++b) acc2[a][b] = 0.f;
  }
  for (int ch = 0; ch < 4; ++ch) {
    #pragma unroll
    for (int i = 0; i < 2; ++i) {
      int idx = tid + 512*i;               // exactly the 1024-quad W1 tile
      int o = idx >> 3, k4 = idx & 7;
      int k = ch*32 + k4*4;
      float4 w = (o < 64) ? ld4(W1 + (size_t)o*NG + k)
                          : ld4(W1 + (size_t)(o-64)*NG + 128 + k);
      *reinterpret_cast<float4*>(&W1s[o*32 + ((k4 ^ (o&7))<<2)]) = w;
    }
    __syncthreads();
    #pragma unroll
    for (int k4 = 0; k4 < 8; ++k4) {
      float4 xv[4];
      #pragma unroll
      for (int nn = 0; nn < 4; ++nn)
        xv[nn] = *reinterpret_cast<const float4*>(&Mn[(ty + 16*nn)*128 + ch*32 + k4*4]);
      #pragma unroll
      for (int og = 0; og < 4; ++og) {
        int o = tx + 32*og;
        float4 w = *reinterpret_cast<const float4*>(&W1s[o*32 + ((k4 ^ (o&7))<<2)]);
        #pragma unroll
        for (int nn = 0; nn < 4; ++nn) {
          acc2[nn][og] = fmaf(w.x, xv[nn].x, acc2[nn][og]);
          acc2[nn][og] = fmaf(w.y, xv[nn].y, acc2[nn][og]);
          acc2[nn][og] = fmaf(w.z, xv[nn].z, acc2[nn][og]);
          acc2[nn][og] = fmaf(w.w, xv[nn].w, acc2[nn][og]);
        }
      }
    }
    __syncthreads();
  }
  #pragma unroll
  for (int nn = 0; nn < 4; ++nn) {
    int nl = ty + 16*nn;
    if (base + nl < cnt) {
      int self = sn_self[nl];
      #pragma unroll
      for (int og = 0; og < 4; ++og)
        uv[(size_t)self*128 + tx + 32*og] = acc2[nn][og];
    }
  }
}

// ---------- price LSTM via bf16 MFMA: 64 edges/block, 4 waves x 16 edges ----------
// gates[16e][128] = h[16e][32] @ W_hh^T : 8 x mfma_16x16x32_bf16 per step.
// Lane l holds gates for edges (l>>4)*4+i, units {l&15, (l&15)+16}; c/h update is
// lane-local (fp32). h round-trips through wave-private LDS (stride 36) only to
// re-shape into the next step's A-fragment (bf16). No block barriers in step loop:
// wave-granular LDS + s_waitcnt lgkmcnt(0) (memory-clobber pins compiler order).
__global__ __launch_bounds__(256) void k_lstm(
    const float* __restrict__ price, const float* __restrict__ W_ihl,
    const float* __restrict__ W_hhl, const float* __restrict__ b_ihl,
    const float* __restrict__ b_hhl, float* __restrict__ hn_out)
{
  __shared__ short Wb[4096];      // W_hh bf16 [128 rows][32 k] = 8KB
  __shared__ float ps[64*50];     // 12.8KB price rows
  __shared__ float hbuf[4][576];  // per-wave h [16 e][stride 36] = 9.2KB
  int tid = threadIdx.x;
  int lane = tid & 63, wid = tid >> 6;
  int lr = lane & 15, lk = lane >> 4;

  // stage W_hh -> bf16 LDS (each thread: 16 consecutive fp32 -> 8 packed words)
  {
    int base = tid * 16;
    #pragma unroll
    for (int q = 0; q < 8; ++q) {
      float a = W_hhl[base + q*2], b = W_hhl[base + q*2 + 1];
      unsigned pk = (unsigned)(unsigned short)f2bf(a)
                  | ((unsigned)(unsigned short)f2bf(b) << 16);
      reinterpret_cast<unsigned*>(Wb)[tid*8 + q] = pk;
    }
  }
  // stage price rows (clamped tail)
  int ebase = blockIdx.x * 64;
  int m = NE - ebase; if (m > 64) m = 64;
  for (int i = tid; i < 64*50; i += 256) {
    int r = i / 50, cidx = i % 50;
    int rr = r < m ? r : m - 1;
    ps[i] = price[(size_t)(ebase + rr)*50 + cidx];
  }
  __syncthreads();

  // per-lane B-frags (W_hh rows t*16+lr, k = lk*8..+8) + x-weights/bias
  bf16x8 bw[8];
  float wih8[8], bias8[8];
  #pragma unroll
  for (int t = 0; t < 8; ++t) {
    int row = t*16 + lr;
    bw[t] = *reinterpret_cast<const bf16x8*>(&Wb[row*32 + lk*8]);
    wih8[t] = W_ihl[row];
    bias8[t] = b_ihl[row] + b_hhl[row];
  }

  int we = wid * 16;            // wave's edge base within block
  float* hb = hbuf[wid];

  float c8[4][2];
  #pragma unroll
  for (int i = 0; i < 4; ++i) { c8[i][0] = 0.f; c8[i][1] = 0.f; }
  bf16x8 afrag = {0,0,0,0,0,0,0,0};   // h_0 = 0

  #pragma unroll 1
  for (int s = 0; s < 50; ++s) {
    float xv[4];
    #pragma unroll
    for (int i = 0; i < 4; ++i) xv[i] = ps[(we + lk*4 + i)*50 + s];
    f32x4 acc[8];
    #pragma unroll
    for (int t = 0; t < 8; ++t) {
      f32x4 ci;
      #pragma unroll
      for (int i = 0; i < 4; ++i) ci[i] = fmaf(xv[i], wih8[t], bias8[t]);
      acc[t] = __builtin_amdgcn_mfma_f32_16x16x32_bf16(afrag, bw[t], ci, 0, 0, 0);
    }
    // tiles: 0,1=i  2,3=f  4,5=g  6,7=o ; lane: edge (lk*4+i), unit p*16+lr
    #pragma unroll
    for (int i = 0; i < 4; ++i) {
      #pragma unroll
      for (int p = 0; p < 2; ++p) {
        float ig = sigf(acc[0+p][i]);
        float fg = sigf(acc[2+p][i]);
        float gg = tanhf_(acc[4+p][i]);
        float og = sigf(acc[6+p][i]);
        c8[i][p] = fmaf(fg, c8[i][p], ig*gg);
        float h = og * tanhf_(c8[i][p]);
        hb[(lk*4 + i)*36 + p*16 + lr] = h;
      }
    }
    asm volatile("s_waitcnt lgkmcnt(0)" ::: "memory");
    // A-frag for next step: edge = lr, units lk*8..+8 (16B-aligned: 36%4==0)
    float4 h0 = *reinterpret_cast<const float4*>(&hb[lr*36 + lk*8]);
    float4 h1 = *reinterpret_cast<const float4*>(&hb[lr*36 + lk*8 + 4]);
    short hs[8];
    hs[0]=f2bf(h0.x); hs[1]=f2bf(h0.y); hs[2]=f2bf(h0.z); hs[3]=f2bf(h0.w);
    hs[4]=f2bf(h1.x); hs[5]=f2bf(h1.y); hs[6]=f2bf(h1.z); hs[7]=f2bf(h1.w);
    afrag = *reinterpret_cast<bf16x8*>(hs);
  }

  // store h_n (fp32 from hbuf): lane -> edge lr, units lk*8..+8
  int e_g = ebase + we + lr;
  if (e_g < NE) {
    float4 h0 = *reinterpret_cast<const float4*>(&hb[lr*36 + lk*8]);
    float4 h1 = *reinterpret_cast<const float4*>(&hb[lr*36 + lk*8 + 4]);
    *reinterpret_cast<float4*>(hn_out + (size_t)e_g*32 + lk*8)     = h0;
    *reinterpret_cast<float4*>(hn_out + (size_t)e_g*32 + lk*8 + 4) = h1;
  }
}

// ---------- fused output: out = W2 @ relu(u[s] + v[d] + A@sf + B@hn + c0) + b2 ----------
__global__ __launch_bounds__(256) void k_final(
    const int* __restrict__ src, const int* __restrict__ dst, const int* __restrict__ xst,
    const float* __restrict__ party, const float* __restrict__ state,
    const float* __restrict__ uv, const float* __restrict__ hn,
    const float* __restrict__ A, const float* __restrict__ B, const float* __restrict__ c0,
    const float* __restrict__ W2, const float* __restrict__ b2, float* __restrict__ out)
{
  __shared__ float As[2048], Bs[2048], c0s[64], W2s[64];
  int tid = threadIdx.x;
  for (int i = tid; i < 2048; i += 256) { As[i] = A[i]; Bs[i] = B[i]; }
  if (tid < 64) { c0s[tid] = c0[tid]; W2s[tid] = W2[tid]; }
  __syncthreads();
  int e = blockIdx.x*256 + tid;
  if (e >= NE) return;
  int s = src[e], d = dst[e];
  int p = xst[2*s], stt = xst[2*s + 1];
  float4 sf4[8], hv4[8];
  #pragma unroll
  for (int i = 0; i < 4; ++i) sf4[i]   = ld4(party + p*16 + i*4);
  #pragma unroll
  for (int i = 0; i < 4; ++i) sf4[4+i] = ld4(state + stt*16 + i*4);
  #pragma unroll
  for (int i = 0; i < 8; ++i) hv4[i] = ld4(hn + (size_t)e*32 + i*4);
  const float* urow = uv + (size_t)s*128;
  const float* vrow = uv + (size_t)d*128 + 64;
  float oacc = b2[0];
  #pragma unroll 4
  for (int o4 = 0; o4 < 16; ++o4) {
    float4 u4 = ld4(urow + o4*4);
    float4 v4 = ld4(vrow + o4*4);
    float4 cc = *reinterpret_cast<const float4*>(&c0s[o4*4]);
    float4 w2 = *reinterpret_cast<const float4*>(&W2s[o4*4]);
    float hh[4] = {u4.x+v4.x+cc.x, u4.y+v4.y+cc.y, u4.z+v4.z+cc.z, u4.w+v4.w+cc.w};
    #pragma unroll
    for (int oo = 0; oo < 4; ++oo) {
      int o = o4*4 + oo;
      float acc = hh[oo];
      #pragma unroll
      for (int j4 = 0; j4 < 8; ++j4) {
        float4 a = *reinterpret_cast<const float4*>(&As[o*32 + j4*4]);
        float4 b = *reinterpret_cast<const float4*>(&Bs[o*32 + j4*4]);
        float4 sfv = sf4[j4], hvv = hv4[j4];
        acc = fmaf(a.x,sfv.x, fmaf(a.y,sfv.y, fmaf(a.z,sfv.z, fmaf(a.w,sfv.w, acc))));
        acc = fmaf(b.x,hvv.x, fmaf(b.y,hvv.y, fmaf(b.z,hvv.z, fmaf(b.w,hvv.w, acc))));
      }
      float w2v = (oo==0) ? w2.x : (oo==1) ? w2.y : (oo==2) ? w2.z : w2.w;
      oacc = fmaf(w2v, fmaxf(acc, 0.f), oacc);
    }
  }
  out[e] = oacc;
}

extern "C" void kernel_launch(void* const* d_in, const int* in_sizes, int n_in,
                              void* d_out, int out_size, void* d_ws, size_t ws_size,
                              hipStream_t stream) {
  const int*   src   = (const int*)d_in[0];
  const int*   dst   = (const int*)d_in[1];
  const int*   t     = (const int*)d_in[2];
  const float* msg   = (const float*)d_in[3];
  const float* price = (const float*)d_in[4];
  // d_in[5] trade_t: unused by reference
  const int*   xst   = (const int*)d_in[6];
  const float* memory= (const float*)d_in[7];
  const float* lu    = (const float*)d_in[8];
  const float* w_t   = (const float*)d_in[9];
  const float* b_t   = (const float*)d_in[10];
  const float* W_ih  = (const float*)d_in[11];
  const float* b_ih  = (const float*)d_in[12];
  const float* W_hh  = (const float*)d_in[13];
  const float* b_hh  = (const float*)d_in[14];
  const float* party = (const float*)d_in[15];
  const float* state = (const float*)d_in[16];
  const float* W_sp  = (const float*)d_in[17];
  const float* b_sp  = (const float*)d_in[18];
  const float* W_ihl = (const float*)d_in[19];
  const float* W_hhl = (const float*)d_in[20];
  const float* b_ihl = (const float*)d_in[21];
  const float* b_hhl = (const float*)d_in[22];
  const float* W_pp  = (const float*)d_in[23];
  const float* b_pp  = (const float*)d_in[24];
  const float* W1    = (const float*)d_in[25];
  const float* b1    = (const float*)d_in[26];
  const float* W2    = (const float*)d_in[27];
  const float* b2    = (const float*)d_in[28];
  float* out = (float*)d_out;

  if (ws_size < WS_NEED) {              // loud failure: zero output
    (void)hipMemsetAsync(d_out, 0, (size_t)out_size*4, stream);
    return;
  }

  char* ws = (char*)d_ws;
  u64*   key  = (u64*)(ws + OFF_KEY);
  int*   cnt  = (int*)(ws + OFF_CNT);
  int*   list = (int*)(ws + OFF_LIST);
  float* uv   = (float*)(ws + OFF_UV);
  float* hn   = (float*)(ws + OFF_HN);
  float* A    = (float*)(ws + OFF_A);
  float* B    = (float*)(ws + OFF_B);
  float* c0   = (float*)(ws + OFF_C0);
  short* Wbf  = (short*)(ws + OFF_WBF);

  (void)hipMemsetAsync(ws, 0, OFF_LIST, stream);   // zero key[] + count
  k_scatter<<<(NE+255)/256, 256, 0, stream>>>(src, dst, t, key);
  k_compact<<<(NN+255)/256, 256, 0, stream>>>(key, list, cnt);
  k_pre<<<17, 256, 0, stream>>>(W1, W_sp, W_pp, b_sp, b_pp, b1, A, B, c0);
  k_prew<<<108, 256, 0, stream>>>(W_ih, W_hh, Wbf);
  k_lstm<<<(NE+63)/64, 256, 0, stream>>>(price, W_ihl, W_hhl, b_ihl, b_hhl, hn);
  k_gru<<<(NN+63)/64, 512, 0, stream>>>(key, list, cnt, src, dst, t, msg, memory, lu,
                                        w_t, b_t, Wbf, b_ih, b_hh, W1, uv);
  k_final<<<(NE+255)/256, 256, 0, stream>>>(src, dst, xst, party, state, uv, hn,
                                            A, B, c0, W2, b2, out);
}

// Round 15
// 617.579 us; speedup vs baseline: 3.7252x; 1.0180x over previous
//
#include <hip/hip_runtime.h>
#include <stdint.h>

#define NN    200000   // nodes
#define NE    100000   // edges
#define HD    128      // hidden/memory/time dim
#define EFD   64       // edge feat dim
#define NG    384      // 3*HD gates

typedef unsigned long long u64;
typedef short bf16x8 __attribute__((ext_vector_type(8)));   // 8 bf16 (4 VGPRs)
typedef float f32x4  __attribute__((ext_vector_type(4)));   // MFMA C/D frag

// ---- ws layout (bytes) ----
#define OFF_KEY   ((size_t)0)            // u64 * NN = 1,600,000
#define OFF_CNT   ((size_t)1600000)      // int
#define OFF_LIST  ((size_t)1600256)      // int * NN = 800,000
#define OFF_UV    ((size_t)2400256)      // float * NN*128 = 102,400,000
#define OFF_HN    ((size_t)104800256)    // float * NE*32 = 12,800,000
#define OFF_A     ((size_t)117600256)    // float * 2048
#define OFF_B     ((size_t)117608448)    // float * 2048
#define OFF_C0    ((size_t)117616640)    // float * 64 (+pad)
#define OFF_WBF   ((size_t)117616896)    // short * 9*384*64 = 442,368 B (bf16 W, pre-swizzled)
#define WS_NEED   ((size_t)118059264)

__device__ __forceinline__ float frcp(float x){ return __builtin_amdgcn_rcpf(x); }
__device__ __forceinline__ float sigf(float x){ return frcp(1.f + __expf(-x)); }
__device__ __forceinline__ float tanhf_(float x){ return 1.f - 2.f*frcp(__expf(2.f*x) + 1.f); }
__device__ __forceinline__ float4 ld4(const float* p){ return *reinterpret_cast<const float4*>(p); }

// fp32 -> bf16 RNE (bit math; inputs finite)
__device__ __forceinline__ short f2bf(float f){
  unsigned u = __float_as_uint(f);
  u += 0x7fffu + ((u>>16)&1u);
  return (short)(u>>16);
}

// async global->LDS, 16B per lane; LDS dest = (first lane's ptr) + lane*16.
__device__ __forceinline__ void gl16(const void* g, void* l) {
  __builtin_amdgcn_global_load_lds(
      (const __attribute__((address_space(1))) void*)g,
      (__attribute__((address_space(3))) void*)l, 16, 0, 0);
}

// ---------- per-node winner key: max (t, isDst, e) ----------
__global__ void k_scatter(const int* __restrict__ src, const int* __restrict__ dst,
                          const int* __restrict__ t, u64* __restrict__ key) {
  int e = blockIdx.x*256 + threadIdx.x;
  if (e >= NE) return;
  u64 tt = (u64)(unsigned)(t[e] + 1);
  atomicMax(&key[src[e]], (tt<<18) | (u64)(unsigned)e);
  atomicMax(&key[dst[e]], (tt<<18) | (1ULL<<17) | (u64)(unsigned)e);
}

__global__ void k_compact(const u64* __restrict__ key, int* __restrict__ list,
                          int* __restrict__ count) {
  int n = blockIdx.x*256 + threadIdx.x;
  if (n >= NN) return;
  if (key[n] != 0ULL) { int p = atomicAdd(count, 1); list[p] = n; }
}

// ---------- fold W1/W_sp/W_pp/biases: A=W1a@W_sp, B=(W1b+W1c)@W_pp, c0 ----------
__global__ void k_pre(const float* __restrict__ W1, const float* __restrict__ W_sp,
                      const float* __restrict__ W_pp, const float* __restrict__ b_sp,
                      const float* __restrict__ b_pp, const float* __restrict__ b1,
                      float* __restrict__ A, float* __restrict__ B, float* __restrict__ c0)
{
  int tid = blockIdx.x*256 + threadIdx.x;
  if (tid < 2048) {
    int o = tid >> 5, j = tid & 31;
    float s = 0.f;
    for (int k = 0; k < 128; ++k) s = fmaf(W1[o*NG + k], W_sp[k*32 + j], s);
    A[tid] = s;
  } else if (tid < 4096) {
    int q = tid - 2048;
    int o = q >> 5, j = q & 31;
    float s = 0.f;
    for (int k = 0; k < 128; ++k)
      s = fmaf(W1[o*NG + 128 + k] + W1[o*NG + 256 + k], W_pp[k*32 + j], s);
    B[q] = s;
  } else if (tid < 4160) {
    int o = tid - 4096;
    float s = b1[o];
    for (int k = 0; k < 128; ++k) {
      s = fmaf(W1[o*NG + k], b_sp[k], s);
      s = fmaf(W1[o*NG + 128 + k] + W1[o*NG + 256 + k], b_pp[k], s);
    }
    c0[o] = s;
  }
}

// ---------- pre-convert GRU weights to bf16, pre-swizzled for gl16 staging ----------
__global__ void k_prew(const float* __restrict__ W_ih, const float* __restrict__ W_hh,
                       short* __restrict__ Wbf)
{
  int idx = blockIdx.x*256 + threadIdx.x;
  if (idx >= 9*384*8) return;
  int s   = idx & 7;
  int n   = (idx >> 3) % 384;
  int ch9 = idx / (384*8);
  int k8  = s ^ (n & 7);
  int k   = ch9*64 + k8*8;
  short v[8];
  #pragma unroll
  for (int e = 0; e < 8; ++e) {
    int kk = k + e;
    float f = (kk < 448) ? W_ih[(size_t)n*448 + kk] : W_hh[(size_t)n*HD + (kk-448)];
    v[e] = f2bf(f);
  }
  *reinterpret_cast<bf16x8*>(Wbf + (size_t)ch9*24576 + n*64 + s*8) =
      *reinterpret_cast<bf16x8*>(v);
}

// ---------- GRU via bf16 MFMA, pipelined: 64 nodes/block, 512 thr = 8 waves ----------
// R15: chunk order (0,7),(1,8),2..6 — pairs share X (chunks 7,8 are bit-identical X
// to 0,1: memory[self][0..127]); X gather for next phase issued AFTER barrier1 so it
// flies under the MFMA compute (T14). W chunk ids stay as stored in Wbf.
__global__ __launch_bounds__(512, 2) void k_gru(
    const u64* __restrict__ key, const int* __restrict__ list, const int* __restrict__ count,
    const int* __restrict__ src, const int* __restrict__ dst, const int* __restrict__ t,
    const float* __restrict__ msg, const float* __restrict__ memory,
    const float* __restrict__ last_update,
    const float* __restrict__ w_t, const float* __restrict__ b_t,
    const short* __restrict__ Wbf, const float* __restrict__ b_ih,
    const float* __restrict__ b_hh, const float* __restrict__ W1,
    float* __restrict__ uv)
{
  __shared__ short Wsb[24576];    // 48KB: W chunk [384 n][8 slots][8 bf16]
  __shared__ short Xsb[4096];     // 8KB: X chunk [64 node][8 slots][8 bf16]
  __shared__ float bias4[512];    // br|bz|bnx|bnm per h
  __shared__ int   sn_self[64];
  __shared__ int   sn_other[64];
  __shared__ int   sn_e[64];
  __shared__ float sn_dt[64];

  float* Mn  = reinterpret_cast<float*>(&Wsb[8192]);  // [64][128] fp32, bytes 16K..48K
  float* W1s = reinterpret_cast<float*>(&Wsb[0]);     // 4096 floats for uv staging

  int cnt = count[0];
  int base = blockIdx.x * 64;
  if (base >= cnt) return;
  int tid = threadIdx.x;
  int tx = tid & 31, ty = tid >> 5;      // for uv epilogue (16 ty-groups)
  int wid = tid >> 6, lane = tid & 63;
  int lr = lane & 15, lk = lane >> 4;    // fragment row/col & k-group
  int mb = (wid & 3) * 16;               // M-tile node base
  int hb = (wid >> 2) * 4;               // h-tile base (4 tiles = 64 h)

  if (tid < 64) {
    int idx = base + tid;
    int cl = idx < cnt ? idx : (cnt - 1);
    int n = list[cl];
    u64 k = key[n];
    int e   = (int)(k & 0x1FFFFULL);
    int isd = (int)((k >> 17) & 1ULL);
    sn_self[tid]  = n;
    sn_other[tid] = isd ? src[e] : dst[e];
    sn_e[tid]     = e;
    sn_dt[tid]    = (float)t[e] - last_update[n];
  }
  if (tid < 128) {
    int h = tid;
    bias4[h]       = b_ih[h]       + b_hh[h];
    bias4[128 + h] = b_ih[128 + h] + b_hh[128 + h];
    bias4[256 + h] = b_ih[256 + h];
    bias4[384 + h] = b_hh[256 + h];
  }
  __syncthreads();

  f32x4 aR[4], aZ[4], aNX[4], aNM[4];
  #pragma unroll
  for (int j = 0; j < 4; ++j) { aR[j] = (f32x4)0.f; aZ[j] = (f32x4)0.f;
                                aNX[j] = (f32x4)0.f; aNM[j] = (f32x4)0.f; }

  int node8 = tid >> 3, k8s = tid & 7;   // staging coords
  // gather source row for X chunk xch (0..4); chunks 5,6 are cos (no gather)
  auto srcp = [&](int xch) -> const float* {
    if (xch <= 1)      return memory + (size_t)sn_self[node8]*HD  + (xch==1 ? 64 : 0) + k8s*8;
    else if (xch <= 3) return memory + (size_t)sn_other[node8]*HD + (xch==3 ? 64 : 0) + k8s*8;
    else               return msg + (size_t)sn_e[node8]*EFD + k8s*8;
  };

  // phase tables: W chunk id; X to stage (-1 reuse, -2 cos); X to issue mid-phase
  constexpr int WCH[9] = {0, 7, 1, 8, 2, 3, 4, 5, 6};
  constexpr int XST[9] = {0,-1, 1,-1, 2, 3, 4,-2,-2};
  constexpr int XIS[9] = {1,-9, 2,-9, 3, 4,-9,-9,-9};

  float4 xfA, xfB;
  { const float* p = srcp(0); xfA = ld4(p); xfB = ld4(p+4); }   // prologue: X for phase 0

  #pragma unroll
  for (int p = 0; p < 9; ++p) {
    const int W = WCH[p];
    // W chunk: 3072 x 16B via gl16, zero data regs
    #pragma unroll
    for (int i = 0; i < 6; ++i) {
      int q = i*512 + tid;
      gl16(Wbf + (size_t)W*24576 + q*8, &Wsb[q*8]);
    }
    if (XST[p] >= 0) {
      short xs[8];
      xs[0]=f2bf(xfA.x); xs[1]=f2bf(xfA.y); xs[2]=f2bf(xfA.z); xs[3]=f2bf(xfA.w);
      xs[4]=f2bf(xfB.x); xs[5]=f2bf(xfB.y); xs[6]=f2bf(xfB.z); xs[7]=f2bf(xfB.w);
      *reinterpret_cast<bf16x8*>(&Xsb[node8*64 + ((k8s ^ (node8&7))<<3)]) =
          *reinterpret_cast<bf16x8*>(xs);
    } else if (XST[p] == -2) {
      int kk = (W == 6 ? 64 : 0) + k8s*8;
      float dt = sn_dt[node8];
      short xs[8];
      #pragma unroll
      for (int q = 0; q < 8; ++q) xs[q] = f2bf(cosf(fmaf(dt, w_t[kk+q], b_t[kk+q])));
      *reinterpret_cast<bf16x8*>(&Xsb[node8*64 + ((k8s ^ (node8&7))<<3)]) =
          *reinterpret_cast<bf16x8*>(xs);
    }
    __syncthreads();   // Wsb (gl16 drained) + Xsb ready

    if (XIS[p] >= 0) { const float* q = srcp(XIS[p]); xfA = ld4(q); xfB = ld4(q+4); }

    int anode = mb + lr;
    #pragma unroll
    for (int ks = 0; ks < 2; ++ks) {
      int k8 = ks*4 + lk;
      bf16x8 a = *reinterpret_cast<const bf16x8*>(&Xsb[anode*64 + ((k8 ^ (anode&7))<<3)]);
      #pragma unroll
      for (int j = 0; j < 4; ++j) {
        int nR = (hb + j)*16 + lr;
        int nZ = nR + 128;
        int nN = nR + 256;
        bf16x8 bR = *reinterpret_cast<const bf16x8*>(&Wsb[nR*64 + ((k8 ^ (nR&7))<<3)]);
        aR[j] = __builtin_amdgcn_mfma_f32_16x16x32_bf16(a, bR, aR[j], 0, 0, 0);
        bf16x8 bZ = *reinterpret_cast<const bf16x8*>(&Wsb[nZ*64 + ((k8 ^ (nZ&7))<<3)]);
        aZ[j] = __builtin_amdgcn_mfma_f32_16x16x32_bf16(a, bZ, aZ[j], 0, 0, 0);
        bf16x8 bN = *reinterpret_cast<const bf16x8*>(&Wsb[nN*64 + ((k8 ^ (nN&7))<<3)]);
        if (W < 7) aNX[j] = __builtin_amdgcn_mfma_f32_16x16x32_bf16(a, bN, aNX[j], 0, 0, 0);
        else       aNM[j] = __builtin_amdgcn_mfma_f32_16x16x32_bf16(a, bN, aNM[j], 0, 0, 0);
      }
    }
    __syncthreads();   // all reads of Wsb/Xsb done before next stage
  }

  // ---- GRU nonlinearity, lane-local; Mn overlays Wsb[16K..48K) ----
  #pragma unroll
  for (int j = 0; j < 4; ++j) {
    int h = (hb + j)*16 + lr;
    float br_ = bias4[h], bz_ = bias4[128+h], bnx_ = bias4[256+h], bnm_ = bias4[384+h];
    #pragma unroll
    for (int i = 0; i < 4; ++i) {
      int node = mb + lk*4 + i;
      float r  = sigf(aR[j][i] + br_);
      float z  = sigf(aZ[j][i] + bz_);
      float nv = tanhf_(aNX[j][i] + bnx_ + r*(aNM[j][i] + bnm_));
      float m  = memory[(size_t)sn_self[node]*HD + h];
      Mn[node*128 + h] = (1.f - z)*nv + z*m;
    }
  }
  __syncthreads();

  // ---- uv = [W1a@mn | W1b@mn] fp32: K=128 in 4 chunks; W1 staged at W1s ----
  float acc2[4][4];
  #pragma unroll
  for (int a = 0; a < 4; ++a) {
    #pragma unroll
    for (int b = 0; b < 4; ++b) acc2[a][b] = 0.f;
  }
  for (int ch = 0; ch < 4; ++ch) {
    #pragma unroll
    for (int i = 0; i < 2; ++i) {
      int idx = tid + 512*i;               // exactly the 1024-quad W1 tile
      int o = idx >> 3, k4 = idx & 7;
      int k = ch*32 + k4*4;
      float4 w = (o < 64) ? ld4(W1 + (size_t)o*NG + k)
                          : ld4(W1 + (size_t)(o-64)*NG + 128 + k);
      *reinterpret_cast<float4*>(&W1s[o*32 + ((k4 ^ (o&7))<<2)]) = w;
    }
    __syncthreads();
    #pragma unroll
    for (int k4 = 0; k4 < 8; ++k4) {
      float4 xv[4];
      #pragma unroll
      for (int nn = 0; nn < 4; ++nn)
        xv[nn] = *reinterpret_cast<const float4*>(&Mn[(ty + 16*nn)*128 + ch*32 + k4*4]);
      #pragma unroll
      for (int og = 0; og < 4; ++og) {
        int o = tx + 32*og;
        float4 w = *reinterpret_cast<const float4*>(&W1s[o*32 + ((k4 ^ (o&7))<<2)]);
        #pragma unroll
        for (int nn = 0; nn < 4; ++nn) {
          acc2[nn][og] = fmaf(w.x, xv[nn].x, acc2[nn][og]);
          acc2[nn][og] = fmaf(w.y, xv[nn].y, acc2[nn][og]);
          acc2[nn][og] = fmaf(w.z, xv[nn].z, acc2[nn][og]);
          acc2[nn][og] = fmaf(w.w, xv[nn].w, acc2[nn][og]);
        }
      }
    }
    __syncthreads();
  }
  #pragma unroll
  for (int nn = 0; nn < 4; ++nn) {
    int nl = ty + 16*nn;
    if (base + nl < cnt) {
      int self = sn_self[nl];
      #pragma unroll
      for (int og = 0; og < 4; ++og)
        uv[(size_t)self*128 + tx + 32*og] = acc2[nn][og];
    }
  }
}

// ---------- price LSTM via bf16 MFMA: 64 edges/block, 4 waves x 16 edges ----------
__global__ __launch_bounds__(256) void k_lstm(
    const float* __restrict__ price, const float* __restrict__ W_ihl,
    const float* __restrict__ W_hhl, const float* __restrict__ b_ihl,
    const float* __restrict__ b_hhl, float* __restrict__ hn_out)
{
  __shared__ short Wb[4096];      // W_hh bf16 [128 rows][32 k] = 8KB
  __shared__ float ps[64*50];     // 12.8KB price rows
  __shared__ float hbuf[4][576];  // per-wave h [16 e][stride 36] = 9.2KB
  int tid = threadIdx.x;
  int lane = tid & 63, wid = tid >> 6;
  int lr = lane & 15, lk = lane >> 4;

  {
    int base = tid * 16;
    #pragma unroll
    for (int q = 0; q < 8; ++q) {
      float a = W_hhl[base + q*2], b = W_hhl[base + q*2 + 1];
      unsigned pk = (unsigned)(unsigned short)f2bf(a)
                  | ((unsigned)(unsigned short)f2bf(b) << 16);
      reinterpret_cast<unsigned*>(Wb)[tid*8 + q] = pk;
    }
  }
  int ebase = blockIdx.x * 64;
  int m = NE - ebase; if (m > 64) m = 64;
  for (int i = tid; i < 64*50; i += 256) {
    int r = i / 50, cidx = i % 50;
    int rr = r < m ? r : m - 1;
    ps[i] = price[(size_t)(ebase + rr)*50 + cidx];
  }
  __syncthreads();

  bf16x8 bw[8];
  float wih8[8], bias8[8];
  #pragma unroll
  for (int t = 0; t < 8; ++t) {
    int row = t*16 + lr;
    bw[t] = *reinterpret_cast<const bf16x8*>(&Wb[row*32 + lk*8]);
    wih8[t] = W_ihl[row];
    bias8[t] = b_ihl[row] + b_hhl[row];
  }

  int we = wid * 16;
  float* hb = hbuf[wid];

  float c8[4][2];
  #pragma unroll
  for (int i = 0; i < 4; ++i) { c8[i][0] = 0.f; c8[i][1] = 0.f; }
  bf16x8 afrag = {0,0,0,0,0,0,0,0};

  #pragma unroll 1
  for (int s = 0; s < 50; ++s) {
    float xv[4];
    #pragma unroll
    for (int i = 0; i < 4; ++i) xv[i] = ps[(we + lk*4 + i)*50 + s];
    f32x4 acc[8];
    #pragma unroll
    for (int t = 0; t < 8; ++t) {
      f32x4 ci;
      #pragma unroll
      for (int i = 0; i < 4; ++i) ci[i] = fmaf(xv[i], wih8[t], bias8[t]);
      acc[t] = __builtin_amdgcn_mfma_f32_16x16x32_bf16(afrag, bw[t], ci, 0, 0, 0);
    }
    #pragma unroll
    for (int i = 0; i < 4; ++i) {
      #pragma unroll
      for (int p = 0; p < 2; ++p) {
        float ig = sigf(acc[0+p][i]);
        float fg = sigf(acc[2+p][i]);
        float gg = tanhf_(acc[4+p][i]);
        float og = sigf(acc[6+p][i]);
        c8[i][p] = fmaf(fg, c8[i][p], ig*gg);
        float h = og * tanhf_(c8[i][p]);
        hb[(lk*4 + i)*36 + p*16 + lr] = h;
      }
    }
    asm volatile("s_waitcnt lgkmcnt(0)" ::: "memory");
    float4 h0 = *reinterpret_cast<const float4*>(&hb[lr*36 + lk*8]);
    float4 h1 = *reinterpret_cast<const float4*>(&hb[lr*36 + lk*8 + 4]);
    short hs[8];
    hs[0]=f2bf(h0.x); hs[1]=f2bf(h0.y); hs[2]=f2bf(h0.z); hs[3]=f2bf(h0.w);
    hs[4]=f2bf(h1.x); hs[5]=f2bf(h1.y); hs[6]=f2bf(h1.z); hs[7]=f2bf(h1.w);
    afrag = *reinterpret_cast<bf16x8*>(hs);
  }

  int e_g = ebase + we + lr;
  if (e_g < NE) {
    float4 h0 = *reinterpret_cast<const float4*>(&hb[lr*36 + lk*8]);
    float4 h1 = *reinterpret_cast<const float4*>(&hb[lr*36 + lk*8 + 4]);
    *reinterpret_cast<float4*>(hn_out + (size_t)e_g*32 + lk*8)     = h0;
    *reinterpret_cast<float4*>(hn_out + (size_t)e_g*32 + lk*8 + 4) = h1;
  }
}

// ---------- fused output: out = W2 @ relu(u[s] + v[d] + A@sf + B@hn + c0) + b2 ----------
__global__ __launch_bounds__(256) void k_final(
    const int* __restrict__ src, const int* __restrict__ dst, const int* __restrict__ xst,
    const float* __restrict__ party, const float* __restrict__ state,
    const float* __restrict__ uv, const float* __restrict__ hn,
    const float* __restrict__ A, const float* __restrict__ B, const float* __restrict__ c0,
    const float* __restrict__ W2, const float* __restrict__ b2, float* __restrict__ out)
{
  __shared__ float As[2048], Bs[2048], c0s[64], W2s[64];
  int tid = threadIdx.x;
  for (int i = tid; i < 2048; i += 256) { As[i] = A[i]; Bs[i] = B[i]; }
  if (tid < 64) { c0s[tid] = c0[tid]; W2s[tid] = W2[tid]; }
  __syncthreads();
  int e = blockIdx.x*256 + tid;
  if (e >= NE) return;
  int s = src[e], d = dst[e];
  int p = xst[2*s], stt = xst[2*s + 1];
  float4 sf4[8], hv4[8];
  #pragma unroll
  for (int i = 0; i < 4; ++i) sf4[i]   = ld4(party + p*16 + i*4);
  #pragma unroll
  for (int i = 0; i < 4; ++i) sf4[4+i] = ld4(state + stt*16 + i*4);
  #pragma unroll
  for (int i = 0; i < 8; ++i) hv4[i] = ld4(hn + (size_t)e*32 + i*4);
  const float* urow = uv + (size_t)s*128;
  const float* vrow = uv + (size_t)d*128 + 64;
  float oacc = b2[0];
  #pragma unroll 4
  for (int o4 = 0; o4 < 16; ++o4) {
    float4 u4 = ld4(urow + o4*4);
    float4 v4 = ld4(vrow + o4*4);
    float4 cc = *reinterpret_cast<const float4*>(&c0s[o4*4]);
    float4 w2 = *reinterpret_cast<const float4*>(&W2s[o4*4]);
    float hh[4] = {u4.x+v4.x+cc.x, u4.y+v4.y+cc.y, u4.z+v4.z+cc.z, u4.w+v4.w+cc.w};
    #pragma unroll
    for (int oo = 0; oo < 4; ++oo) {
      int o = o4*4 + oo;
      float acc = hh[oo];
      #pragma unroll
      for (int j4 = 0; j4 < 8; ++j4) {
        float4 a = *reinterpret_cast<const float4*>(&As[o*32 + j4*4]);
        float4 b = *reinterpret_cast<const float4*>(&Bs[o*32 + j4*4]);
        float4 sfv = sf4[j4], hvv = hv4[j4];
        acc = fmaf(a.x,sfv.x, fmaf(a.y,sfv.y, fmaf(a.z,sfv.z, fmaf(a.w,sfv.w, acc))));
        acc = fmaf(b.x,hvv.x, fmaf(b.y,hvv.y, fmaf(b.z,hvv.z, fmaf(b.w,hvv.w, acc))));
      }
      float w2v = (oo==0) ? w2.x : (oo==1) ? w2.y : (oo==2) ? w2.z : w2.w;
      oacc = fmaf(w2v, fmaxf(acc, 0.f), oacc);
    }
  }
  out[e] = oacc;
}

extern "C" void kernel_launch(void* const* d_in, const int* in_sizes, int n_in,
                              void* d_out, int out_size, void* d_ws, size_t ws_size,
                              hipStream_t stream) {
  const int*   src   = (const int*)d_in[0];
  const int*   dst   = (const int*)d_in[1];
  const int*   t     = (const int*)d_in[2];
  const float* msg   = (const float*)d_in[3];
  const float* price = (const float*)d_in[4];
  // d_in[5] trade_t: unused by reference
  const int*   xst   = (const int*)d_in[6];
  const float* memory= (const float*)d_in[7];
  const float* lu    = (const float*)d_in[8];
  const float* w_t   = (const float*)d_in[9];
  const float* b_t   = (const float*)d_in[10];
  const float* W_ih  = (const float*)d_in[11];
  const float* b_ih  = (const float*)d_in[12];
  const float* W_hh  = (const float*)d_in[13];
  const float* b_hh  = (const float*)d_in[14];
  const float* party = (const float*)d_in[15];
  const float* state = (const float*)d_in[16];
  const float* W_sp  = (const float*)d_in[17];
  const float* b_sp  = (const float*)d_in[18];
  const float* W_ihl = (const float*)d_in[19];
  const float* W_hhl = (const float*)d_in[20];
  const float* b_ihl = (const float*)d_in[21];
  const float* b_hhl = (const float*)d_in[22];
  const float* W_pp  = (const float*)d_in[23];
  const float* b_pp  = (const float*)d_in[24];
  const float* W1    = (const float*)d_in[25];
  const float* b1    = (const float*)d_in[26];
  const float* W2    = (const float*)d_in[27];
  const float* b2    = (const float*)d_in[28];
  float* out = (float*)d_out;

  if (ws_size < WS_NEED) {              // loud failure: zero output
    (void)hipMemsetAsync(d_out, 0, (size_t)out_size*4, stream);
    return;
  }

  char* ws = (char*)d_ws;
  u64*   key  = (u64*)(ws + OFF_KEY);
  int*   cnt  = (int*)(ws + OFF_CNT);
  int*   list = (int*)(ws + OFF_LIST);
  float* uv   = (float*)(ws + OFF_UV);
  float* hn   = (float*)(ws + OFF_HN);
  float* A    = (float*)(ws + OFF_A);
  float* B    = (float*)(ws + OFF_B);
  float* c0   = (float*)(ws + OFF_C0);
  short* Wbf  = (short*)(ws + OFF_WBF);

  (void)hipMemsetAsync(ws, 0, OFF_LIST, stream);   // zero key[] + count
  k_scatter<<<(NE+255)/256, 256, 0, stream>>>(src, dst, t, key);
  k_compact<<<(NN+255)/256, 256, 0, stream>>>(key, list, cnt);
  k_pre<<<17, 256, 0, stream>>>(W1, W_sp, W_pp, b_sp, b_pp, b1, A, B, c0);
  k_prew<<<108, 256, 0, stream>>>(W_ih, W_hh, Wbf);
  k_lstm<<<(NE+63)/64, 256, 0, stream>>>(price, W_ihl, W_hhl, b_ihl, b_hhl, hn);
  k_gru<<<(NN+63)/64, 512, 0, stream>>>(key, list, cnt, src, dst, t, msg, memory, lu,
                                        w_t, b_t, Wbf, b_ih, b_hh, W1, uv);
  k_final<<<(NE+255)/256, 256, 0, stream>>>(src, dst, xst, party, state, uv, hn,
                                            A, B, c0, W2, b2, out);
}

// Round 16
// 613.809 us; speedup vs baseline: 3.7481x; 1.0061x over previous
//
#include <hip/hip_runtime.h>
#include <stdint.h>

#define NN    200000   // nodes
#define NE    100000   // edges
#define HD    128      // hidden/memory/time dim
#define EFD   64       // edge feat dim
#define NG    384      // 3*HD gates

typedef unsigned long long u64;
typedef short bf16x8 __attribute__((ext_vector_type(8)));   // 8 bf16 (4 VGPRs)
typedef float f32x4  __attribute__((ext_vector_type(4)));   // MFMA C/D frag

// ---- ws layout (bytes) ----
#define OFF_KEY   ((size_t)0)            // u64 * NN = 1,600,000
#define OFF_CNT   ((size_t)1600000)      // int
#define OFF_LIST  ((size_t)1600256)      // int * NN = 800,000
#define OFF_UV    ((size_t)2400256)      // float * NN*128 = 102,400,000
#define OFF_HN    ((size_t)104800256)    // float * NE*32 = 12,800,000
#define OFF_A     ((size_t)117600256)    // float * 2048
#define OFF_B     ((size_t)117608448)    // float * 2048
#define OFF_C0    ((size_t)117616640)    // float * 64 (+pad)
#define OFF_WBF   ((size_t)117616896)    // short * 9*384*64 = 442,368 B (bf16 W, pre-swizzled)
#define WS_NEED   ((size_t)118059264)

__device__ __forceinline__ float frcp(float x){ return __builtin_amdgcn_rcpf(x); }
__device__ __forceinline__ float sigf(float x){ return frcp(1.f + __expf(-x)); }
__device__ __forceinline__ float tanhf_(float x){ return 1.f - 2.f*frcp(__expf(2.f*x) + 1.f); }
__device__ __forceinline__ float4 ld4(const float* p){ return *reinterpret_cast<const float4*>(p); }

// fp32 -> bf16 RNE (bit math; inputs finite)
__device__ __forceinline__ short f2bf(float f){
  unsigned u = __float_as_uint(f);
  u += 0x7fffu + ((u>>16)&1u);
  return (short)(u>>16);
}

// async global->LDS, 16B per lane; LDS dest = (first lane's ptr) + lane*16.
__device__ __forceinline__ void gl16(const void* g, void* l) {
  __builtin_amdgcn_global_load_lds(
      (const __attribute__((address_space(1))) void*)g,
      (__attribute__((address_space(3))) void*)l, 16, 0, 0);
}

// ---------- per-node winner key: max (t, isDst, e) ----------
__global__ void k_scatter(const int* __restrict__ src, const int* __restrict__ dst,
                          const int* __restrict__ t, u64* __restrict__ key) {
  int e = blockIdx.x*256 + threadIdx.x;
  if (e >= NE) return;
  u64 tt = (u64)(unsigned)(t[e] + 1);
  atomicMax(&key[src[e]], (tt<<18) | (u64)(unsigned)e);
  atomicMax(&key[dst[e]], (tt<<18) | (1ULL<<17) | (u64)(unsigned)e);
}

__global__ void k_compact(const u64* __restrict__ key, int* __restrict__ list,
                          int* __restrict__ count) {
  int n = blockIdx.x*256 + threadIdx.x;
  if (n >= NN) return;
  if (key[n] != 0ULL) { int p = atomicAdd(count, 1); list[p] = n; }
}

// ---------- fold W1/W_sp/W_pp/biases: A=W1a@W_sp, B=(W1b+W1c)@W_pp, c0 ----------
__global__ void k_pre(const float* __restrict__ W1, const float* __restrict__ W_sp,
                      const float* __restrict__ W_pp, const float* __restrict__ b_sp,
                      const float* __restrict__ b_pp, const float* __restrict__ b1,
                      float* __restrict__ A, float* __restrict__ B, float* __restrict__ c0)
{
  int tid = blockIdx.x*256 + threadIdx.x;
  if (tid < 2048) {
    int o = tid >> 5, j = tid & 31;
    float s = 0.f;
    for (int k = 0; k < 128; ++k) s = fmaf(W1[o*NG + k], W_sp[k*32 + j], s);
    A[tid] = s;
  } else if (tid < 4096) {
    int q = tid - 2048;
    int o = q >> 5, j = q & 31;
    float s = 0.f;
    for (int k = 0; k < 128; ++k)
      s = fmaf(W1[o*NG + 128 + k] + W1[o*NG + 256 + k], W_pp[k*32 + j], s);
    B[q] = s;
  } else if (tid < 4160) {
    int o = tid - 4096;
    float s = b1[o];
    for (int k = 0; k < 128; ++k) {
      s = fmaf(W1[o*NG + k], b_sp[k], s);
      s = fmaf(W1[o*NG + 128 + k] + W1[o*NG + 256 + k], b_pp[k], s);
    }
    c0[o] = s;
  }
}

// ---------- pre-convert GRU weights to bf16, pre-swizzled for gl16 staging ----------
__global__ void k_prew(const float* __restrict__ W_ih, const float* __restrict__ W_hh,
                       short* __restrict__ Wbf)
{
  int idx = blockIdx.x*256 + threadIdx.x;
  if (idx >= 9*384*8) return;
  int s   = idx & 7;
  int n   = (idx >> 3) % 384;
  int ch9 = idx / (384*8);
  int k8  = s ^ (n & 7);
  int k   = ch9*64 + k8*8;
  short v[8];
  #pragma unroll
  for (int e = 0; e < 8; ++e) {
    int kk = k + e;
    float f = (kk < 448) ? W_ih[(size_t)n*448 + kk] : W_hh[(size_t)n*HD + (kk-448)];
    v[e] = f2bf(f);
  }
  *reinterpret_cast<bf16x8*>(Wbf + (size_t)ch9*24576 + n*64 + s*8) =
      *reinterpret_cast<bf16x8*>(v);
}

// ---------- GRU via bf16 MFMA: 64 nodes/block, 512 thr = 8 waves ----------
// R16: wave re-tiling (Mt=4, G=3) — wave w owns h-slice w*16..+16 and ALL 4 M-tiles.
// Per phase per wave: 6 b-reads + 8 a-reads (14) vs previous 26 — b-frags no longer
// read 4x redundantly across M-waves. Phases/staging/swizzles/epilogue identical R15.
__global__ __launch_bounds__(512, 2) void k_gru(
    const u64* __restrict__ key, const int* __restrict__ list, const int* __restrict__ count,
    const int* __restrict__ src, const int* __restrict__ dst, const int* __restrict__ t,
    const float* __restrict__ msg, const float* __restrict__ memory,
    const float* __restrict__ last_update,
    const float* __restrict__ w_t, const float* __restrict__ b_t,
    const short* __restrict__ Wbf, const float* __restrict__ b_ih,
    const float* __restrict__ b_hh, const float* __restrict__ W1,
    float* __restrict__ uv)
{
  __shared__ short Wsb[24576];    // 48KB: W chunk [384 n][8 slots][8 bf16]
  __shared__ short Xsb[4096];     // 8KB: X chunk [64 node][8 slots][8 bf16]
  __shared__ float bias4[512];    // br|bz|bnx|bnm per h
  __shared__ int   sn_self[64];
  __shared__ int   sn_other[64];
  __shared__ int   sn_e[64];
  __shared__ float sn_dt[64];

  float* Mn  = reinterpret_cast<float*>(&Wsb[8192]);  // [64][128] fp32, bytes 16K..48K
  float* W1s = reinterpret_cast<float*>(&Wsb[0]);     // 4096 floats for uv staging

  int cnt = count[0];
  int base = blockIdx.x * 64;
  if (base >= cnt) return;
  int tid = threadIdx.x;
  int tx = tid & 31, ty = tid >> 5;      // for uv epilogue (16 ty-groups)
  int wid = tid >> 6, lane = tid & 63;
  int lr = lane & 15, lk = lane >> 4;    // fragment row/col & k-group

  if (tid < 64) {
    int idx = base + tid;
    int cl = idx < cnt ? idx : (cnt - 1);
    int n = list[cl];
    u64 k = key[n];
    int e   = (int)(k & 0x1FFFFULL);
    int isd = (int)((k >> 17) & 1ULL);
    sn_self[tid]  = n;
    sn_other[tid] = isd ? src[e] : dst[e];
    sn_e[tid]     = e;
    sn_dt[tid]    = (float)t[e] - last_update[n];
  }
  if (tid < 128) {
    int h = tid;
    bias4[h]       = b_ih[h]       + b_hh[h];
    bias4[128 + h] = b_ih[128 + h] + b_hh[128 + h];
    bias4[256 + h] = b_ih[256 + h];
    bias4[384 + h] = b_hh[256 + h];
  }
  __syncthreads();

  // accumulators: 4 M-tiles x {R,Z,NX,NM} for this wave's 16-h slice
  f32x4 aR[4], aZ[4], aNX[4], aNM[4];
  #pragma unroll
  for (int mt = 0; mt < 4; ++mt) { aR[mt] = (f32x4)0.f; aZ[mt] = (f32x4)0.f;
                                   aNX[mt] = (f32x4)0.f; aNM[mt] = (f32x4)0.f; }

  int node8 = tid >> 3, k8s = tid & 7;   // staging coords
  auto srcp = [&](int xch) -> const float* {
    if (xch <= 1)      return memory + (size_t)sn_self[node8]*HD  + (xch==1 ? 64 : 0) + k8s*8;
    else if (xch <= 3) return memory + (size_t)sn_other[node8]*HD + (xch==3 ? 64 : 0) + k8s*8;
    else               return msg + (size_t)sn_e[node8]*EFD + k8s*8;
  };

  constexpr int WCH[9] = {0, 7, 1, 8, 2, 3, 4, 5, 6};
  constexpr int XST[9] = {0,-1, 1,-1, 2, 3, 4,-2,-2};
  constexpr int XIS[9] = {1,-9, 2,-9, 3, 4,-9,-9,-9};

  float4 xfA, xfB;
  { const float* p = srcp(0); xfA = ld4(p); xfB = ld4(p+4); }

  int hrow = wid*16 + lr;                // W row within each 128-row gate block
  int swzH = (hrow & 7);                 // (128+hrow)&7 == (256+hrow)&7 == hrow&7

  #pragma unroll
  for (int p = 0; p < 9; ++p) {
    const int W = WCH[p];
    #pragma unroll
    for (int i = 0; i < 6; ++i) {
      int q = i*512 + tid;
      gl16(Wbf + (size_t)W*24576 + q*8, &Wsb[q*8]);
    }
    if (XST[p] >= 0) {
      short xs[8];
      xs[0]=f2bf(xfA.x); xs[1]=f2bf(xfA.y); xs[2]=f2bf(xfA.z); xs[3]=f2bf(xfA.w);
      xs[4]=f2bf(xfB.x); xs[5]=f2bf(xfB.y); xs[6]=f2bf(xfB.z); xs[7]=f2bf(xfB.w);
      *reinterpret_cast<bf16x8*>(&Xsb[node8*64 + ((k8s ^ (node8&7))<<3)]) =
          *reinterpret_cast<bf16x8*>(xs);
    } else if (XST[p] == -2) {
      int kk = (W == 6 ? 64 : 0) + k8s*8;
      float dt = sn_dt[node8];
      short xs[8];
      #pragma unroll
      for (int q = 0; q < 8; ++q) xs[q] = f2bf(cosf(fmaf(dt, w_t[kk+q], b_t[kk+q])));
      *reinterpret_cast<bf16x8*>(&Xsb[node8*64 + ((k8s ^ (node8&7))<<3)]) =
          *reinterpret_cast<bf16x8*>(xs);
    }
    __syncthreads();   // Wsb (gl16 drained) + Xsb ready

    if (XIS[p] >= 0) { const float* q = srcp(XIS[p]); xfA = ld4(q); xfB = ld4(q+4); }

    #pragma unroll
    for (int ks = 0; ks < 2; ++ks) {
      int k8 = ks*4 + lk;
      int so = (k8 ^ swzH) << 3;
      bf16x8 bR = *reinterpret_cast<const bf16x8*>(&Wsb[(size_t)hrow*64 + so]);
      bf16x8 bZ = *reinterpret_cast<const bf16x8*>(&Wsb[(size_t)(128+hrow)*64 + so]);
      bf16x8 bN = *reinterpret_cast<const bf16x8*>(&Wsb[(size_t)(256+hrow)*64 + so]);
      #pragma unroll
      for (int mt = 0; mt < 4; ++mt) {
        int anode = mt*16 + lr;
        bf16x8 a = *reinterpret_cast<const bf16x8*>(&Xsb[anode*64 + ((k8 ^ (anode&7))<<3)]);
        aR[mt] = __builtin_amdgcn_mfma_f32_16x16x32_bf16(a, bR, aR[mt], 0, 0, 0);
        aZ[mt] = __builtin_amdgcn_mfma_f32_16x16x32_bf16(a, bZ, aZ[mt], 0, 0, 0);
        if (W < 7) aNX[mt] = __builtin_amdgcn_mfma_f32_16x16x32_bf16(a, bN, aNX[mt], 0, 0, 0);
        else       aNM[mt] = __builtin_amdgcn_mfma_f32_16x16x32_bf16(a, bN, aNM[mt], 0, 0, 0);
      }
    }
    __syncthreads();   // all reads of Wsb/Xsb done before next stage
  }

  // ---- GRU nonlinearity, lane-local (single h per lane); Mn overlays Wsb ----
  {
    int h = hrow;                                  // this lane's hidden index
    float br_ = bias4[h], bz_ = bias4[128+h], bnx_ = bias4[256+h], bnm_ = bias4[384+h];
    #pragma unroll
    for (int mt = 0; mt < 4; ++mt) {
      #pragma unroll
      for (int i = 0; i < 4; ++i) {
        int node = mt*16 + lk*4 + i;
        float r  = sigf(aR[mt][i] + br_);
        float z  = sigf(aZ[mt][i] + bz_);
        float nv = tanhf_(aNX[mt][i] + bnx_ + r*(aNM[mt][i] + bnm_));
        float m  = memory[(size_t)sn_self[node]*HD + h];
        Mn[node*128 + h] = (1.f - z)*nv + z*m;
      }
    }
  }
  __syncthreads();

  // ---- uv = [W1a@mn | W1b@mn] fp32: K=128 in 4 chunks; W1 staged at W1s ----
  float acc2[4][4];
  #pragma unroll
  for (int a = 0; a < 4; ++a) {
    #pragma unroll
    for (int b = 0; b < 4; ++b) acc2[a][b] = 0.f;
  }
  for (int ch = 0; ch < 4; ++ch) {
    #pragma unroll
    for (int i = 0; i < 2; ++i) {
      int idx = tid + 512*i;               // exactly the 1024-quad W1 tile
      int o = idx >> 3, k4 = idx & 7;
      int k = ch*32 + k4*4;
      float4 w = (o < 64) ? ld4(W1 + (size_t)o*NG + k)
                          : ld4(W1 + (size_t)(o-64)*NG + 128 + k);
      *reinterpret_cast<float4*>(&W1s[o*32 + ((k4 ^ (o&7))<<2)]) = w;
    }
    __syncthreads();
    #pragma unroll
    for (int k4 = 0; k4 < 8; ++k4) {
      float4 xv[4];
      #pragma unroll
      for (int nn = 0; nn < 4; ++nn)
        xv[nn] = *reinterpret_cast<const float4*>(&Mn[(ty + 16*nn)*128 + ch*32 + k4*4]);
      #pragma unroll
      for (int og = 0; og < 4; ++og) {
        int o = tx + 32*og;
        float4 w = *reinterpret_cast<const float4*>(&W1s[o*32 + ((k4 ^ (o&7))<<2)]);
        #pragma unroll
        for (int nn = 0; nn < 4; ++nn) {
          acc2[nn][og] = fmaf(w.x, xv[nn].x, acc2[nn][og]);
          acc2[nn][og] = fmaf(w.y, xv[nn].y, acc2[nn][og]);
          acc2[nn][og] = fmaf(w.z, xv[nn].z, acc2[nn][og]);
          acc2[nn][og] = fmaf(w.w, xv[nn].w, acc2[nn][og]);
        }
      }
    }
    __syncthreads();
  }
  #pragma unroll
  for (int nn = 0; nn < 4; ++nn) {
    int nl = ty + 16*nn;
    if (base + nl < cnt) {
      int self = sn_self[nl];
      #pragma unroll
      for (int og = 0; og < 4; ++og)
        uv[(size_t)self*128 + tx + 32*og] = acc2[nn][og];
    }
  }
}

// ---------- price LSTM via bf16 MFMA: 64 edges/block, 4 waves x 16 edges ----------
__global__ __launch_bounds__(256) void k_lstm(
    const float* __restrict__ price, const float* __restrict__ W_ihl,
    const float* __restrict__ W_hhl, const float* __restrict__ b_ihl,
    const float* __restrict__ b_hhl, float* __restrict__ hn_out)
{
  __shared__ short Wb[4096];      // W_hh bf16 [128 rows][32 k] = 8KB
  __shared__ float ps[64*50];     // 12.8KB price rows
  __shared__ float hbuf[4][576];  // per-wave h [16 e][stride 36] = 9.2KB
  int tid = threadIdx.x;
  int lane = tid & 63, wid = tid >> 6;
  int lr = lane & 15, lk = lane >> 4;

  {
    int base = tid * 16;
    #pragma unroll
    for (int q = 0; q < 8; ++q) {
      float a = W_hhl[base + q*2], b = W_hhl[base + q*2 + 1];
      unsigned pk = (unsigned)(unsigned short)f2bf(a)
                  | ((unsigned)(unsigned short)f2bf(b) << 16);
      reinterpret_cast<unsigned*>(Wb)[tid*8 + q] = pk;
    }
  }
  int ebase = blockIdx.x * 64;
  int m = NE - ebase; if (m > 64) m = 64;
  for (int i = tid; i < 64*50; i += 256) {
    int r = i / 50, cidx = i % 50;
    int rr = r < m ? r : m - 1;
    ps[i] = price[(size_t)(ebase + rr)*50 + cidx];
  }
  __syncthreads();

  bf16x8 bw[8];
  float wih8[8], bias8[8];
  #pragma unroll
  for (int t = 0; t < 8; ++t) {
    int row = t*16 + lr;
    bw[t] = *reinterpret_cast<const bf16x8*>(&Wb[row*32 + lk*8]);
    wih8[t] = W_ihl[row];
    bias8[t] = b_ihl[row] + b_hhl[row];
  }

  int we = wid * 16;
  float* hb = hbuf[wid];

  float c8[4][2];
  #pragma unroll
  for (int i = 0; i < 4; ++i) { c8[i][0] = 0.f; c8[i][1] = 0.f; }
  bf16x8 afrag = {0,0,0,0,0,0,0,0};

  #pragma unroll 1
  for (int s = 0; s < 50; ++s) {
    float xv[4];
    #pragma unroll
    for (int i = 0; i < 4; ++i) xv[i] = ps[(we + lk*4 + i)*50 + s];
    f32x4 acc[8];
    #pragma unroll
    for (int t = 0; t < 8; ++t) {
      f32x4 ci;
      #pragma unroll
      for (int i = 0; i < 4; ++i) ci[i] = fmaf(xv[i], wih8[t], bias8[t]);
      acc[t] = __builtin_amdgcn_mfma_f32_16x16x32_bf16(afrag, bw[t], ci, 0, 0, 0);
    }
    #pragma unroll
    for (int i = 0; i < 4; ++i) {
      #pragma unroll
      for (int p = 0; p < 2; ++p) {
        float ig = sigf(acc[0+p][i]);
        float fg = sigf(acc[2+p][i]);
        float gg = tanhf_(acc[4+p][i]);
        float og = sigf(acc[6+p][i]);
        c8[i][p] = fmaf(fg, c8[i][p], ig*gg);
        float h = og * tanhf_(c8[i][p]);
        hb[(lk*4 + i)*36 + p*16 + lr] = h;
      }
    }
    asm volatile("s_waitcnt lgkmcnt(0)" ::: "memory");
    float4 h0 = *reinterpret_cast<const float4*>(&hb[lr*36 + lk*8]);
    float4 h1 = *reinterpret_cast<const float4*>(&hb[lr*36 + lk*8 + 4]);
    short hs[8];
    hs[0]=f2bf(h0.x); hs[1]=f2bf(h0.y); hs[2]=f2bf(h0.z); hs[3]=f2bf(h0.w);
    hs[4]=f2bf(h1.x); hs[5]=f2bf(h1.y); hs[6]=f2bf(h1.z); hs[7]=f2bf(h1.w);
    afrag = *reinterpret_cast<bf16x8*>(hs);
  }

  int e_g = ebase + we + lr;
  if (e_g < NE) {
    float4 h0 = *reinterpret_cast<const float4*>(&hb[lr*36 + lk*8]);
    float4 h1 = *reinterpret_cast<const float4*>(&hb[lr*36 + lk*8 + 4]);
    *reinterpret_cast<float4*>(hn_out + (size_t)e_g*32 + lk*8)     = h0;
    *reinterpret_cast<float4*>(hn_out + (size_t)e_g*32 + lk*8 + 4) = h1;
  }
}

// ---------- fused output: out = W2 @ relu(u[s] + v[d] + A@sf + B@hn + c0) + b2 ----------
__global__ __launch_bounds__(256) void k_final(
    const int* __restrict__ src, const int* __restrict__ dst, const int* __restrict__ xst,
    const float* __restrict__ party, const float* __restrict__ state,
    const float* __restrict__ uv, const float* __restrict__ hn,
    const float* __restrict__ A, const float* __restrict__ B, const float* __restrict__ c0,
    const float* __restrict__ W2, const float* __restrict__ b2, float* __restrict__ out)
{
  __shared__ float As[2048], Bs[2048], c0s[64], W2s[64];
  int tid = threadIdx.x;
  for (int i = tid; i < 2048; i += 256) { As[i] = A[i]; Bs[i] = B[i]; }
  if (tid < 64) { c0s[tid] = c0[tid]; W2s[tid] = W2[tid]; }
  __syncthreads();
  int e = blockIdx.x*256 + tid;
  if (e >= NE) return;
  int s = src[e], d = dst[e];
  int p = xst[2*s], stt = xst[2*s + 1];
  float4 sf4[8], hv4[8];
  #pragma unroll
  for (int i = 0; i < 4; ++i) sf4[i]   = ld4(party + p*16 + i*4);
  #pragma unroll
  for (int i = 0; i < 4; ++i) sf4[4+i] = ld4(state + stt*16 + i*4);
  #pragma unroll
  for (int i = 0; i < 8; ++i) hv4[i] = ld4(hn + (size_t)e*32 + i*4);
  const float* urow = uv + (size_t)s*128;
  const float* vrow = uv + (size_t)d*128 + 64;
  float oacc = b2[0];
  #pragma unroll 4
  for (int o4 = 0; o4 < 16; ++o4) {
    float4 u4 = ld4(urow + o4*4);
    float4 v4 = ld4(vrow + o4*4);
    float4 cc = *reinterpret_cast<const float4*>(&c0s[o4*4]);
    float4 w2 = *reinterpret_cast<const float4*>(&W2s[o4*4]);
    float hh[4] = {u4.x+v4.x+cc.x, u4.y+v4.y+cc.y, u4.z+v4.z+cc.z, u4.w+v4.w+cc.w};
    #pragma unroll
    for (int oo = 0; oo < 4; ++oo) {
      int o = o4*4 + oo;
      float acc = hh[oo];
      #pragma unroll
      for (int j4 = 0; j4 < 8; ++j4) {
        float4 a = *reinterpret_cast<const float4*>(&As[o*32 + j4*4]);
        float4 b = *reinterpret_cast<const float4*>(&Bs[o*32 + j4*4]);
        float4 sfv = sf4[j4], hvv = hv4[j4];
        acc = fmaf(a.x,sfv.x, fmaf(a.y,sfv.y, fmaf(a.z,sfv.z, fmaf(a.w,sfv.w, acc))));
        acc = fmaf(b.x,hvv.x, fmaf(b.y,hvv.y, fmaf(b.z,hvv.z, fmaf(b.w,hvv.w, acc))));
      }
      float w2v = (oo==0) ? w2.x : (oo==1) ? w2.y : (oo==2) ? w2.z : w2.w;
      oacc = fmaf(w2v, fmaxf(acc, 0.f), oacc);
    }
  }
  out[e] = oacc;
}

extern "C" void kernel_launch(void* const* d_in, const int* in_sizes, int n_in,
                              void* d_out, int out_size, void* d_ws, size_t ws_size,
                              hipStream_t stream) {
  const int*   src   = (const int*)d_in[0];
  const int*   dst   = (const int*)d_in[1];
  const int*   t     = (const int*)d_in[2];
  const float* msg   = (const float*)d_in[3];
  const float* price = (const float*)d_in[4];
  // d_in[5] trade_t: unused by reference
  const int*   xst   = (const int*)d_in[6];
  const float* memory= (const float*)d_in[7];
  const float* lu    = (const float*)d_in[8];
  const float* w_t   = (const float*)d_in[9];
  const float* b_t   = (const float*)d_in[10];
  const float* W_ih  = (const float*)d_in[11];
  const float* b_ih  = (const float*)d_in[12];
  const float* W_hh  = (const float*)d_in[13];
  const float* b_hh  = (const float*)d_in[14];
  const float* party = (const float*)d_in[15];
  const float* state = (const float*)d_in[16];
  const float* W_sp  = (const float*)d_in[17];
  const float* b_sp  = (const float*)d_in[18];
  const float* W_ihl = (const float*)d_in[19];
  const float* W_hhl = (const float*)d_in[20];
  const float* b_ihl = (const float*)d_in[21];
  const float* b_hhl = (const float*)d_in[22];
  const float* W_pp  = (const float*)d_in[23];
  const float* b_pp  = (const float*)d_in[24];
  const float* W1    = (const float*)d_in[25];
  const float* b1    = (const float*)d_in[26];
  const float* W2    = (const float*)d_in[27];
  const float* b2    = (const float*)d_in[28];
  float* out = (float*)d_out;

  if (ws_size < WS_NEED) {              // loud failure: zero output
    (void)hipMemsetAsync(d_out, 0, (size_t)out_size*4, stream);
    return;
  }

  char* ws = (char*)d_ws;
  u64*   key  = (u64*)(ws + OFF_KEY);
  int*   cnt  = (int*)(ws + OFF_CNT);
  int*   list = (int*)(ws + OFF_LIST);
  float* uv   = (float*)(ws + OFF_UV);
  float* hn   = (float*)(ws + OFF_HN);
  float* A    = (float*)(ws + OFF_A);
  float* B    = (float*)(ws + OFF_B);
  float* c0   = (float*)(ws + OFF_C0);
  short* Wbf  = (short*)(ws + OFF_WBF);

  (void)hipMemsetAsync(ws, 0, OFF_LIST, stream);   // zero key[] + count
  k_scatter<<<(NE+255)/256, 256, 0, stream>>>(src, dst, t, key);
  k_compact<<<(NN+255)/256, 256, 0, stream>>>(key, list, cnt);
  k_pre<<<17, 256, 0, stream>>>(W1, W_sp, W_pp, b_sp, b_pp, b1, A, B, c0);
  k_prew<<<108, 256, 0, stream>>>(W_ih, W_hh, Wbf);
  k_lstm<<<(NE+63)/64, 256, 0, stream>>>(price, W_ihl, W_hhl, b_ihl, b_hhl, hn);
  k_gru<<<(NN+63)/64, 512, 0, stream>>>(key, list, cnt, src, dst, t, msg, memory, lu,
                                        w_t, b_t, Wbf, b_ih, b_hh, W1, uv);
  k_final<<<(NE+255)/256, 256, 0, stream>>>(src, dst, xst, party, state, uv, hn,
                                            A, B, c0, W2, b2, out);
}

// Round 17
// 605.741 us; speedup vs baseline: 3.7980x; 1.0133x over previous
//
#include <hip/hip_runtime.h>
#include <stdint.h>

#define NN    200000   // nodes
#define NE    100000   // edges
#define HD    128      // hidden/memory/time dim
#define EFD   64       // edge feat dim
#define NG    384      // 3*HD gates

typedef unsigned long long u64;
typedef short bf16x8 __attribute__((ext_vector_type(8)));   // 8 bf16 (4 VGPRs)
typedef float f32x4  __attribute__((ext_vector_type(4)));   // MFMA C/D frag

// ---- ws layout (bytes) ----
#define OFF_KEY   ((size_t)0)            // u64 * NN = 1,600,000
#define OFF_CNT   ((size_t)1600000)      // int
#define OFF_LIST  ((size_t)1600256)      // int * NN = 800,000
#define OFF_UV    ((size_t)2400256)      // float * NN*128 = 102,400,000
#define OFF_HN    ((size_t)104800256)    // float * NE*32 = 12,800,000
#define OFF_A     ((size_t)117600256)    // float * 2048
#define OFF_B     ((size_t)117608448)    // float * 2048
#define OFF_C0    ((size_t)117616640)    // float * 64 (+pad)
#define OFF_WBF   ((size_t)117616896)    // short * 9*384*64 = 442,368 B (bf16 W, pre-swizzled)
#define WS_NEED   ((size_t)118059264)

__device__ __forceinline__ float frcp(float x){ return __builtin_amdgcn_rcpf(x); }
__device__ __forceinline__ float sigf(float x){ return frcp(1.f + __expf(-x)); }
__device__ __forceinline__ float tanhf_(float x){ return 1.f - 2.f*frcp(__expf(2.f*x) + 1.f); }
__device__ __forceinline__ float4 ld4(const float* p){ return *reinterpret_cast<const float4*>(p); }

// fp32 -> bf16 RNE (bit math; inputs finite)
__device__ __forceinline__ short f2bf(float f){
  unsigned u = __float_as_uint(f);
  u += 0x7fffu + ((u>>16)&1u);
  return (short)(u>>16);
}

// async global->LDS, 16B per lane; LDS dest = (first lane's ptr) + lane*16.
__device__ __forceinline__ void gl16(const void* g, void* l) {
  __builtin_amdgcn_global_load_lds(
      (const __attribute__((address_space(1))) void*)g,
      (__attribute__((address_space(3))) void*)l, 16, 0, 0);
}

// ---------- per-node winner key: max (t, isDst, e) ----------
__global__ void k_scatter(const int* __restrict__ src, const int* __restrict__ dst,
                          const int* __restrict__ t, u64* __restrict__ key) {
  int e = blockIdx.x*256 + threadIdx.x;
  if (e >= NE) return;
  u64 tt = (u64)(unsigned)(t[e] + 1);
  atomicMax(&key[src[e]], (tt<<18) | (u64)(unsigned)e);
  atomicMax(&key[dst[e]], (tt<<18) | (1ULL<<17) | (u64)(unsigned)e);
}

__global__ void k_compact(const u64* __restrict__ key, int* __restrict__ list,
                          int* __restrict__ count) {
  int n = blockIdx.x*256 + threadIdx.x;
  if (n >= NN) return;
  if (key[n] != 0ULL) { int p = atomicAdd(count, 1); list[p] = n; }
}

// ---------- fold W1/W_sp/W_pp/biases: A=W1a@W_sp, B=(W1b+W1c)@W_pp, c0 ----------
__global__ void k_pre(const float* __restrict__ W1, const float* __restrict__ W_sp,
                      const float* __restrict__ W_pp, const float* __restrict__ b_sp,
                      const float* __restrict__ b_pp, const float* __restrict__ b1,
                      float* __restrict__ A, float* __restrict__ B, float* __restrict__ c0)
{
  int tid = blockIdx.x*256 + threadIdx.x;
  if (tid < 2048) {
    int o = tid >> 5, j = tid & 31;
    float s = 0.f;
    for (int k = 0; k < 128; ++k) s = fmaf(W1[o*NG + k], W_sp[k*32 + j], s);
    A[tid] = s;
  } else if (tid < 4096) {
    int q = tid - 2048;
    int o = q >> 5, j = q & 31;
    float s = 0.f;
    for (int k = 0; k < 128; ++k)
      s = fmaf(W1[o*NG + 128 + k] + W1[o*NG + 256 + k], W_pp[k*32 + j], s);
    B[q] = s;
  } else if (tid < 4160) {
    int o = tid - 4096;
    float s = b1[o];
    for (int k = 0; k < 128; ++k) {
      s = fmaf(W1[o*NG + k], b_sp[k], s);
      s = fmaf(W1[o*NG + 128 + k] + W1[o*NG + 256 + k], b_pp[k], s);
    }
    c0[o] = s;
  }
}

// ---------- pre-convert GRU weights to bf16, pre-swizzled for gl16 staging ----------
__global__ void k_prew(const float* __restrict__ W_ih, const float* __restrict__ W_hh,
                       short* __restrict__ Wbf)
{
  int idx = blockIdx.x*256 + threadIdx.x;
  if (idx >= 9*384*8) return;
  int s   = idx & 7;
  int n   = (idx >> 3) % 384;
  int ch9 = idx / (384*8);
  int k8  = s ^ (n & 7);
  int k   = ch9*64 + k8*8;
  short v[8];
  #pragma unroll
  for (int e = 0; e < 8; ++e) {
    int kk = k + e;
    float f = (kk < 448) ? W_ih[(size_t)n*448 + kk] : W_hh[(size_t)n*HD + (kk-448)];
    v[e] = f2bf(f);
  }
  *reinterpret_cast<bf16x8*>(Wbf + (size_t)ch9*24576 + n*64 + s*8) =
      *reinterpret_cast<bf16x8*>(v);
}

// ---------- GRU via bf16 MFMA: 64 nodes/block, 512 thr = 8 waves ----------
// R17: ALL X gathers (5 float4-pairs per thread) issued in the PROLOGUE -> one
// vmcnt(0) latency exposure instead of five phase-serial ones (latency-MLP fix).
// Wave tiling (Mt=4,G=3) and phases identical to R16.
__global__ __launch_bounds__(512, 2) void k_gru(
    const u64* __restrict__ key, const int* __restrict__ list, const int* __restrict__ count,
    const int* __restrict__ src, const int* __restrict__ dst, const int* __restrict__ t,
    const float* __restrict__ msg, const float* __restrict__ memory,
    const float* __restrict__ last_update,
    const float* __restrict__ w_t, const float* __restrict__ b_t,
    const short* __restrict__ Wbf, const float* __restrict__ b_ih,
    const float* __restrict__ b_hh, const float* __restrict__ W1,
    float* __restrict__ uv)
{
  __shared__ short Wsb[24576];    // 48KB: W chunk [384 n][8 slots][8 bf16]
  __shared__ short Xsb[4096];     // 8KB: X chunk [64 node][8 slots][8 bf16]
  __shared__ float bias4[512];    // br|bz|bnx|bnm per h
  __shared__ int   sn_self[64];
  __shared__ int   sn_other[64];
  __shared__ int   sn_e[64];
  __shared__ float sn_dt[64];

  float* Mn  = reinterpret_cast<float*>(&Wsb[8192]);  // [64][128] fp32, bytes 16K..48K
  float* W1s = reinterpret_cast<float*>(&Wsb[0]);     // 4096 floats for uv staging

  int cnt = count[0];
  int base = blockIdx.x * 64;
  if (base >= cnt) return;
  int tid = threadIdx.x;
  int tx = tid & 31, ty = tid >> 5;      // for uv epilogue (16 ty-groups)
  int wid = tid >> 6, lane = tid & 63;
  int lr = lane & 15, lk = lane >> 4;    // fragment row/col & k-group

  if (tid < 64) {
    int idx = base + tid;
    int cl = idx < cnt ? idx : (cnt - 1);
    int n = list[cl];
    u64 k = key[n];
    int e   = (int)(k & 0x1FFFFULL);
    int isd = (int)((k >> 17) & 1ULL);
    sn_self[tid]  = n;
    sn_other[tid] = isd ? src[e] : dst[e];
    sn_e[tid]     = e;
    sn_dt[tid]    = (float)t[e] - last_update[n];
  }
  if (tid < 128) {
    int h = tid;
    bias4[h]       = b_ih[h]       + b_hh[h];
    bias4[128 + h] = b_ih[128 + h] + b_hh[128 + h];
    bias4[256 + h] = b_ih[256 + h];
    bias4[384 + h] = b_hh[256 + h];
  }
  __syncthreads();

  // accumulators: 4 M-tiles x {R,Z,NX,NM} for this wave's 16-h slice
  f32x4 aR[4], aZ[4], aNX[4], aNM[4];
  #pragma unroll
  for (int mt = 0; mt < 4; ++mt) { aR[mt] = (f32x4)0.f; aZ[mt] = (f32x4)0.f;
                                   aNX[mt] = (f32x4)0.f; aNM[mt] = (f32x4)0.f; }

  int node8 = tid >> 3, k8s = tid & 7;   // staging coords

  // ---- PROLOGUE: issue all 5 X gathers now (one latency exposure) ----
  float4 xA0, xB0, xA1, xB1, xA2, xB2, xA3, xB3, xA4, xB4;
  {
    const float* pSelf  = memory + (size_t)sn_self[node8]*HD  + k8s*8;
    const float* pOther = memory + (size_t)sn_other[node8]*HD + k8s*8;
    const float* pMsg   = msg + (size_t)sn_e[node8]*EFD + k8s*8;
    xA0 = ld4(pSelf);       xB0 = ld4(pSelf+4);
    xA1 = ld4(pSelf+64);    xB1 = ld4(pSelf+68);
    xA2 = ld4(pOther);      xB2 = ld4(pOther+4);
    xA3 = ld4(pOther+64);   xB3 = ld4(pOther+68);
    xA4 = ld4(pMsg);        xB4 = ld4(pMsg+4);
  }

  // phase tables: W chunk id; X source (-1 reuse prev Xsb, -2 cos, else reg pair id)
  constexpr int WCH[9] = {0, 7, 1, 8, 2, 3, 4, 5, 6};
  constexpr int XST[9] = {0,-1, 1,-1, 2, 3, 4,-2,-2};

  int hrow = wid*16 + lr;                // W row within each 128-row gate block
  int swzH = (hrow & 7);

  #pragma unroll
  for (int p = 0; p < 9; ++p) {
    const int W = WCH[p];
    #pragma unroll
    for (int i = 0; i < 6; ++i) {
      int q = i*512 + tid;
      gl16(Wbf + (size_t)W*24576 + q*8, &Wsb[q*8]);
    }
    if (XST[p] >= 0) {
      float4 fa, fb;
      switch (XST[p]) {
        case 0: fa = xA0; fb = xB0; break;
        case 1: fa = xA1; fb = xB1; break;
        case 2: fa = xA2; fb = xB2; break;
        case 3: fa = xA3; fb = xB3; break;
        default: fa = xA4; fb = xB4; break;
      }
      short xs[8];
      xs[0]=f2bf(fa.x); xs[1]=f2bf(fa.y); xs[2]=f2bf(fa.z); xs[3]=f2bf(fa.w);
      xs[4]=f2bf(fb.x); xs[5]=f2bf(fb.y); xs[6]=f2bf(fb.z); xs[7]=f2bf(fb.w);
      *reinterpret_cast<bf16x8*>(&Xsb[node8*64 + ((k8s ^ (node8&7))<<3)]) =
          *reinterpret_cast<bf16x8*>(xs);
    } else if (XST[p] == -2) {
      int kk = (W == 6 ? 64 : 0) + k8s*8;
      float dt = sn_dt[node8];
      short xs[8];
      #pragma unroll
      for (int q = 0; q < 8; ++q) xs[q] = f2bf(cosf(fmaf(dt, w_t[kk+q], b_t[kk+q])));
      *reinterpret_cast<bf16x8*>(&Xsb[node8*64 + ((k8s ^ (node8&7))<<3)]) =
          *reinterpret_cast<bf16x8*>(xs);
    }
    __syncthreads();   // Wsb (gl16 drained) + Xsb ready

    #pragma unroll
    for (int ks = 0; ks < 2; ++ks) {
      int k8 = ks*4 + lk;
      int so = (k8 ^ swzH) << 3;
      bf16x8 bR = *reinterpret_cast<const bf16x8*>(&Wsb[(size_t)hrow*64 + so]);
      bf16x8 bZ = *reinterpret_cast<const bf16x8*>(&Wsb[(size_t)(128+hrow)*64 + so]);
      bf16x8 bN = *reinterpret_cast<const bf16x8*>(&Wsb[(size_t)(256+hrow)*64 + so]);
      #pragma unroll
      for (int mt = 0; mt < 4; ++mt) {
        int anode = mt*16 + lr;
        bf16x8 a = *reinterpret_cast<const bf16x8*>(&Xsb[anode*64 + ((k8 ^ (anode&7))<<3)]);
        aR[mt] = __builtin_amdgcn_mfma_f32_16x16x32_bf16(a, bR, aR[mt], 0, 0, 0);
        aZ[mt] = __builtin_amdgcn_mfma_f32_16x16x32_bf16(a, bZ, aZ[mt], 0, 0, 0);
        if (W < 7) aNX[mt] = __builtin_amdgcn_mfma_f32_16x16x32_bf16(a, bN, aNX[mt], 0, 0, 0);
        else       aNM[mt] = __builtin_amdgcn_mfma_f32_16x16x32_bf16(a, bN, aNM[mt], 0, 0, 0);
      }
    }
    __syncthreads();   // all reads of Wsb/Xsb done before next stage
  }

  // ---- GRU nonlinearity, lane-local (single h per lane); Mn overlays Wsb ----
  {
    int h = hrow;
    float br_ = bias4[h], bz_ = bias4[128+h], bnx_ = bias4[256+h], bnm_ = bias4[384+h];
    #pragma unroll
    for (int mt = 0; mt < 4; ++mt) {
      #pragma unroll
      for (int i = 0; i < 4; ++i) {
        int node = mt*16 + lk*4 + i;
        float r  = sigf(aR[mt][i] + br_);
        float z  = sigf(aZ[mt][i] + bz_);
        float nv = tanhf_(aNX[mt][i] + bnx_ + r*(aNM[mt][i] + bnm_));
        float m  = memory[(size_t)sn_self[node]*HD + h];
        Mn[node*128 + h] = (1.f - z)*nv + z*m;
      }
    }
  }
  __syncthreads();

  // ---- uv = [W1a@mn | W1b@mn] fp32: K=128 in 4 chunks; W1 staged at W1s ----
  float acc2[4][4];
  #pragma unroll
  for (int a = 0; a < 4; ++a) {
    #pragma unroll
    for (int b = 0; b < 4; ++b) acc2[a][b] = 0.f;
  }
  for (int ch = 0; ch < 4; ++ch) {
    #pragma unroll
    for (int i = 0; i < 2; ++i) {
      int idx = tid + 512*i;               // exactly the 1024-quad W1 tile
      int o = idx >> 3, k4 = idx & 7;
      int k = ch*32 + k4*4;
      float4 w = (o < 64) ? ld4(W1 + (size_t)o*NG + k)
                          : ld4(W1 + (size_t)(o-64)*NG + 128 + k);
      *reinterpret_cast<float4*>(&W1s[o*32 + ((k4 ^ (o&7))<<2)]) = w;
    }
    __syncthreads();
    #pragma unroll
    for (int k4 = 0; k4 < 8; ++k4) {
      float4 xv[4];
      #pragma unroll
      for (int nn = 0; nn < 4; ++nn)
        xv[nn] = *reinterpret_cast<const float4*>(&Mn[(ty + 16*nn)*128 + ch*32 + k4*4]);
      #pragma unroll
      for (int og = 0; og < 4; ++og) {
        int o = tx + 32*og;
        float4 w = *reinterpret_cast<const float4*>(&W1s[o*32 + ((k4 ^ (o&7))<<2)]);
        #pragma unroll
        for (int nn = 0; nn < 4; ++nn) {
          acc2[nn][og] = fmaf(w.x, xv[nn].x, acc2[nn][og]);
          acc2[nn][og] = fmaf(w.y, xv[nn].y, acc2[nn][og]);
          acc2[nn][og] = fmaf(w.z, xv[nn].z, acc2[nn][og]);
          acc2[nn][og] = fmaf(w.w, xv[nn].w, acc2[nn][og]);
        }
      }
    }
    __syncthreads();
  }
  #pragma unroll
  for (int nn = 0; nn < 4; ++nn) {
    int nl = ty + 16*nn;
    if (base + nl < cnt) {
      int self = sn_self[nl];
      #pragma unroll
      for (int og = 0; og < 4; ++og)
        uv[(size_t)self*128 + tx + 32*og] = acc2[nn][og];
    }
  }
}

// ---------- price LSTM via bf16 MFMA: 64 edges/block, 4 waves x 16 edges ----------
__global__ __launch_bounds__(256) void k_lstm(
    const float* __restrict__ price, const float* __restrict__ W_ihl,
    const float* __restrict__ W_hhl, const float* __restrict__ b_ihl,
    const float* __restrict__ b_hhl, float* __restrict__ hn_out)
{
  __shared__ short Wb[4096];      // W_hh bf16 [128 rows][32 k] = 8KB
  __shared__ float ps[64*50];     // 12.8KB price rows
  __shared__ float hbuf[4][576];  // per-wave h [16 e][stride 36] = 9.2KB
  int tid = threadIdx.x;
  int lane = tid & 63, wid = tid >> 6;
  int lr = lane & 15, lk = lane >> 4;

  {
    int base = tid * 16;
    #pragma unroll
    for (int q = 0; q < 8; ++q) {
      float a = W_hhl[base + q*2], b = W_hhl[base + q*2 + 1];
      unsigned pk = (unsigned)(unsigned short)f2bf(a)
                  | ((unsigned)(unsigned short)f2bf(b) << 16);
      reinterpret_cast<unsigned*>(Wb)[tid*8 + q] = pk;
    }
  }
  int ebase = blockIdx.x * 64;
  int m = NE - ebase; if (m > 64) m = 64;
  for (int i = tid; i < 64*50; i += 256) {
    int r = i / 50, cidx = i % 50;
    int rr = r < m ? r : m - 1;
    ps[i] = price[(size_t)(ebase + rr)*50 + cidx];
  }
  __syncthreads();

  bf16x8 bw[8];
  float wih8[8], bias8[8];
  #pragma unroll
  for (int t = 0; t < 8; ++t) {
    int row = t*16 + lr;
    bw[t] = *reinterpret_cast<const bf16x8*>(&Wb[row*32 + lk*8]);
    wih8[t] = W_ihl[row];
    bias8[t] = b_ihl[row] + b_hhl[row];
  }

  int we = wid * 16;
  float* hb = hbuf[wid];

  float c8[4][2];
  #pragma unroll
  for (int i = 0; i < 4; ++i) { c8[i][0] = 0.f; c8[i][1] = 0.f; }
  bf16x8 afrag = {0,0,0,0,0,0,0,0};

  #pragma unroll 1
  for (int s = 0; s < 50; ++s) {
    float xv[4];
    #pragma unroll
    for (int i = 0; i < 4; ++i) xv[i] = ps[(we + lk*4 + i)*50 + s];
    f32x4 acc[8];
    #pragma unroll
    for (int t = 0; t < 8; ++t) {
      f32x4 ci;
      #pragma unroll
      for (int i = 0; i < 4; ++i) ci[i] = fmaf(xv[i], wih8[t], bias8[t]);
      acc[t] = __builtin_amdgcn_mfma_f32_16x16x32_bf16(afrag, bw[t], ci, 0, 0, 0);
    }
    #pragma unroll
    for (int i = 0; i < 4; ++i) {
      #pragma unroll
      for (int p = 0; p < 2; ++p) {
        float ig = sigf(acc[0+p][i]);
        float fg = sigf(acc[2+p][i]);
        float gg = tanhf_(acc[4+p][i]);
        float og = sigf(acc[6+p][i]);
        c8[i][p] = fmaf(fg, c8[i][p], ig*gg);
        float h = og * tanhf_(c8[i][p]);
        hb[(lk*4 + i)*36 + p*16 + lr] = h;
      }
    }
    asm volatile("s_waitcnt lgkmcnt(0)" ::: "memory");
    float4 h0 = *reinterpret_cast<const float4*>(&hb[lr*36 + lk*8]);
    float4 h1 = *reinterpret_cast<const float4*>(&hb[lr*36 + lk*8 + 4]);
    short hs[8];
    hs[0]=f2bf(h0.x); hs[1]=f2bf(h0.y); hs[2]=f2bf(h0.z); hs[3]=f2bf(h0.w);
    hs[4]=f2bf(h1.x); hs[5]=f2bf(h1.y); hs[6]=f2bf(h1.z); hs[7]=f2bf(h1.w);
    afrag = *reinterpret_cast<bf16x8*>(hs);
  }

  int e_g = ebase + we + lr;
  if (e_g < NE) {
    float4 h0 = *reinterpret_cast<const float4*>(&hb[lr*36 + lk*8]);
    float4 h1 = *reinterpret_cast<const float4*>(&hb[lr*36 + lk*8 + 4]);
    *reinterpret_cast<float4*>(hn_out + (size_t)e_g*32 + lk*8)     = h0;
    *reinterpret_cast<float4*>(hn_out + (size_t)e_g*32 + lk*8 + 4) = h1;
  }
}

// ---------- fused output: out = W2 @ relu(u[s] + v[d] + A@sf + B@hn + c0) + b2 ----------
__global__ __launch_bounds__(256) void k_final(
    const int* __restrict__ src, const int* __restrict__ dst, const int* __restrict__ xst,
    const float* __restrict__ party, const float* __restrict__ state,
    const float* __restrict__ uv, const float* __restrict__ hn,
    const float* __restrict__ A, const float* __restrict__ B, const float* __restrict__ c0,
    const float* __restrict__ W2, const float* __restrict__ b2, float* __restrict__ out)
{
  __shared__ float As[2048], Bs[2048], c0s[64], W2s[64];
  int tid = threadIdx.x;
  for (int i = tid; i < 2048; i += 256) { As[i] = A[i]; Bs[i] = B[i]; }
  if (tid < 64) { c0s[tid] = c0[tid]; W2s[tid] = W2[tid]; }
  __syncthreads();
  int e = blockIdx.x*256 + tid;
  if (e >= NE) return;
  int s = src[e], d = dst[e];
  int p = xst[2*s], stt = xst[2*s + 1];
  float4 sf4[8], hv4[8];
  #pragma unroll
  for (int i = 0; i < 4; ++i) sf4[i]   = ld4(party + p*16 + i*4);
  #pragma unroll
  for (int i = 0; i < 4; ++i) sf4[4+i] = ld4(state + stt*16 + i*4);
  #pragma unroll
  for (int i = 0; i < 8; ++i) hv4[i] = ld4(hn + (size_t)e*32 + i*4);
  const float* urow = uv + (size_t)s*128;
  const float* vrow = uv + (size_t)d*128 + 64;
  float oacc = b2[0];
  #pragma unroll 4
  for (int o4 = 0; o4 < 16; ++o4) {
    float4 u4 = ld4(urow + o4*4);
    float4 v4 = ld4(vrow + o4*4);
    float4 cc = *reinterpret_cast<const float4*>(&c0s[o4*4]);
    float4 w2 = *reinterpret_cast<const float4*>(&W2s[o4*4]);
    float hh[4] = {u4.x+v4.x+cc.x, u4.y+v4.y+cc.y, u4.z+v4.z+cc.z, u4.w+v4.w+cc.w};
    #pragma unroll
    for (int oo = 0; oo < 4; ++oo) {
      int o = o4*4 + oo;
      float acc = hh[oo];
      #pragma unroll
      for (int j4 = 0; j4 < 8; ++j4) {
        float4 a = *reinterpret_cast<const float4*>(&As[o*32 + j4*4]);
        float4 b = *reinterpret_cast<const float4*>(&Bs[o*32 + j4*4]);
        float4 sfv = sf4[j4], hvv = hv4[j4];
        acc = fmaf(a.x,sfv.x, fmaf(a.y,sfv.y, fmaf(a.z,sfv.z, fmaf(a.w,sfv.w, acc))));
        acc = fmaf(b.x,hvv.x, fmaf(b.y,hvv.y, fmaf(b.z,hvv.z, fmaf(b.w,hvv.w, acc))));
      }
      float w2v = (oo==0) ? w2.x : (oo==1) ? w2.y : (oo==2) ? w2.z : w2.w;
      oacc = fmaf(w2v, fmaxf(acc, 0.f), oacc);
    }
  }
  out[e] = oacc;
}

extern "C" void kernel_launch(void* const* d_in, const int* in_sizes, int n_in,
                              void* d_out, int out_size, void* d_ws, size_t ws_size,
                              hipStream_t stream) {
  const int*   src   = (const int*)d_in[0];
  const int*   dst   = (const int*)d_in[1];
  const int*   t     = (const int*)d_in[2];
  const float* msg   = (const float*)d_in[3];
  const float* price = (const float*)d_in[4];
  // d_in[5] trade_t: unused by reference
  const int*   xst   = (const int*)d_in[6];
  const float* memory= (const float*)d_in[7];
  const float* lu    = (const float*)d_in[8];
  const float* w_t   = (const float*)d_in[9];
  const float* b_t   = (const float*)d_in[10];
  const float* W_ih  = (const float*)d_in[11];
  const float* b_ih  = (const float*)d_in[12];
  const float* W_hh  = (const float*)d_in[13];
  const float* b_hh  = (const float*)d_in[14];
  const float* party = (const float*)d_in[15];
  const float* state = (const float*)d_in[16];
  const float* W_sp  = (const float*)d_in[17];
  const float* b_sp  = (const float*)d_in[18];
  const float* W_ihl = (const float*)d_in[19];
  const float* W_hhl = (const float*)d_in[20];
  const float* b_ihl = (const float*)d_in[21];
  const float* b_hhl = (const float*)d_in[22];
  const float* W_pp  = (const float*)d_in[23];
  const float* b_pp  = (const float*)d_in[24];
  const float* W1    = (const float*)d_in[25];
  const float* b1    = (const float*)d_in[26];
  const float* W2    = (const float*)d_in[27];
  const float* b2    = (const float*)d_in[28];
  float* out = (float*)d_out;

  if (ws_size < WS_NEED) {              // loud failure: zero output
    (void)hipMemsetAsync(d_out, 0, (size_t)out_size*4, stream);
    return;
  }

  char* ws = (char*)d_ws;
  u64*   key  = (u64*)(ws + OFF_KEY);
  int*   cnt  = (int*)(ws + OFF_CNT);
  int*   list = (int*)(ws + OFF_LIST);
  float* uv   = (float*)(ws + OFF_UV);
  float* hn   = (float*)(ws + OFF_HN);
  float* A    = (float*)(ws + OFF_A);
  float* B    = (float*)(ws + OFF_B);
  float* c0   = (float*)(ws + OFF_C0);
  short* Wbf  = (short*)(ws + OFF_WBF);

  (void)hipMemsetAsync(ws, 0, OFF_LIST, stream);   // zero key[] + count
  k_scatter<<<(NE+255)/256, 256, 0, stream>>>(src, dst, t, key);
  k_compact<<<(NN+255)/256, 256, 0, stream>>>(key, list, cnt);
  k_pre<<<17, 256, 0, stream>>>(W1, W_sp, W_pp, b_sp, b_pp, b1, A, B, c0);
  k_prew<<<108, 256, 0, stream>>>(W_ih, W_hh, Wbf);
  k_lstm<<<(NE+63)/64, 256, 0, stream>>>(price, W_ihl, W_hhl, b_ihl, b_hhl, hn);
  k_gru<<<(NN+63)/64, 512, 0, stream>>>(key, list, cnt, src, dst, t, msg, memory, lu,
                                        w_t, b_t, Wbf, b_ih, b_hh, W1, uv);
  k_final<<<(NE+255)/256, 256, 0, stream>>>(src, dst, xst, party, state, uv, hn,
                                            A, B, c0, W2, b2, out);
}

// Round 18
// 536.002 us; speedup vs baseline: 4.2922x; 1.1301x over previous
//
#include <hip/hip_runtime.h>
#include <stdint.h>

#define NN    200000   // nodes
#define NE    100000   // edges
#define HD    128      // hidden/memory/time dim
#define EFD   64       // edge feat dim
#define NG    384      // 3*HD gates

typedef unsigned long long u64;
typedef short bf16x8 __attribute__((ext_vector_type(8)));   // 8 bf16 (4 VGPRs)
typedef float f32x4  __attribute__((ext_vector_type(4)));   // MFMA C/D frag

// ---- ws layout (bytes) ----
#define OFF_KEY   ((size_t)0)            // u64 * NN = 1,600,000
#define OFF_CNT   ((size_t)1600000)      // int
#define OFF_LIST  ((size_t)1600256)      // int * NN = 800,000
#define OFF_UV    ((size_t)2400256)      // float * NN*128 = 102,400,000
#define OFF_HN    ((size_t)104800256)    // float * NE*32 = 12,800,000
#define OFF_A     ((size_t)117600256)    // float * 2048
#define OFF_B     ((size_t)117608448)    // float * 2048
#define OFF_C0    ((size_t)117616640)    // float * 64 (+pad)
#define OFF_WBF   ((size_t)117616896)    // short: 9*384*64 (gates) + 128*128 (W1ab) = 237,568 shorts
#define WS_NEED   ((size_t)118092032)

#define W1OFF 221184   // short offset of W1ab section inside Wbf

__device__ __forceinline__ float frcp(float x){ return __builtin_amdgcn_rcpf(x); }
__device__ __forceinline__ float sigf(float x){ return frcp(1.f + __expf(-x)); }
__device__ __forceinline__ float tanhf_(float x){ return 1.f - 2.f*frcp(__expf(2.f*x) + 1.f); }
__device__ __forceinline__ float4 ld4(const float* p){ return *reinterpret_cast<const float4*>(p); }

// fp32 -> bf16 RNE (bit math; inputs finite)
__device__ __forceinline__ short f2bf(float f){
  unsigned u = __float_as_uint(f);
  u += 0x7fffu + ((u>>16)&1u);
  return (short)(u>>16);
}

// async global->LDS, 16B per lane; LDS dest = (first lane's ptr) + lane*16.
__device__ __forceinline__ void gl16(const void* g, void* l) {
  __builtin_amdgcn_global_load_lds(
      (const __attribute__((address_space(1))) void*)g,
      (__attribute__((address_space(3))) void*)l, 16, 0, 0);
}

// ---------- per-node winner key: max (t, isDst, e) ----------
__global__ void k_scatter(const int* __restrict__ src, const int* __restrict__ dst,
                          const int* __restrict__ t, u64* __restrict__ key) {
  int e = blockIdx.x*256 + threadIdx.x;
  if (e >= NE) return;
  u64 tt = (u64)(unsigned)(t[e] + 1);
  atomicMax(&key[src[e]], (tt<<18) | (u64)(unsigned)e);
  atomicMax(&key[dst[e]], (tt<<18) | (1ULL<<17) | (u64)(unsigned)e);
}

__global__ void k_compact(const u64* __restrict__ key, int* __restrict__ list,
                          int* __restrict__ count) {
  int n = blockIdx.x*256 + threadIdx.x;
  if (n >= NN) return;
  if (key[n] != 0ULL) { int p = atomicAdd(count, 1); list[p] = n; }
}

// ---------- fold W1/W_sp/W_pp/biases: A=W1a@W_sp, B=(W1b+W1c)@W_pp, c0 ----------
__global__ void k_pre(const float* __restrict__ W1, const float* __restrict__ W_sp,
                      const float* __restrict__ W_pp, const float* __restrict__ b_sp,
                      const float* __restrict__ b_pp, const float* __restrict__ b1,
                      float* __restrict__ A, float* __restrict__ B, float* __restrict__ c0)
{
  int tid = blockIdx.x*256 + threadIdx.x;
  if (tid < 2048) {
    int o = tid >> 5, j = tid & 31;
    float s = 0.f;
    for (int k = 0; k < 128; ++k) s = fmaf(W1[o*NG + k], W_sp[k*32 + j], s);
    A[tid] = s;
  } else if (tid < 4096) {
    int q = tid - 2048;
    int o = q >> 5, j = q & 31;
    float s = 0.f;
    for (int k = 0; k < 128; ++k)
      s = fmaf(W1[o*NG + 128 + k] + W1[o*NG + 256 + k], W_pp[k*32 + j], s);
    B[q] = s;
  } else if (tid < 4160) {
    int o = tid - 4096;
    float s = b1[o];
    for (int k = 0; k < 128; ++k) {
      s = fmaf(W1[o*NG + k], b_sp[k], s);
      s = fmaf(W1[o*NG + 128 + k] + W1[o*NG + 256 + k], b_pp[k], s);
    }
    c0[o] = s;
  }
}

// ---------- pre-convert weights to bf16, pre-swizzled for gl16 staging ----------
// Section 1 (idx < 27648): gate W chunks [9][384 n][8 slots][8] (slot s holds k8=s^(n&7))
// Section 2: W1ab [128 r][16 slots][8] (slot s holds k8=s^(r&15));
//   r<64 -> W1[r][k], r>=64 -> W1[r-64][128+k]
__global__ void k_prew(const float* __restrict__ W_ih, const float* __restrict__ W_hh,
                       const float* __restrict__ W1, short* __restrict__ Wbf)
{
  int idx = blockIdx.x*256 + threadIdx.x;
  if (idx < 9*384*8) {
    int s   = idx & 7;
    int n   = (idx >> 3) % 384;
    int ch9 = idx / (384*8);
    int k8  = s ^ (n & 7);
    int k   = ch9*64 + k8*8;
    short v[8];
    #pragma unroll
    for (int e = 0; e < 8; ++e) {
      int kk = k + e;
      float f = (kk < 448) ? W_ih[(size_t)n*448 + kk] : W_hh[(size_t)n*HD + (kk-448)];
      v[e] = f2bf(f);
    }
    *reinterpret_cast<bf16x8*>(Wbf + (size_t)ch9*24576 + n*64 + s*8) =
        *reinterpret_cast<bf16x8*>(v);
  } else if (idx < 9*384*8 + 128*16) {
    int idx2 = idx - 9*384*8;
    int s = idx2 & 15, r = idx2 >> 4;
    int k8 = s ^ (r & 15);
    int k = k8*8;
    short v[8];
    #pragma unroll
    for (int e = 0; e < 8; ++e) {
      int kk = k + e;
      float f = (r < 64) ? W1[(size_t)r*NG + kk] : W1[(size_t)(r-64)*NG + 128 + kk];
      v[e] = f2bf(f);
    }
    *reinterpret_cast<bf16x8*>(Wbf + W1OFF + r*128 + s*8) =
        *reinterpret_cast<bf16x8*>(v);
  }
}

// ---------- GRU via bf16 MFMA: 64 nodes/block, 512 thr = 8 waves ----------
// R18: uv-epilogue MFMA-ized. Main loop identical R17. After phases: gl16 W1ab
// (4 calls, overlaps nonlinearity VALU), Mn written as bf16 A-frags into LDS,
// uv = Mn @ W1ab^T via 16 MFMA/wave (wave w owns o-slice w*16..+16).
__global__ __launch_bounds__(512, 2) void k_gru(
    const u64* __restrict__ key, const int* __restrict__ list, const int* __restrict__ count,
    const int* __restrict__ src, const int* __restrict__ dst, const int* __restrict__ t,
    const float* __restrict__ msg, const float* __restrict__ memory,
    const float* __restrict__ last_update,
    const float* __restrict__ w_t, const float* __restrict__ b_t,
    const short* __restrict__ Wbf, const float* __restrict__ b_ih,
    const float* __restrict__ b_hh, float* __restrict__ uv)
{
  __shared__ short Wsb[24576];    // 48KB: W chunk [384 n][8 slots][8 bf16]
  __shared__ short Xsb[4096];     // 8KB: X chunk [64 node][8 slots][8 bf16]
  __shared__ float bias4[512];    // br|bz|bnx|bnm per h
  __shared__ int   sn_self[64];
  __shared__ int   sn_other[64];
  __shared__ int   sn_e[64];
  __shared__ float sn_dt[64];

  short* Mn2 = &Wsb[16384];       // bf16 Mn A-frags [64 node][16 slots][8] = 16KB

  int cnt = count[0];
  int base = blockIdx.x * 64;
  if (base >= cnt) return;
  int tid = threadIdx.x;
  int wid = tid >> 6, lane = tid & 63;
  int lr = lane & 15, lk = lane >> 4;    // fragment row/col & k-group

  if (tid < 64) {
    int idx = base + tid;
    int cl = idx < cnt ? idx : (cnt - 1);
    int n = list[cl];
    u64 k = key[n];
    int e   = (int)(k & 0x1FFFFULL);
    int isd = (int)((k >> 17) & 1ULL);
    sn_self[tid]  = n;
    sn_other[tid] = isd ? src[e] : dst[e];
    sn_e[tid]     = e;
    sn_dt[tid]    = (float)t[e] - last_update[n];
  }
  if (tid < 128) {
    int h = tid;
    bias4[h]       = b_ih[h]       + b_hh[h];
    bias4[128 + h] = b_ih[128 + h] + b_hh[128 + h];
    bias4[256 + h] = b_ih[256 + h];
    bias4[384 + h] = b_hh[256 + h];
  }
  __syncthreads();

  // accumulators: 4 M-tiles x {R,Z,NX,NM} for this wave's 16-h slice
  f32x4 aR[4], aZ[4], aNX[4], aNM[4];
  #pragma unroll
  for (int mt = 0; mt < 4; ++mt) { aR[mt] = (f32x4)0.f; aZ[mt] = (f32x4)0.f;
                                   aNX[mt] = (f32x4)0.f; aNM[mt] = (f32x4)0.f; }

  int node8 = tid >> 3, k8s = tid & 7;   // staging coords

  // ---- PROLOGUE: issue all 5 X gathers now (one latency exposure) ----
  float4 xA0, xB0, xA1, xB1, xA2, xB2, xA3, xB3, xA4, xB4;
  {
    const float* pSelf  = memory + (size_t)sn_self[node8]*HD  + k8s*8;
    const float* pOther = memory + (size_t)sn_other[node8]*HD + k8s*8;
    const float* pMsg   = msg + (size_t)sn_e[node8]*EFD + k8s*8;
    xA0 = ld4(pSelf);       xB0 = ld4(pSelf+4);
    xA1 = ld4(pSelf+64);    xB1 = ld4(pSelf+68);
    xA2 = ld4(pOther);      xB2 = ld4(pOther+4);
    xA3 = ld4(pOther+64);   xB3 = ld4(pOther+68);
    xA4 = ld4(pMsg);        xB4 = ld4(pMsg+4);
  }

  constexpr int WCH[9] = {0, 7, 1, 8, 2, 3, 4, 5, 6};
  constexpr int XST[9] = {0,-1, 1,-1, 2, 3, 4,-2,-2};

  int hrow = wid*16 + lr;                // W row within each 128-row gate block
  int swzH = (hrow & 7);

  #pragma unroll
  for (int p = 0; p < 9; ++p) {
    const int W = WCH[p];
    #pragma unroll
    for (int i = 0; i < 6; ++i) {
      int q = i*512 + tid;
      gl16(Wbf + (size_t)W*24576 + q*8, &Wsb[q*8]);
    }
    if (XST[p] >= 0) {
      float4 fa, fb;
      switch (XST[p]) {
        case 0: fa = xA0; fb = xB0; break;
        case 1: fa = xA1; fb = xB1; break;
        case 2: fa = xA2; fb = xB2; break;
        case 3: fa = xA3; fb = xB3; break;
        default: fa = xA4; fb = xB4; break;
      }
      short xs[8];
      xs[0]=f2bf(fa.x); xs[1]=f2bf(fa.y); xs[2]=f2bf(fa.z); xs[3]=f2bf(fa.w);
      xs[4]=f2bf(fb.x); xs[5]=f2bf(fb.y); xs[6]=f2bf(fb.z); xs[7]=f2bf(fb.w);
      *reinterpret_cast<bf16x8*>(&Xsb[node8*64 + ((k8s ^ (node8&7))<<3)]) =
          *reinterpret_cast<bf16x8*>(xs);
    } else if (XST[p] == -2) {
      int kk = (W == 6 ? 64 : 0) + k8s*8;
      float dt = sn_dt[node8];
      short xs[8];
      #pragma unroll
      for (int q = 0; q < 8; ++q) xs[q] = f2bf(cosf(fmaf(dt, w_t[kk+q], b_t[kk+q])));
      *reinterpret_cast<bf16x8*>(&Xsb[node8*64 + ((k8s ^ (node8&7))<<3)]) =
          *reinterpret_cast<bf16x8*>(xs);
    }
    __syncthreads();   // Wsb (gl16 drained) + Xsb ready

    #pragma unroll
    for (int ks = 0; ks < 2; ++ks) {
      int k8 = ks*4 + lk;
      int so = (k8 ^ swzH) << 3;
      bf16x8 bR = *reinterpret_cast<const bf16x8*>(&Wsb[(size_t)hrow*64 + so]);
      bf16x8 bZ = *reinterpret_cast<const bf16x8*>(&Wsb[(size_t)(128+hrow)*64 + so]);
      bf16x8 bN = *reinterpret_cast<const bf16x8*>(&Wsb[(size_t)(256+hrow)*64 + so]);
      #pragma unroll
      for (int mt = 0; mt < 4; ++mt) {
        int anode = mt*16 + lr;
        bf16x8 a = *reinterpret_cast<const bf16x8*>(&Xsb[anode*64 + ((k8 ^ (anode&7))<<3)]);
        aR[mt] = __builtin_amdgcn_mfma_f32_16x16x32_bf16(a, bR, aR[mt], 0, 0, 0);
        aZ[mt] = __builtin_amdgcn_mfma_f32_16x16x32_bf16(a, bZ, aZ[mt], 0, 0, 0);
        if (W < 7) aNX[mt] = __builtin_amdgcn_mfma_f32_16x16x32_bf16(a, bN, aNX[mt], 0, 0, 0);
        else       aNM[mt] = __builtin_amdgcn_mfma_f32_16x16x32_bf16(a, bN, aNM[mt], 0, 0, 0);
      }
    }
    __syncthreads();   // all reads of Wsb/Xsb done before next stage
  }

  // ---- stage W1ab (2048 quads via gl16, overlaps nonlinearity below) ----
  #pragma unroll
  for (int i = 0; i < 4; ++i) {
    int q = i*512 + tid;
    gl16(Wbf + W1OFF + q*8, &Wsb[q*8]);
  }

  // ---- GRU nonlinearity, lane-local; Mn -> bf16 A-frags at Mn2 ----
  {
    int h = hrow;
    int k8h = h >> 3, eh = h & 7;
    float br_ = bias4[h], bz_ = bias4[128+h], bnx_ = bias4[256+h], bnm_ = bias4[384+h];
    #pragma unroll
    for (int mt = 0; mt < 4; ++mt) {
      #pragma unroll
      for (int i = 0; i < 4; ++i) {
        int node = mt*16 + lk*4 + i;
        float r  = sigf(aR[mt][i] + br_);
        float z  = sigf(aZ[mt][i] + bz_);
        float nv = tanhf_(aNX[mt][i] + bnx_ + r*(aNM[mt][i] + bnm_));
        float m  = memory[(size_t)sn_self[node]*HD + h];
        Mn2[node*128 + ((k8h ^ (node&15))<<3) + eh] = f2bf((1.f - z)*nv + z*m);
      }
    }
  }
  __syncthreads();   // W1ab staged (vmcnt drained) + Mn2 complete

  // ---- uv = Mn @ W1ab^T via MFMA: wave wid owns o-rows wid*16..+16 ----
  {
    int orow = wid*16 + lr;
    f32x4 acc2[4];
    #pragma unroll
    for (int mt = 0; mt < 4; ++mt) acc2[mt] = (f32x4)0.f;
    #pragma unroll
    for (int kf = 0; kf < 4; ++kf) {
      int k8 = kf*4 + lk;
      bf16x8 b = *reinterpret_cast<const bf16x8*>(&Wsb[orow*128 + ((k8 ^ (orow&15))<<3)]);
      #pragma unroll
      for (int mt = 0; mt < 4; ++mt) {
        int anode = mt*16 + lr;
        bf16x8 a = *reinterpret_cast<const bf16x8*>(&Mn2[anode*128 + ((k8 ^ (anode&15))<<3)]);
        acc2[mt] = __builtin_amdgcn_mfma_f32_16x16x32_bf16(a, b, acc2[mt], 0, 0, 0);
      }
    }
    #pragma unroll
    for (int mt = 0; mt < 4; ++mt) {
      #pragma unroll
      for (int i = 0; i < 4; ++i) {
        int node = mt*16 + lk*4 + i;
        if (base + node < cnt)
          uv[(size_t)sn_self[node]*128 + orow] = acc2[mt][i];
      }
    }
  }
}

// ---------- price LSTM via bf16 MFMA: 64 edges/block, 4 waves x 16 edges ----------
__global__ __launch_bounds__(256) void k_lstm(
    const float* __restrict__ price, const float* __restrict__ W_ihl,
    const float* __restrict__ W_hhl, const float* __restrict__ b_ihl,
    const float* __restrict__ b_hhl, float* __restrict__ hn_out)
{
  __shared__ short Wb[4096];      // W_hh bf16 [128 rows][32 k] = 8KB
  __shared__ float ps[64*50];     // 12.8KB price rows
  __shared__ float hbuf[4][576];  // per-wave h [16 e][stride 36] = 9.2KB
  int tid = threadIdx.x;
  int lane = tid & 63, wid = tid >> 6;
  int lr = lane & 15, lk = lane >> 4;

  {
    int base = tid * 16;
    #pragma unroll
    for (int q = 0; q < 8; ++q) {
      float a = W_hhl[base + q*2], b = W_hhl[base + q*2 + 1];
      unsigned pk = (unsigned)(unsigned short)f2bf(a)
                  | ((unsigned)(unsigned short)f2bf(b) << 16);
      reinterpret_cast<unsigned*>(Wb)[tid*8 + q] = pk;
    }
  }
  int ebase = blockIdx.x * 64;
  int m = NE - ebase; if (m > 64) m = 64;
  for (int i = tid; i < 64*50; i += 256) {
    int r = i / 50, cidx = i % 50;
    int rr = r < m ? r : m - 1;
    ps[i] = price[(size_t)(ebase + rr)*50 + cidx];
  }
  __syncthreads();

  bf16x8 bw[8];
  float wih8[8], bias8[8];
  #pragma unroll
  for (int t = 0; t < 8; ++t) {
    int row = t*16 + lr;
    bw[t] = *reinterpret_cast<const bf16x8*>(&Wb[row*32 + lk*8]);
    wih8[t] = W_ihl[row];
    bias8[t] = b_ihl[row] + b_hhl[row];
  }

  int we = wid * 16;
  float* hb = hbuf[wid];

  float c8[4][2];
  #pragma unroll
  for (int i = 0; i < 4; ++i) { c8[i][0] = 0.f; c8[i][1] = 0.f; }
  bf16x8 afrag = {0,0,0,0,0,0,0,0};

  #pragma unroll 1
  for (int s = 0; s < 50; ++s) {
    float xv[4];
    #pragma unroll
    for (int i = 0; i < 4; ++i) xv[i] = ps[(we + lk*4 + i)*50 + s];
    f32x4 acc[8];
    #pragma unroll
    for (int t = 0; t < 8; ++t) {
      f32x4 ci;
      #pragma unroll
      for (int i = 0; i < 4; ++i) ci[i] = fmaf(xv[i], wih8[t], bias8[t]);
      acc[t] = __builtin_amdgcn_mfma_f32_16x16x32_bf16(afrag, bw[t], ci, 0, 0, 0);
    }
    #pragma unroll
    for (int i = 0; i < 4; ++i) {
      #pragma unroll
      for (int p = 0; p < 2; ++p) {
        float ig = sigf(acc[0+p][i]);
        float fg = sigf(acc[2+p][i]);
        float gg = tanhf_(acc[4+p][i]);
        float og = sigf(acc[6+p][i]);
        c8[i][p] = fmaf(fg, c8[i][p], ig*gg);
        float h = og * tanhf_(c8[i][p]);
        hb[(lk*4 + i)*36 + p*16 + lr] = h;
      }
    }
    asm volatile("s_waitcnt lgkmcnt(0)" ::: "memory");
    float4 h0 = *reinterpret_cast<const float4*>(&hb[lr*36 + lk*8]);
    float4 h1 = *reinterpret_cast<const float4*>(&hb[lr*36 + lk*8 + 4]);
    short hs[8];
    hs[0]=f2bf(h0.x); hs[1]=f2bf(h0.y); hs[2]=f2bf(h0.z); hs[3]=f2bf(h0.w);
    hs[4]=f2bf(h1.x); hs[5]=f2bf(h1.y); hs[6]=f2bf(h1.z); hs[7]=f2bf(h1.w);
    afrag = *reinterpret_cast<bf16x8*>(hs);
  }

  int e_g = ebase + we + lr;
  if (e_g < NE) {
    float4 h0 = *reinterpret_cast<const float4*>(&hb[lr*36 + lk*8]);
    float4 h1 = *reinterpret_cast<const float4*>(&hb[lr*36 + lk*8 + 4]);
    *reinterpret_cast<float4*>(hn_out + (size_t)e_g*32 + lk*8)     = h0;
    *reinterpret_cast<float4*>(hn_out + (size_t)e_g*32 + lk*8 + 4) = h1;
  }
}

// ---------- fused output: out = W2 @ relu(u[s] + v[d] + A@sf + B@hn + c0) + b2 ----------
__global__ __launch_bounds__(256) void k_final(
    const int* __restrict__ src, const int* __restrict__ dst, const int* __restrict__ xst,
    const float* __restrict__ party, const float* __restrict__ state,
    const float* __restrict__ uv, const float* __restrict__ hn,
    const float* __restrict__ A, const float* __restrict__ B, const float* __restrict__ c0,
    const float* __restrict__ W2, const float* __restrict__ b2, float* __restrict__ out)
{
  __shared__ float As[2048], Bs[2048], c0s[64], W2s[64];
  int tid = threadIdx.x;
  for (int i = tid; i < 2048; i += 256) { As[i] = A[i]; Bs[i] = B[i]; }
  if (tid < 64) { c0s[tid] = c0[tid]; W2s[tid] = W2[tid]; }
  __syncthreads();
  int e = blockIdx.x*256 + tid;
  if (e >= NE) return;
  int s = src[e], d = dst[e];
  int p = xst[2*s], stt = xst[2*s + 1];
  float4 sf4[8], hv4[8];
  #pragma unroll
  for (int i = 0; i < 4; ++i) sf4[i]   = ld4(party + p*16 + i*4);
  #pragma unroll
  for (int i = 0; i < 4; ++i) sf4[4+i] = ld4(state + stt*16 + i*4);
  #pragma unroll
  for (int i = 0; i < 8; ++i) hv4[i] = ld4(hn + (size_t)e*32 + i*4);
  const float* urow = uv + (size_t)s*128;
  const float* vrow = uv + (size_t)d*128 + 64;
  float oacc = b2[0];
  #pragma unroll 4
  for (int o4 = 0; o4 < 16; ++o4) {
    float4 u4 = ld4(urow + o4*4);
    float4 v4 = ld4(vrow + o4*4);
    float4 cc = *reinterpret_cast<const float4*>(&c0s[o4*4]);
    float4 w2 = *reinterpret_cast<const float4*>(&W2s[o4*4]);
    float hh[4] = {u4.x+v4.x+cc.x, u4.y+v4.y+cc.y, u4.z+v4.z+cc.z, u4.w+v4.w+cc.w};
    #pragma unroll
    for (int oo = 0; oo < 4; ++oo) {
      int o = o4*4 + oo;
      float acc = hh[oo];
      #pragma unroll
      for (int j4 = 0; j4 < 8; ++j4) {
        float4 a = *reinterpret_cast<const float4*>(&As[o*32 + j4*4]);
        float4 b = *reinterpret_cast<const float4*>(&Bs[o*32 + j4*4]);
        float4 sfv = sf4[j4], hvv = hv4[j4];
        acc = fmaf(a.x,sfv.x, fmaf(a.y,sfv.y, fmaf(a.z,sfv.z, fmaf(a.w,sfv.w, acc))));
        acc = fmaf(b.x,hvv.x, fmaf(b.y,hvv.y, fmaf(b.z,hvv.z, fmaf(b.w,hvv.w, acc))));
      }
      float w2v = (oo==0) ? w2.x : (oo==1) ? w2.y : (oo==2) ? w2.z : w2.w;
      oacc = fmaf(w2v, fmaxf(acc, 0.f), oacc);
    }
  }
  out[e] = oacc;
}

extern "C" void kernel_launch(void* const* d_in, const int* in_sizes, int n_in,
                              void* d_out, int out_size, void* d_ws, size_t ws_size,
                              hipStream_t stream) {
  const int*   src   = (const int*)d_in[0];
  const int*   dst   = (const int*)d_in[1];
  const int*   t     = (const int*)d_in[2];
  const float* msg   = (const float*)d_in[3];
  const float* price = (const float*)d_in[4];
  // d_in[5] trade_t: unused by reference
  const int*   xst   = (const int*)d_in[6];
  const float* memory= (const float*)d_in[7];
  const float* lu    = (const float*)d_in[8];
  const float* w_t   = (const float*)d_in[9];
  const float* b_t   = (const float*)d_in[10];
  const float* W_ih  = (const float*)d_in[11];
  const float* b_ih  = (const float*)d_in[12];
  const float* W_hh  = (const float*)d_in[13];
  const float* b_hh  = (const float*)d_in[14];
  const float* party = (const float*)d_in[15];
  const float* state = (const float*)d_in[16];
  const float* W_sp  = (const float*)d_in[17];
  const float* b_sp  = (const float*)d_in[18];
  const float* W_ihl = (const float*)d_in[19];
  const float* W_hhl = (const float*)d_in[20];
  const float* b_ihl = (const float*)d_in[21];
  const float* b_hhl = (const float*)d_in[22];
  const float* W_pp  = (const float*)d_in[23];
  const float* b_pp  = (const float*)d_in[24];
  const float* W1    = (const float*)d_in[25];
  const float* b1    = (const float*)d_in[26];
  const float* W2    = (const float*)d_in[27];
  const float* b2    = (const float*)d_in[28];
  float* out = (float*)d_out;

  if (ws_size < WS_NEED) {              // loud failure: zero output
    (void)hipMemsetAsync(d_out, 0, (size_t)out_size*4, stream);
    return;
  }

  char* ws = (char*)d_ws;
  u64*   key  = (u64*)(ws + OFF_KEY);
  int*   cnt  = (int*)(ws + OFF_CNT);
  int*   list = (int*)(ws + OFF_LIST);
  float* uv   = (float*)(ws + OFF_UV);
  float* hn   = (float*)(ws + OFF_HN);
  float* A    = (float*)(ws + OFF_A);
  float* B    = (float*)(ws + OFF_B);
  float* c0   = (float*)(ws + OFF_C0);
  short* Wbf  = (short*)(ws + OFF_WBF);

  (void)hipMemsetAsync(ws, 0, OFF_LIST, stream);   // zero key[] + count
  k_scatter<<<(NE+255)/256, 256, 0, stream>>>(src, dst, t, key);
  k_compact<<<(NN+255)/256, 256, 0, stream>>>(key, list, cnt);
  k_pre<<<17, 256, 0, stream>>>(W1, W_sp, W_pp, b_sp, b_pp, b1, A, B, c0);
  k_prew<<<116, 256, 0, stream>>>(W_ih, W_hh, W1, Wbf);
  k_lstm<<<(NE+63)/64, 256, 0, stream>>>(price, W_ihl, W_hhl, b_ihl, b_hhl, hn);
  k_gru<<<(NN+63)/64, 512, 0, stream>>>(key, list, cnt, src, dst, t, msg, memory, lu,
                                        w_t, b_t, Wbf, b_ih, b_hh, uv);
  k_final<<<(NE+255)/256, 256, 0, stream>>>(src, dst, xst, party, state, uv, hn,
                                            A, B, c0, W2, b2, out);
}

// Round 19
// 523.683 us; speedup vs baseline: 4.3931x; 1.0235x over previous
//
#include <hip/hip_runtime.h>
#include <stdint.h>

#define NN    200000   // nodes
#define NE    100000   // edges
#define HD    128      // hidden/memory/time dim
#define EFD   64       // edge feat dim
#define NG    384      // 3*HD gates

typedef unsigned long long u64;
typedef short bf16x8 __attribute__((ext_vector_type(8)));   // 8 bf16 (4 VGPRs)
typedef float f32x4  __attribute__((ext_vector_type(4)));   // MFMA C/D frag

// ---- ws layout (bytes) ----
#define OFF_KEY   ((size_t)0)            // u64 * NN = 1,600,000
#define OFF_CNT   ((size_t)1600000)      // int
#define OFF_LIST  ((size_t)1600256)      // int * NN = 800,000
#define OFF_UV    ((size_t)2400256)      // float * NN*128 = 102,400,000
#define OFF_HN    ((size_t)104800256)    // float * NE*32 = 12,800,000
#define OFF_A     ((size_t)117600256)    // float * 2048
#define OFF_B     ((size_t)117608448)    // float * 2048
#define OFF_C0    ((size_t)117616640)    // float * 64 (+pad)
#define OFF_WBF   ((size_t)117616896)    // short: 9*384*64 (gates) + 128*128 (W1ab) = 237,568 shorts
#define WS_NEED   ((size_t)118092032)

#define W1OFF 221184   // short offset of W1ab section inside Wbf

__device__ __forceinline__ float frcp(float x){ return __builtin_amdgcn_rcpf(x); }
__device__ __forceinline__ float sigf(float x){ return frcp(1.f + __expf(-x)); }
__device__ __forceinline__ float tanhf_(float x){ return 1.f - 2.f*frcp(__expf(2.f*x) + 1.f); }
__device__ __forceinline__ float4 ld4(const float* p){ return *reinterpret_cast<const float4*>(p); }

// fp32 -> bf16 RNE (bit math; inputs finite)
__device__ __forceinline__ short f2bf(float f){
  unsigned u = __float_as_uint(f);
  u += 0x7fffu + ((u>>16)&1u);
  return (short)(u>>16);
}

// pack 2 fp32 -> 1 u32 of 2 bf16 (hardware RNE)
__device__ __forceinline__ unsigned cvtpk(float lo, float hi){
  unsigned r;
  asm("v_cvt_pk_bf16_f32 %0, %1, %2" : "=v"(r) : "v"(lo), "v"(hi));
  return r;
}

// async global->LDS, 16B per lane; LDS dest = (first lane's ptr) + lane*16.
__device__ __forceinline__ void gl16(const void* g, void* l) {
  __builtin_amdgcn_global_load_lds(
      (const __attribute__((address_space(1))) void*)g,
      (__attribute__((address_space(3))) void*)l, 16, 0, 0);
}

// ---------- per-node winner key: max (t, isDst, e) ----------
__global__ void k_scatter(const int* __restrict__ src, const int* __restrict__ dst,
                          const int* __restrict__ t, u64* __restrict__ key) {
  int e = blockIdx.x*256 + threadIdx.x;
  if (e >= NE) return;
  u64 tt = (u64)(unsigned)(t[e] + 1);
  atomicMax(&key[src[e]], (tt<<18) | (u64)(unsigned)e);
  atomicMax(&key[dst[e]], (tt<<18) | (1ULL<<17) | (u64)(unsigned)e);
}

__global__ void k_compact(const u64* __restrict__ key, int* __restrict__ list,
                          int* __restrict__ count) {
  int n = blockIdx.x*256 + threadIdx.x;
  if (n >= NN) return;
  if (key[n] != 0ULL) { int p = atomicAdd(count, 1); list[p] = n; }
}

// ---------- fold W1/W_sp/W_pp/biases: A=W1a@W_sp, B=(W1b+W1c)@W_pp, c0 ----------
__global__ void k_pre(const float* __restrict__ W1, const float* __restrict__ W_sp,
                      const float* __restrict__ W_pp, const float* __restrict__ b_sp,
                      const float* __restrict__ b_pp, const float* __restrict__ b1,
                      float* __restrict__ A, float* __restrict__ B, float* __restrict__ c0)
{
  int tid = blockIdx.x*256 + threadIdx.x;
  if (tid < 2048) {
    int o = tid >> 5, j = tid & 31;
    float s = 0.f;
    for (int k = 0; k < 128; ++k) s = fmaf(W1[o*NG + k], W_sp[k*32 + j], s);
    A[tid] = s;
  } else if (tid < 4096) {
    int q = tid - 2048;
    int o = q >> 5, j = q & 31;
    float s = 0.f;
    for (int k = 0; k < 128; ++k)
      s = fmaf(W1[o*NG + 128 + k] + W1[o*NG + 256 + k], W_pp[k*32 + j], s);
    B[q] = s;
  } else if (tid < 4160) {
    int o = tid - 4096;
    float s = b1[o];
    for (int k = 0; k < 128; ++k) {
      s = fmaf(W1[o*NG + k], b_sp[k], s);
      s = fmaf(W1[o*NG + 128 + k] + W1[o*NG + 256 + k], b_pp[k], s);
    }
    c0[o] = s;
  }
}

// ---------- pre-convert weights to bf16, pre-swizzled for gl16 staging ----------
__global__ void k_prew(const float* __restrict__ W_ih, const float* __restrict__ W_hh,
                       const float* __restrict__ W1, short* __restrict__ Wbf)
{
  int idx = blockIdx.x*256 + threadIdx.x;
  if (idx < 9*384*8) {
    int s   = idx & 7;
    int n   = (idx >> 3) % 384;
    int ch9 = idx / (384*8);
    int k8  = s ^ (n & 7);
    int k   = ch9*64 + k8*8;
    short v[8];
    #pragma unroll
    for (int e = 0; e < 8; ++e) {
      int kk = k + e;
      float f = (kk < 448) ? W_ih[(size_t)n*448 + kk] : W_hh[(size_t)n*HD + (kk-448)];
      v[e] = f2bf(f);
    }
    *reinterpret_cast<bf16x8*>(Wbf + (size_t)ch9*24576 + n*64 + s*8) =
        *reinterpret_cast<bf16x8*>(v);
  } else if (idx < 9*384*8 + 128*16) {
    int idx2 = idx - 9*384*8;
    int s = idx2 & 15, r = idx2 >> 4;
    int k8 = s ^ (r & 15);
    int k = k8*8;
    short v[8];
    #pragma unroll
    for (int e = 0; e < 8; ++e) {
      int kk = k + e;
      float f = (r < 64) ? W1[(size_t)r*NG + kk] : W1[(size_t)(r-64)*NG + 128 + kk];
      v[e] = f2bf(f);
    }
    *reinterpret_cast<bf16x8*>(Wbf + W1OFF + r*128 + s*8) =
        *reinterpret_cast<bf16x8*>(v);
  }
}

// ---------- GRU via bf16 MFMA: 64 nodes/block, 512 thr = 8 waves (R18, verified) ----------
__global__ __launch_bounds__(512, 2) void k_gru(
    const u64* __restrict__ key, const int* __restrict__ list, const int* __restrict__ count,
    const int* __restrict__ src, const int* __restrict__ dst, const int* __restrict__ t,
    const float* __restrict__ msg, const float* __restrict__ memory,
    const float* __restrict__ last_update,
    const float* __restrict__ w_t, const float* __restrict__ b_t,
    const short* __restrict__ Wbf, const float* __restrict__ b_ih,
    const float* __restrict__ b_hh, float* __restrict__ uv)
{
  __shared__ short Wsb[24576];    // 48KB: W chunk [384 n][8 slots][8 bf16]
  __shared__ short Xsb[4096];     // 8KB: X chunk [64 node][8 slots][8 bf16]
  __shared__ float bias4[512];    // br|bz|bnx|bnm per h
  __shared__ int   sn_self[64];
  __shared__ int   sn_other[64];
  __shared__ int   sn_e[64];
  __shared__ float sn_dt[64];

  short* Mn2 = &Wsb[16384];       // bf16 Mn A-frags [64 node][16 slots][8] = 16KB

  int cnt = count[0];
  int base = blockIdx.x * 64;
  if (base >= cnt) return;
  int tid = threadIdx.x;
  int wid = tid >> 6, lane = tid & 63;
  int lr = lane & 15, lk = lane >> 4;    // fragment row/col & k-group

  if (tid < 64) {
    int idx = base + tid;
    int cl = idx < cnt ? idx : (cnt - 1);
    int n = list[cl];
    u64 k = key[n];
    int e   = (int)(k & 0x1FFFFULL);
    int isd = (int)((k >> 17) & 1ULL);
    sn_self[tid]  = n;
    sn_other[tid] = isd ? src[e] : dst[e];
    sn_e[tid]     = e;
    sn_dt[tid]    = (float)t[e] - last_update[n];
  }
  if (tid < 128) {
    int h = tid;
    bias4[h]       = b_ih[h]       + b_hh[h];
    bias4[128 + h] = b_ih[128 + h] + b_hh[128 + h];
    bias4[256 + h] = b_ih[256 + h];
    bias4[384 + h] = b_hh[256 + h];
  }
  __syncthreads();

  f32x4 aR[4], aZ[4], aNX[4], aNM[4];
  #pragma unroll
  for (int mt = 0; mt < 4; ++mt) { aR[mt] = (f32x4)0.f; aZ[mt] = (f32x4)0.f;
                                   aNX[mt] = (f32x4)0.f; aNM[mt] = (f32x4)0.f; }

  int node8 = tid >> 3, k8s = tid & 7;   // staging coords

  // ---- PROLOGUE: issue all 5 X gathers now (one latency exposure) ----
  float4 xA0, xB0, xA1, xB1, xA2, xB2, xA3, xB3, xA4, xB4;
  {
    const float* pSelf  = memory + (size_t)sn_self[node8]*HD  + k8s*8;
    const float* pOther = memory + (size_t)sn_other[node8]*HD + k8s*8;
    const float* pMsg   = msg + (size_t)sn_e[node8]*EFD + k8s*8;
    xA0 = ld4(pSelf);       xB0 = ld4(pSelf+4);
    xA1 = ld4(pSelf+64);    xB1 = ld4(pSelf+68);
    xA2 = ld4(pOther);      xB2 = ld4(pOther+4);
    xA3 = ld4(pOther+64);   xB3 = ld4(pOther+68);
    xA4 = ld4(pMsg);        xB4 = ld4(pMsg+4);
  }

  constexpr int WCH[9] = {0, 7, 1, 8, 2, 3, 4, 5, 6};
  constexpr int XST[9] = {0,-1, 1,-1, 2, 3, 4,-2,-2};

  int hrow = wid*16 + lr;
  int swzH = (hrow & 7);

  #pragma unroll
  for (int p = 0; p < 9; ++p) {
    const int W = WCH[p];
    #pragma unroll
    for (int i = 0; i < 6; ++i) {
      int q = i*512 + tid;
      gl16(Wbf + (size_t)W*24576 + q*8, &Wsb[q*8]);
    }
    if (XST[p] >= 0) {
      float4 fa, fb;
      switch (XST[p]) {
        case 0: fa = xA0; fb = xB0; break;
        case 1: fa = xA1; fb = xB1; break;
        case 2: fa = xA2; fb = xB2; break;
        case 3: fa = xA3; fb = xB3; break;
        default: fa = xA4; fb = xB4; break;
      }
      short xs[8];
      xs[0]=f2bf(fa.x); xs[1]=f2bf(fa.y); xs[2]=f2bf(fa.z); xs[3]=f2bf(fa.w);
      xs[4]=f2bf(fb.x); xs[5]=f2bf(fb.y); xs[6]=f2bf(fb.z); xs[7]=f2bf(fb.w);
      *reinterpret_cast<bf16x8*>(&Xsb[node8*64 + ((k8s ^ (node8&7))<<3)]) =
          *reinterpret_cast<bf16x8*>(xs);
    } else if (XST[p] == -2) {
      int kk = (W == 6 ? 64 : 0) + k8s*8;
      float dt = sn_dt[node8];
      short xs[8];
      #pragma unroll
      for (int q = 0; q < 8; ++q) xs[q] = f2bf(cosf(fmaf(dt, w_t[kk+q], b_t[kk+q])));
      *reinterpret_cast<bf16x8*>(&Xsb[node8*64 + ((k8s ^ (node8&7))<<3)]) =
          *reinterpret_cast<bf16x8*>(xs);
    }
    __syncthreads();   // Wsb (gl16 drained) + Xsb ready

    #pragma unroll
    for (int ks = 0; ks < 2; ++ks) {
      int k8 = ks*4 + lk;
      int so = (k8 ^ swzH) << 3;
      bf16x8 bR = *reinterpret_cast<const bf16x8*>(&Wsb[(size_t)hrow*64 + so]);
      bf16x8 bZ = *reinterpret_cast<const bf16x8*>(&Wsb[(size_t)(128+hrow)*64 + so]);
      bf16x8 bN = *reinterpret_cast<const bf16x8*>(&Wsb[(size_t)(256+hrow)*64 + so]);
      #pragma unroll
      for (int mt = 0; mt < 4; ++mt) {
        int anode = mt*16 + lr;
        bf16x8 a = *reinterpret_cast<const bf16x8*>(&Xsb[anode*64 + ((k8 ^ (anode&7))<<3)]);
        aR[mt] = __builtin_amdgcn_mfma_f32_16x16x32_bf16(a, bR, aR[mt], 0, 0, 0);
        aZ[mt] = __builtin_amdgcn_mfma_f32_16x16x32_bf16(a, bZ, aZ[mt], 0, 0, 0);
        if (W < 7) aNX[mt] = __builtin_amdgcn_mfma_f32_16x16x32_bf16(a, bN, aNX[mt], 0, 0, 0);
        else       aNM[mt] = __builtin_amdgcn_mfma_f32_16x16x32_bf16(a, bN, aNM[mt], 0, 0, 0);
      }
    }
    __syncthreads();
  }

  // ---- stage W1ab (2048 quads via gl16, overlaps nonlinearity below) ----
  #pragma unroll
  for (int i = 0; i < 4; ++i) {
    int q = i*512 + tid;
    gl16(Wbf + W1OFF + q*8, &Wsb[q*8]);
  }

  // ---- GRU nonlinearity, lane-local; Mn -> bf16 A-frags at Mn2 ----
  {
    int h = hrow;
    int k8h = h >> 3, eh = h & 7;
    float br_ = bias4[h], bz_ = bias4[128+h], bnx_ = bias4[256+h], bnm_ = bias4[384+h];
    #pragma unroll
    for (int mt = 0; mt < 4; ++mt) {
      #pragma unroll
      for (int i = 0; i < 4; ++i) {
        int node = mt*16 + lk*4 + i;
        float r  = sigf(aR[mt][i] + br_);
        float z  = sigf(aZ[mt][i] + bz_);
        float nv = tanhf_(aNX[mt][i] + bnx_ + r*(aNM[mt][i] + bnm_));
        float m  = memory[(size_t)sn_self[node]*HD + h];
        Mn2[node*128 + ((k8h ^ (node&15))<<3) + eh] = f2bf((1.f - z)*nv + z*m);
      }
    }
  }
  __syncthreads();   // W1ab staged (vmcnt drained) + Mn2 complete

  // ---- uv = Mn @ W1ab^T via MFMA: wave wid owns o-rows wid*16..+16 ----
  {
    int orow = wid*16 + lr;
    f32x4 acc2[4];
    #pragma unroll
    for (int mt = 0; mt < 4; ++mt) acc2[mt] = (f32x4)0.f;
    #pragma unroll
    for (int kf = 0; kf < 4; ++kf) {
      int k8 = kf*4 + lk;
      bf16x8 b = *reinterpret_cast<const bf16x8*>(&Wsb[orow*128 + ((k8 ^ (orow&15))<<3)]);
      #pragma unroll
      for (int mt = 0; mt < 4; ++mt) {
        int anode = mt*16 + lr;
        bf16x8 a = *reinterpret_cast<const bf16x8*>(&Mn2[anode*128 + ((k8 ^ (anode&15))<<3)]);
        acc2[mt] = __builtin_amdgcn_mfma_f32_16x16x32_bf16(a, b, acc2[mt], 0, 0, 0);
      }
    }
    #pragma unroll
    for (int mt = 0; mt < 4; ++mt) {
      #pragma unroll
      for (int i = 0; i < 4; ++i) {
        int node = mt*16 + lk*4 + i;
        if (base + node < cnt)
          uv[(size_t)sn_self[node]*128 + orow] = acc2[mt][i];
      }
    }
  }
}

// ---------- price LSTM via bf16 MFMA: 64 edges/block, 4 waves x 16 edges ----------
// R19: trans-pipe relief — 4 gate denominators share ONE rcp (5->2 rcp/gate-set);
// afrag pack via v_cvt_pk_bf16_f32 (4 inst vs ~24 bit-math).
__global__ __launch_bounds__(256) void k_lstm(
    const float* __restrict__ price, const float* __restrict__ W_ihl,
    const float* __restrict__ W_hhl, const float* __restrict__ b_ihl,
    const float* __restrict__ b_hhl, float* __restrict__ hn_out)
{
  __shared__ short Wb[4096];      // W_hh bf16 [128 rows][32 k] = 8KB
  __shared__ float ps[64*50];     // 12.8KB price rows
  __shared__ float hbuf[4][576];  // per-wave h [16 e][stride 36] = 9.2KB
  int tid = threadIdx.x;
  int lane = tid & 63, wid = tid >> 6;
  int lr = lane & 15, lk = lane >> 4;

  {
    int base = tid * 16;
    #pragma unroll
    for (int q = 0; q < 8; ++q) {
      unsigned pk = cvtpk(W_hhl[base + q*2], W_hhl[base + q*2 + 1]);
      reinterpret_cast<unsigned*>(Wb)[tid*8 + q] = pk;
    }
  }
  int ebase = blockIdx.x * 64;
  int m = NE - ebase; if (m > 64) m = 64;
  for (int i = tid; i < 64*50; i += 256) {
    int r = i / 50, cidx = i % 50;
    int rr = r < m ? r : m - 1;
    ps[i] = price[(size_t)(ebase + rr)*50 + cidx];
  }
  __syncthreads();

  bf16x8 bw[8];
  float wih8[8], bias8[8];
  #pragma unroll
  for (int t = 0; t < 8; ++t) {
    int row = t*16 + lr;
    bw[t] = *reinterpret_cast<const bf16x8*>(&Wb[row*32 + lk*8]);
    wih8[t] = W_ihl[row];
    bias8[t] = b_ihl[row] + b_hhl[row];
  }

  int we = wid * 16;
  float* hb = hbuf[wid];

  float c8[4][2];
  #pragma unroll
  for (int i = 0; i < 4; ++i) { c8[i][0] = 0.f; c8[i][1] = 0.f; }
  bf16x8 afrag = {0,0,0,0,0,0,0,0};

  #pragma unroll 1
  for (int s = 0; s < 50; ++s) {
    float xv[4];
    #pragma unroll
    for (int i = 0; i < 4; ++i) xv[i] = ps[(we + lk*4 + i)*50 + s];
    f32x4 acc[8];
    #pragma unroll
    for (int t = 0; t < 8; ++t) {
      f32x4 ci;
      #pragma unroll
      for (int i = 0; i < 4; ++i) ci[i] = fmaf(xv[i], wih8[t], bias8[t]);
      acc[t] = __builtin_amdgcn_mfma_f32_16x16x32_bf16(afrag, bw[t], ci, 0, 0, 0);
    }
    // gates with shared-rcp: denominators di,df,do,dg -> one rcp + muls
    #pragma unroll
    for (int i = 0; i < 4; ++i) {
      #pragma unroll
      for (int p = 0; p < 2; ++p) {
        float ei = __expf(-acc[0+p][i]);
        float ef = __expf(-acc[2+p][i]);
        float eg = __expf(2.f*acc[4+p][i]);
        float eo = __expf(-acc[6+p][i]);
        float di = 1.f + ei, df_ = 1.f + ef, dg = eg + 1.f, do_ = 1.f + eo;
        float m1 = di*df_, m2 = do_*dg;
        float R  = frcp(m1*m2);
        float ig = R*df_*m2;
        float fg = R*di*m2;
        float og = R*m1*dg;
        float gg = fmaf(-2.f, R*m1*do_, 1.f);
        c8[i][p] = fmaf(fg, c8[i][p], ig*gg);
        float th = 1.f - 2.f*frcp(__expf(2.f*c8[i][p]) + 1.f);
        hb[(lk*4 + i)*36 + p*16 + lr] = og*th;
      }
    }
    asm volatile("s_waitcnt lgkmcnt(0)" ::: "memory");
    float4 h0 = *reinterpret_cast<const float4*>(&hb[lr*36 + lk*8]);
    float4 h1 = *reinterpret_cast<const float4*>(&hb[lr*36 + lk*8 + 4]);
    unsigned pk_[4];
    pk_[0] = cvtpk(h0.x, h0.y);
    pk_[1] = cvtpk(h0.z, h0.w);
    pk_[2] = cvtpk(h1.x, h1.y);
    pk_[3] = cvtpk(h1.z, h1.w);
    afrag = *reinterpret_cast<bf16x8*>(pk_);
  }

  int e_g = ebase + we + lr;
  if (e_g < NE) {
    float4 h0 = *reinterpret_cast<const float4*>(&hb[lr*36 + lk*8]);
    float4 h1 = *reinterpret_cast<const float4*>(&hb[lr*36 + lk*8 + 4]);
    *reinterpret_cast<float4*>(hn_out + (size_t)e_g*32 + lk*8)     = h0;
    *reinterpret_cast<float4*>(hn_out + (size_t)e_g*32 + lk*8 + 4) = h1;
  }
}

// ---------- fused output: out = W2 @ relu(u[s] + v[d] + A@sf + B@hn + c0) + b2 ----------
__global__ __launch_bounds__(256) void k_final(
    const int* __restrict__ src, const int* __restrict__ dst, const int* __restrict__ xst,
    const float* __restrict__ party, const float* __restrict__ state,
    const float* __restrict__ uv, const float* __restrict__ hn,
    const float* __restrict__ A, const float* __restrict__ B, const float* __restrict__ c0,
    const float* __restrict__ W2, const float* __restrict__ b2, float* __restrict__ out)
{
  __shared__ float As[2048], Bs[2048], c0s[64], W2s[64];
  int tid = threadIdx.x;
  for (int i = tid; i < 2048; i += 256) { As[i] = A[i]; Bs[i] = B[i]; }
  if (tid < 64) { c0s[tid] = c0[tid]; W2s[tid] = W2[tid]; }
  __syncthreads();
  int e = blockIdx.x*256 + tid;
  if (e >= NE) return;
  int s = src[e], d = dst[e];
  int p = xst[2*s], stt = xst[2*s + 1];
  float4 sf4[8], hv4[8];
  #pragma unroll
  for (int i = 0; i < 4; ++i) sf4[i]   = ld4(party + p*16 + i*4);
  #pragma unroll
  for (int i = 0; i < 4; ++i) sf4[4+i] = ld4(state + stt*16 + i*4);
  #pragma unroll
  for (int i = 0; i < 8; ++i) hv4[i] = ld4(hn + (size_t)e*32 + i*4);
  const float* urow = uv + (size_t)s*128;
  const float* vrow = uv + (size_t)d*128 + 64;
  float oacc = b2[0];
  #pragma unroll 4
  for (int o4 = 0; o4 < 16; ++o4) {
    float4 u4 = ld4(urow + o4*4);
    float4 v4 = ld4(vrow + o4*4);
    float4 cc = *reinterpret_cast<const float4*>(&c0s[o4*4]);
    float4 w2 = *reinterpret_cast<const float4*>(&W2s[o4*4]);
    float hh[4] = {u4.x+v4.x+cc.x, u4.y+v4.y+cc.y, u4.z+v4.z+cc.z, u4.w+v4.w+cc.w};
    #pragma unroll
    for (int oo = 0; oo < 4; ++oo) {
      int o = o4*4 + oo;
      float acc = hh[oo];
      #pragma unroll
      for (int j4 = 0; j4 < 8; ++j4) {
        float4 a = *reinterpret_cast<const float4*>(&As[o*32 + j4*4]);
        float4 b = *reinterpret_cast<const float4*>(&Bs[o*32 + j4*4]);
        float4 sfv = sf4[j4], hvv = hv4[j4];
        acc = fmaf(a.x,sfv.x, fmaf(a.y,sfv.y, fmaf(a.z,sfv.z, fmaf(a.w,sfv.w, acc))));
        acc = fmaf(b.x,hvv.x, fmaf(b.y,hvv.y, fmaf(b.z,hvv.z, fmaf(b.w,hvv.w, acc))));
      }
      float w2v = (oo==0) ? w2.x : (oo==1) ? w2.y : (oo==2) ? w2.z : w2.w;
      oacc = fmaf(w2v, fmaxf(acc, 0.f), oacc);
    }
  }
  out[e] = oacc;
}

extern "C" void kernel_launch(void* const* d_in, const int* in_sizes, int n_in,
                              void* d_out, int out_size, void* d_ws, size_t ws_size,
                              hipStream_t stream) {
  const int*   src   = (const int*)d_in[0];
  const int*   dst   = (const int*)d_in[1];
  const int*   t     = (const int*)d_in[2];
  const float* msg   = (const float*)d_in[3];
  const float* price = (const float*)d_in[4];
  // d_in[5] trade_t: unused by reference
  const int*   xst   = (const int*)d_in[6];
  const float* memory= (const float*)d_in[7];
  const float* lu    = (const float*)d_in[8];
  const float* w_t   = (const float*)d_in[9];
  const float* b_t   = (const float*)d_in[10];
  const float* W_ih  = (const float*)d_in[11];
  const float* b_ih  = (const float*)d_in[12];
  const float* W_hh  = (const float*)d_in[13];
  const float* b_hh  = (const float*)d_in[14];
  const float* party = (const float*)d_in[15];
  const float* state = (const float*)d_in[16];
  const float* W_sp  = (const float*)d_in[17];
  const float* b_sp  = (const float*)d_in[18];
  const float* W_ihl = (const float*)d_in[19];
  const float* W_hhl = (const float*)d_in[20];
  const float* b_ihl = (const float*)d_in[21];
  const float* b_hhl = (const float*)d_in[22];
  const float* W_pp  = (const float*)d_in[23];
  const float* b_pp  = (const float*)d_in[24];
  const float* W1    = (const float*)d_in[25];
  const float* b1    = (const float*)d_in[26];
  const float* W2    = (const float*)d_in[27];
  const float* b2    = (const float*)d_in[28];
  float* out = (float*)d_out;

  if (ws_size < WS_NEED) {              // loud failure: zero output
    (void)hipMemsetAsync(d_out, 0, (size_t)out_size*4, stream);
    return;
  }

  char* ws = (char*)d_ws;
  u64*   key  = (u64*)(ws + OFF_KEY);
  int*   cnt  = (int*)(ws + OFF_CNT);
  int*   list = (int*)(ws + OFF_LIST);
  float* uv   = (float*)(ws + OFF_UV);
  float* hn   = (float*)(ws + OFF_HN);
  float* A    = (float*)(ws + OFF_A);
  float* B    = (float*)(ws + OFF_B);
  float* c0   = (float*)(ws + OFF_C0);
  short* Wbf  = (short*)(ws + OFF_WBF);

  (void)hipMemsetAsync(ws, 0, OFF_LIST, stream);   // zero key[] + count
  k_scatter<<<(NE+255)/256, 256, 0, stream>>>(src, dst, t, key);
  k_compact<<<(NN+255)/256, 256, 0, stream>>>(key, list, cnt);
  k_pre<<<17, 256, 0, stream>>>(W1, W_sp, W_pp, b_sp, b_pp, b1, A, B, c0);
  k_prew<<<116, 256, 0, stream>>>(W_ih, W_hh, W1, Wbf);
  k_lstm<<<(NE+63)/64, 256, 0, stream>>>(price, W_ihl, W_hhl, b_ihl, b_hhl, hn);
  k_gru<<<(NN+63)/64, 512, 0, stream>>>(key, list, cnt, src, dst, t, msg, memory, lu,
                                        w_t, b_t, Wbf, b_ih, b_hh, uv);
  k_final<<<(NE+255)/256, 256, 0, stream>>>(src, dst, xst, party, state, uv, hn,
                                            A, B, c0, W2, b2, out);
}

// Round 20
// 475.589 us; speedup vs baseline: 4.8374x; 1.1011x over previous
//
#include <hip/hip_runtime.h>
#include <stdint.h>

#define NN    200000
#define NE    100000
#define HD    128
#define EFD   64
#define NG    384

typedef unsigned long long u64;
typedef short bf16x8 __attribute__((ext_vector_type(8)));
typedef float f32x4  __attribute__((ext_vector_type(4)));

#define OFF_KEY   ((size_t)0)
#define OFF_CNT   ((size_t)1600000)
#define OFF_LIST  ((size_t)1600256)
#define OFF_UV    ((size_t)2400256)
#define OFF_HN    ((size_t)104800256)
#define OFF_A     ((size_t)117600256)
#define OFF_B     ((size_t)117608448)
#define OFF_C0    ((size_t)117616640)
#define OFF_WBF   ((size_t)117616896)
#define WS_NEED   ((size_t)118092032)

#define W1OFF 221184
#define GRUB  3128      // GRU virtual blocks covered by interleave (>= 3125)
#define LSTB  782       // LSTM blocks (128 edges each)

__device__ __forceinline__ float frcp(float x){ return __builtin_amdgcn_rcpf(x); }
__device__ __forceinline__ float sigf(float x){ return frcp(1.f + __expf(-x)); }
__device__ __forceinline__ float tanhf_(float x){ return 1.f - 2.f*frcp(__expf(2.f*x) + 1.f); }
__device__ __forceinline__ float4 ld4(const float* p){ return *reinterpret_cast<const float4*>(p); }

__device__ __forceinline__ short f2bf(float f){
  unsigned u = __float_as_uint(f);
  u += 0x7fffu + ((u>>16)&1u);
  return (short)(u>>16);
}
__device__ __forceinline__ unsigned cvtpk(float lo, float hi){
  unsigned r;
  asm("v_cvt_pk_bf16_f32 %0, %1, %2" : "=v"(r) : "v"(lo), "v"(hi));
  return r;
}
__device__ __forceinline__ void gl16(const void* g, void* l) {
  __builtin_amdgcn_global_load_lds(
      (const __attribute__((address_space(1))) void*)g,
      (__attribute__((address_space(3))) void*)l, 16, 0, 0);
}

__global__ void k_scatter(const int* __restrict__ src, const int* __restrict__ dst,
                          const int* __restrict__ t, u64* __restrict__ key) {
  int e = blockIdx.x*256 + threadIdx.x;
  if (e >= NE) return;
  u64 tt = (u64)(unsigned)(t[e] + 1);
  atomicMax(&key[src[e]], (tt<<18) | (u64)(unsigned)e);
  atomicMax(&key[dst[e]], (tt<<18) | (1ULL<<17) | (u64)(unsigned)e);
}

__global__ void k_compact(const u64* __restrict__ key, int* __restrict__ list,
                          int* __restrict__ count) {
  int n = blockIdx.x*256 + threadIdx.x;
  if (n >= NN) return;
  if (key[n] != 0ULL) { int p = atomicAdd(count, 1); list[p] = n; }
}

__global__ void k_pre(const float* __restrict__ W1, const float* __restrict__ W_sp,
                      const float* __restrict__ W_pp, const float* __restrict__ b_sp,
                      const float* __restrict__ b_pp, const float* __restrict__ b1,
                      float* __restrict__ A, float* __restrict__ B, float* __restrict__ c0)
{
  int tid = blockIdx.x*256 + threadIdx.x;
  if (tid < 2048) {
    int o = tid >> 5, j = tid & 31;
    float s = 0.f;
    for (int k = 0; k < 128; ++k) s = fmaf(W1[o*NG + k], W_sp[k*32 + j], s);
    A[tid] = s;
  } else if (tid < 4096) {
    int q = tid - 2048;
    int o = q >> 5, j = q & 31;
    float s = 0.f;
    for (int k = 0; k < 128; ++k)
      s = fmaf(W1[o*NG + 128 + k] + W1[o*NG + 256 + k], W_pp[k*32 + j], s);
    B[q] = s;
  } else if (tid < 4160) {
    int o = tid - 4096;
    float s = b1[o];
    for (int k = 0; k < 128; ++k) {
      s = fmaf(W1[o*NG + k], b_sp[k], s);
      s = fmaf(W1[o*NG + 128 + k] + W1[o*NG + 256 + k], b_pp[k], s);
    }
    c0[o] = s;
  }
}

__global__ void k_prew(const float* __restrict__ W_ih, const float* __restrict__ W_hh,
                       const float* __restrict__ W1, short* __restrict__ Wbf)
{
  int idx = blockIdx.x*256 + threadIdx.x;
  if (idx < 9*384*8) {
    int s   = idx & 7;
    int n   = (idx >> 3) % 384;
    int ch9 = idx / (384*8);
    int k8  = s ^ (n & 7);
    int k   = ch9*64 + k8*8;
    short v[8];
    #pragma unroll
    for (int e = 0; e < 8; ++e) {
      int kk = k + e;
      float f = (kk < 448) ? W_ih[(size_t)n*448 + kk] : W_hh[(size_t)n*HD + (kk-448)];
      v[e] = f2bf(f);
    }
    *reinterpret_cast<bf16x8*>(Wbf + (size_t)ch9*24576 + n*64 + s*8) =
        *reinterpret_cast<bf16x8*>(v);
  } else if (idx < 9*384*8 + 128*16) {
    int idx2 = idx - 9*384*8;
    int s = idx2 & 15, r = idx2 >> 4;
    int k8 = s ^ (r & 15);
    int k = k8*8;
    short v[8];
    #pragma unroll
    for (int e = 0; e < 8; ++e) {
      int kk = k + e;
      float f = (r < 64) ? W1[(size_t)r*NG + kk] : W1[(size_t)(r-64)*NG + 128 + kk];
      v[e] = f2bf(f);
    }
    *reinterpret_cast<bf16x8*>(Wbf + W1OFF + r*128 + s*8) =
        *reinterpret_cast<bf16x8*>(v);
  }
}

// ---------- FUSED GRU + LSTM: 512 thr; bid%5==4 -> LSTM(128 edges), else GRU ----------
__global__ __launch_bounds__(512, 2) void k_gl(
    const u64* __restrict__ key, const int* __restrict__ list, const int* __restrict__ count,
    const int* __restrict__ src, const int* __restrict__ dst, const int* __restrict__ t,
    const float* __restrict__ msg, const float* __restrict__ memory,
    const float* __restrict__ last_update,
    const float* __restrict__ w_t, const float* __restrict__ b_t,
    const short* __restrict__ Wbf, const float* __restrict__ b_ih,
    const float* __restrict__ b_hh, float* __restrict__ uv,
    const float* __restrict__ price, const float* __restrict__ W_ihl,
    const float* __restrict__ W_hhl, const float* __restrict__ b_ihl,
    const float* __restrict__ b_hhl, float* __restrict__ hn_out)
{
  __shared__ char lds[60416];    // arena, carved per role
  int bid = blockIdx.x;
  int tid = threadIdx.x;
  int wid = tid >> 6, lane = tid & 63;
  int lr = lane & 15, lk = lane >> 4;

  if (bid % 5 != 4) {
    // ================= GRU role (virtual block g) =================
    int g = (bid/5)*4 + (bid%5);
    short* Wsb   = reinterpret_cast<short*>(lds);            // 48KB
    short* Xsb   = reinterpret_cast<short*>(lds + 49152);    // 8KB
    float* bias4 = reinterpret_cast<float*>(lds + 57344);    // 2KB
    int*   sn_self  = reinterpret_cast<int*>(lds + 59392);
    int*   sn_other = reinterpret_cast<int*>(lds + 59648);
    int*   sn_e     = reinterpret_cast<int*>(lds + 59904);
    float* sn_dt    = reinterpret_cast<float*>(lds + 60160);
    short* Mn2 = &Wsb[16384];

    int cnt = count[0];
    int base = g * 64;
    if (base >= cnt) return;

    if (tid < 64) {
      int idx = base + tid;
      int cl = idx < cnt ? idx : (cnt - 1);
      int n = list[cl];
      u64 k = key[n];
      int e   = (int)(k & 0x1FFFFULL);
      int isd = (int)((k >> 17) & 1ULL);
      sn_self[tid]  = n;
      sn_other[tid] = isd ? src[e] : dst[e];
      sn_e[tid]     = e;
      sn_dt[tid]    = (float)t[e] - last_update[n];
    }
    if (tid < 128) {
      int h = tid;
      bias4[h]       = b_ih[h]       + b_hh[h];
      bias4[128 + h] = b_ih[128 + h] + b_hh[128 + h];
      bias4[256 + h] = b_ih[256 + h];
      bias4[384 + h] = b_hh[256 + h];
    }
    __syncthreads();

    f32x4 aR[4], aZ[4], aNX[4], aNM[4];
    #pragma unroll
    for (int mt = 0; mt < 4; ++mt) { aR[mt] = (f32x4)0.f; aZ[mt] = (f32x4)0.f;
                                     aNX[mt] = (f32x4)0.f; aNM[mt] = (f32x4)0.f; }

    int node8 = tid >> 3, k8s = tid & 7;

    float4 xA0, xB0, xA1, xB1, xA2, xB2, xA3, xB3, xA4, xB4;
    {
      const float* pSelf  = memory + (size_t)sn_self[node8]*HD  + k8s*8;
      const float* pOther = memory + (size_t)sn_other[node8]*HD + k8s*8;
      const float* pMsg   = msg + (size_t)sn_e[node8]*EFD + k8s*8;
      xA0 = ld4(pSelf);       xB0 = ld4(pSelf+4);
      xA1 = ld4(pSelf+64);    xB1 = ld4(pSelf+68);
      xA2 = ld4(pOther);      xB2 = ld4(pOther+4);
      xA3 = ld4(pOther+64);   xB3 = ld4(pOther+68);
      xA4 = ld4(pMsg);        xB4 = ld4(pMsg+4);
    }

    constexpr int WCH[9] = {0, 7, 1, 8, 2, 3, 4, 5, 6};
    constexpr int XST[9] = {0,-1, 1,-1, 2, 3, 4,-2,-2};

    int hrow = wid*16 + lr;
    int swzH = (hrow & 7);

    #pragma unroll
    for (int p = 0; p < 9; ++p) {
      const int W = WCH[p];
      #pragma unroll
      for (int i = 0; i < 6; ++i) {
        int q = i*512 + tid;
        gl16(Wbf + (size_t)W*24576 + q*8, &Wsb[q*8]);
      }
      if (XST[p] >= 0) {
        float4 fa, fb;
        switch (XST[p]) {
          case 0: fa = xA0; fb = xB0; break;
          case 1: fa = xA1; fb = xB1; break;
          case 2: fa = xA2; fb = xB2; break;
          case 3: fa = xA3; fb = xB3; break;
          default: fa = xA4; fb = xB4; break;
        }
        short xs[8];
        xs[0]=f2bf(fa.x); xs[1]=f2bf(fa.y); xs[2]=f2bf(fa.z); xs[3]=f2bf(fa.w);
        xs[4]=f2bf(fb.x); xs[5]=f2bf(fb.y); xs[6]=f2bf(fb.z); xs[7]=f2bf(fb.w);
        *reinterpret_cast<bf16x8*>(&Xsb[node8*64 + ((k8s ^ (node8&7))<<3)]) =
            *reinterpret_cast<bf16x8*>(xs);
      } else if (XST[p] == -2) {
        int kk = (W == 6 ? 64 : 0) + k8s*8;
        float dt = sn_dt[node8];
        short xs[8];
        #pragma unroll
        for (int q = 0; q < 8; ++q) xs[q] = f2bf(cosf(fmaf(dt, w_t[kk+q], b_t[kk+q])));
        *reinterpret_cast<bf16x8*>(&Xsb[node8*64 + ((k8s ^ (node8&7))<<3)]) =
            *reinterpret_cast<bf16x8*>(xs);
      }
      __syncthreads();

      #pragma unroll
      for (int ks = 0; ks < 2; ++ks) {
        int k8 = ks*4 + lk;
        int so = (k8 ^ swzH) << 3;
        bf16x8 bR = *reinterpret_cast<const bf16x8*>(&Wsb[(size_t)hrow*64 + so]);
        bf16x8 bZ = *reinterpret_cast<const bf16x8*>(&Wsb[(size_t)(128+hrow)*64 + so]);
        bf16x8 bN = *reinterpret_cast<const bf16x8*>(&Wsb[(size_t)(256+hrow)*64 + so]);
        #pragma unroll
        for (int mt = 0; mt < 4; ++mt) {
          int anode = mt*16 + lr;
          bf16x8 a = *reinterpret_cast<const bf16x8*>(&Xsb[anode*64 + ((k8 ^ (anode&7))<<3)]);
          aR[mt] = __builtin_amdgcn_mfma_f32_16x16x32_bf16(a, bR, aR[mt], 0, 0, 0);
          aZ[mt] = __builtin_amdgcn_mfma_f32_16x16x32_bf16(a, bZ, aZ[mt], 0, 0, 0);
          if (W < 7) aNX[mt] = __builtin_amdgcn_mfma_f32_16x16x32_bf16(a, bN, aNX[mt], 0, 0, 0);
          else       aNM[mt] = __builtin_amdgcn_mfma_f32_16x16x32_bf16(a, bN, aNM[mt], 0, 0, 0);
        }
      }
      __syncthreads();
    }

    #pragma unroll
    for (int i = 0; i < 4; ++i) {
      int q = i*512 + tid;
      gl16(Wbf + W1OFF + q*8, &Wsb[q*8]);
    }

    {
      int h = hrow;
      int k8h = h >> 3, eh = h & 7;
      float br_ = bias4[h], bz_ = bias4[128+h], bnx_ = bias4[256+h], bnm_ = bias4[384+h];
      #pragma unroll
      for (int mt = 0; mt < 4; ++mt) {
        #pragma unroll
        for (int i = 0; i < 4; ++i) {
          int node = mt*16 + lk*4 + i;
          float r  = sigf(aR[mt][i] + br_);
          float z  = sigf(aZ[mt][i] + bz_);
          float nv = tanhf_(aNX[mt][i] + bnx_ + r*(aNM[mt][i] + bnm_));
          float m  = memory[(size_t)sn_self[node]*HD + h];
          Mn2[node*128 + ((k8h ^ (node&15))<<3) + eh] = f2bf((1.f - z)*nv + z*m);
        }
      }
    }
    __syncthreads();

    {
      int orow = wid*16 + lr;
      f32x4 acc2[4];
      #pragma unroll
      for (int mt = 0; mt < 4; ++mt) acc2[mt] = (f32x4)0.f;
      #pragma unroll
      for (int kf = 0; kf < 4; ++kf) {
        int k8 = kf*4 + lk;
        bf16x8 b = *reinterpret_cast<const bf16x8*>(&Wsb[orow*128 + ((k8 ^ (orow&15))<<3)]);
        #pragma unroll
        for (int mt = 0; mt < 4; ++mt) {
          int anode = mt*16 + lr;
          bf16x8 a = *reinterpret_cast<const bf16x8*>(&Mn2[anode*128 + ((k8 ^ (anode&15))<<3)]);
          acc2[mt] = __builtin_amdgcn_mfma_f32_16x16x32_bf16(a, b, acc2[mt], 0, 0, 0);
        }
      }
      #pragma unroll
      for (int mt = 0; mt < 4; ++mt) {
        #pragma unroll
        for (int i = 0; i < 4; ++i) {
          int node = mt*16 + lk*4 + i;
          if (base + node < cnt)
            uv[(size_t)sn_self[node]*128 + orow] = acc2[mt][i];
        }
      }
    }
  } else {
    // ================= LSTM role (block l, 128 edges, 8 waves) =================
    int l = bid / 5;
    if (l >= LSTB) return;
    short* Wb   = reinterpret_cast<short*>(lds);             // 8KB
    float* ps   = reinterpret_cast<float*>(lds + 8192);      // 25.6KB
    float* hbuf = reinterpret_cast<float*>(lds + 33792);     // 18.4KB (8 x 576)

    {
      int base = tid * 8;
      #pragma unroll
      for (int q = 0; q < 4; ++q) {
        unsigned pk = cvtpk(W_hhl[base + q*2], W_hhl[base + q*2 + 1]);
        reinterpret_cast<unsigned*>(Wb)[tid*4 + q] = pk;
      }
    }
    int ebase = l * 128;
    int m = NE - ebase; if (m > 128) m = 128;
    for (int i = tid; i < 128*50; i += 512) {
      int r = i / 50, cidx = i % 50;
      int rr = r < m ? r : m - 1;
      ps[i] = price[(size_t)(ebase + rr)*50 + cidx];
    }
    __syncthreads();

    bf16x8 bw[8];
    float wih8[8], bias8[8];
    #pragma unroll
    for (int tI = 0; tI < 8; ++tI) {
      int row = tI*16 + lr;
      bw[tI] = *reinterpret_cast<const bf16x8*>(&Wb[row*32 + lk*8]);
      wih8[tI] = W_ihl[row];
      bias8[tI] = b_ihl[row] + b_hhl[row];
    }

    int we = wid * 16;
    float* hb = hbuf + wid*576;

    float c8[4][2];
    #pragma unroll
    for (int i = 0; i < 4; ++i) { c8[i][0] = 0.f; c8[i][1] = 0.f; }
    bf16x8 afrag = {0,0,0,0,0,0,0,0};

    #pragma unroll 1
    for (int s = 0; s < 50; ++s) {
      float xv[4];
      #pragma unroll
      for (int i = 0; i < 4; ++i) xv[i] = ps[(we + lk*4 + i)*50 + s];
      f32x4 acc[8];
      #pragma unroll
      for (int tI = 0; tI < 8; ++tI) {
        f32x4 ci;
        #pragma unroll
        for (int i = 0; i < 4; ++i) ci[i] = fmaf(xv[i], wih8[tI], bias8[tI]);
        acc[tI] = __builtin_amdgcn_mfma_f32_16x16x32_bf16(afrag, bw[tI], ci, 0, 0, 0);
      }
      #pragma unroll
      for (int i = 0; i < 4; ++i) {
        #pragma unroll
        for (int p = 0; p < 2; ++p) {
          float ei = __expf(-acc[0+p][i]);
          float ef = __expf(-acc[2+p][i]);
          float eg = __expf(2.f*acc[4+p][i]);
          float eo = __expf(-acc[6+p][i]);
          float di = 1.f + ei, df_ = 1.f + ef, dg = eg + 1.f, do_ = 1.f + eo;
          float m1 = di*df_, m2 = do_*dg;
          float R  = frcp(m1*m2);
          float ig = R*df_*m2;
          float fg = R*di*m2;
          float og = R*m1*dg;
          float gg = fmaf(-2.f, R*m1*do_, 1.f);
          c8[i][p] = fmaf(fg, c8[i][p], ig*gg);
          float th = 1.f - 2.f*frcp(__expf(2.f*c8[i][p]) + 1.f);
          hb[(lk*4 + i)*36 + p*16 + lr] = og*th;
        }
      }
      asm volatile("s_waitcnt lgkmcnt(0)" ::: "memory");
      float4 h0 = *reinterpret_cast<const float4*>(&hb[lr*36 + lk*8]);
      float4 h1 = *reinterpret_cast<const float4*>(&hb[lr*36 + lk*8 + 4]);
      unsigned pk_[4];
      pk_[0] = cvtpk(h0.x, h0.y);
      pk_[1] = cvtpk(h0.z, h0.w);
      pk_[2] = cvtpk(h1.x, h1.y);
      pk_[3] = cvtpk(h1.z, h1.w);
      afrag = *reinterpret_cast<bf16x8*>(pk_);
    }

    int e_g = ebase + we + lr;
    if (e_g < NE) {
      float4 h0 = *reinterpret_cast<const float4*>(&hb[lr*36 + lk*8]);
      float4 h1 = *reinterpret_cast<const float4*>(&hb[lr*36 + lk*8 + 4]);
      *reinterpret_cast<float4*>(hn_out + (size_t)e_g*32 + lk*8)     = h0;
      *reinterpret_cast<float4*>(hn_out + (size_t)e_g*32 + lk*8 + 4) = h1;
    }
  }
}

// ---------- fused output ----------
__global__ __launch_bounds__(256) void k_final(
    const int* __restrict__ src, const int* __restrict__ dst, const int* __restrict__ xst,
    const float* __restrict__ party, const float* __restrict__ state,
    const float* __restrict__ uv, const float* __restrict__ hn,
    const float* __restrict__ A, const float* __restrict__ B, const float* __restrict__ c0,
    const float* __restrict__ W2, const float* __restrict__ b2, float* __restrict__ out)
{
  __shared__ float As[2048], Bs[2048], c0s[64], W2s[64];
  int tid = threadIdx.x;
  for (int i = tid; i < 2048; i += 256) { As[i] = A[i]; Bs[i] = B[i]; }
  if (tid < 64) { c0s[tid] = c0[tid]; W2s[tid] = W2[tid]; }
  __syncthreads();
  int e = blockIdx.x*256 + tid;
  if (e >= NE) return;
  int s = src[e], d = dst[e];
  int p = xst[2*s], stt = xst[2*s + 1];
  float4 sf4[8], hv4[8];
  #pragma unroll
  for (int i = 0; i < 4; ++i) sf4[i]   = ld4(party + p*16 + i*4);
  #pragma unroll
  for (int i = 0; i < 4; ++i) sf4[4+i] = ld4(state + stt*16 + i*4);
  #pragma unroll
  for (int i = 0; i < 8; ++i) hv4[i] = ld4(hn + (size_t)e*32 + i*4);
  const float* urow = uv + (size_t)s*128;
  const float* vrow = uv + (size_t)d*128 + 64;
  float oacc = b2[0];
  #pragma unroll 4
  for (int o4 = 0; o4 < 16; ++o4) {
    float4 u4 = ld4(urow + o4*4);
    float4 v4 = ld4(vrow + o4*4);
    float4 cc = *reinterpret_cast<const float4*>(&c0s[o4*4]);
    float4 w2 = *reinterpret_cast<const float4*>(&W2s[o4*4]);
    float hh[4] = {u4.x+v4.x+cc.x, u4.y+v4.y+cc.y, u4.z+v4.z+cc.z, u4.w+v4.w+cc.w};
    #pragma unroll
    for (int oo = 0; oo < 4; ++oo) {
      int o = o4*4 + oo;
      float acc = hh[oo];
      #pragma unroll
      for (int j4 = 0; j4 < 8; ++j4) {
        float4 a = *reinterpret_cast<const float4*>(&As[o*32 + j4*4]);
        float4 b = *reinterpret_cast<const float4*>(&Bs[o*32 + j4*4]);
        float4 sfv = sf4[j4], hvv = hv4[j4];
        acc = fmaf(a.x,sfv.x, fmaf(a.y,sfv.y, fmaf(a.z,sfv.z, fmaf(a.w,sfv.w, acc))));
        acc = fmaf(b.x,hvv.x, fmaf(b.y,hvv.y, fmaf(b.z,hvv.z, fmaf(b.w,hvv.w, acc))));
      }
      float w2v = (oo==0) ? w2.x : (oo==1) ? w2.y : (oo==2) ? w2.z : w2.w;
      oacc = fmaf(w2v, fmaxf(acc, 0.f), oacc);
    }
  }
  out[e] = oacc;
}

extern "C" void kernel_launch(void* const* d_in, const int* in_sizes, int n_in,
                              void* d_out, int out_size, void* d_ws, size_t ws_size,
                              hipStream_t stream) {
  const int*   src   = (const int*)d_in[0];
  const int*   dst   = (const int*)d_in[1];
  const int*   t     = (const int*)d_in[2];
  const float* msg   = (const float*)d_in[3];
  const float* price = (const float*)d_in[4];
  const int*   xst   = (const int*)d_in[6];
  const float* memory= (const float*)d_in[7];
  const float* lu    = (const float*)d_in[8];
  const float* w_t   = (const float*)d_in[9];
  const float* b_t   = (const float*)d_in[10];
  const float* W_ih  = (const float*)d_in[11];
  const float* b_ih  = (const float*)d_in[12];
  const float* W_hh  = (const float*)d_in[13];
  const float* b_hh  = (const float*)d_in[14];
  const float* party = (const float*)d_in[15];
  const float* state = (const float*)d_in[16];
  const float* W_sp  = (const float*)d_in[17];
  const float* b_sp  = (const float*)d_in[18];
  const float* W_ihl = (const float*)d_in[19];
  const float* W_hhl = (const float*)d_in[20];
  const float* b_ihl = (const float*)d_in[21];
  const float* b_hhl = (const float*)d_in[22];
  const float* W_pp  = (const float*)d_in[23];
  const float* b_pp  = (const float*)d_in[24];
  const float* W1    = (const float*)d_in[25];
  const float* b1    = (const float*)d_in[26];
  const float* W2    = (const float*)d_in[27];
  const float* b2    = (const float*)d_in[28];
  float* out = (float*)d_out;

  if (ws_size < WS_NEED) {
    (void)hipMemsetAsync(d_out, 0, (size_t)out_size*4, stream);
    return;
  }

  char* ws = (char*)d_ws;
  u64*   key  = (u64*)(ws + OFF_KEY);
  int*   cnt  = (int*)(ws + OFF_CNT);
  int*   list = (int*)(ws + OFF_LIST);
  float* uv   = (float*)(ws + OFF_UV);
  float* hn   = (float*)(ws + OFF_HN);
  float* A    = (float*)(ws + OFF_A);
  float* B    = (float*)(ws + OFF_B);
  float* c0   = (float*)(ws + OFF_C0);
  short* Wbf  = (short*)(ws + OFF_WBF);

  (void)hipMemsetAsync(ws, 0, OFF_LIST, stream);
  k_scatter<<<(NE+255)/256, 256, 0, stream>>>(src, dst, t, key);
  k_compact<<<(NN+255)/256, 256, 0, stream>>>(key, list, cnt);
  k_pre<<<17, 256, 0, stream>>>(W1, W_sp, W_pp, b_sp, b_pp, b1, A, B, c0);
  k_prew<<<116, 256, 0, stream>>>(W_ih, W_hh, W1, Wbf);
  k_gl<<<LSTB*5, 512, 0, stream>>>(key, list, cnt, src, dst, t, msg, memory, lu,
                                   w_t, b_t, Wbf, b_ih, b_hh, uv,
                                   price, W_ihl, W_hhl, b_ihl, b_hhl, hn);
  k_final<<<(NE+255)/256, 256, 0, stream>>>(src, dst, xst, party, state, uv, hn,
                                            A, B, c0, W2, b2, out);
}

// Round 21
// 443.595 us; speedup vs baseline: 5.1863x; 1.0721x over previous
//
#include <hip/hip_runtime.h>
#include <stdint.h>

#define NN    200000
#define NE    100000
#define HD    128
#define EFD   64
#define NG    384

typedef unsigned long long u64;
typedef short bf16x8 __attribute__((ext_vector_type(8)));
typedef float f32x4  __attribute__((ext_vector_type(4)));

#define OFF_KEY   ((size_t)0)
#define OFF_CNT   ((size_t)1600000)
#define OFF_LIST  ((size_t)1600256)
#define OFF_UV    ((size_t)2400256)
#define OFF_HN    ((size_t)104800256)
#define OFF_A     ((size_t)117600256)
#define OFF_B     ((size_t)117608448)
#define OFF_C0    ((size_t)117616640)
#define OFF_WBF   ((size_t)117616896)
#define WS_NEED   ((size_t)118092032)

#define W1OFF 221184
#define GRUB  3128      // GRU virtual blocks (>= ceil(cnt/64) worst case 3125)
#define LSTB  782       // LSTM blocks (128 edges each)

__device__ __forceinline__ float frcp(float x){ return __builtin_amdgcn_rcpf(x); }
__device__ __forceinline__ float sigf(float x){ return frcp(1.f + __expf(-x)); }
__device__ __forceinline__ float tanhf_(float x){ return 1.f - 2.f*frcp(__expf(2.f*x) + 1.f); }
__device__ __forceinline__ float4 ld4(const float* p){ return *reinterpret_cast<const float4*>(p); }

__device__ __forceinline__ short f2bf(float f){
  unsigned u = __float_as_uint(f);
  u += 0x7fffu + ((u>>16)&1u);
  return (short)(u>>16);
}
__device__ __forceinline__ unsigned cvtpk(float lo, float hi){
  unsigned r;
  asm("v_cvt_pk_bf16_f32 %0, %1, %2" : "=v"(r) : "v"(lo), "v"(hi));
  return r;
}
__device__ __forceinline__ void gl16(const void* g, void* l) {
  __builtin_amdgcn_global_load_lds(
      (const __attribute__((address_space(1))) void*)g,
      (__attribute__((address_space(3))) void*)l, 16, 0, 0);
}

__global__ void k_scatter(const int* __restrict__ src, const int* __restrict__ dst,
                          const int* __restrict__ t, u64* __restrict__ key) {
  int e = blockIdx.x*256 + threadIdx.x;
  if (e >= NE) return;
  u64 tt = (u64)(unsigned)(t[e] + 1);
  atomicMax(&key[src[e]], (tt<<18) | (u64)(unsigned)e);
  atomicMax(&key[dst[e]], (tt<<18) | (1ULL<<17) | (u64)(unsigned)e);
}

__global__ void k_compact(const u64* __restrict__ key, int* __restrict__ list,
                          int* __restrict__ count) {
  int n = blockIdx.x*256 + threadIdx.x;
  if (n >= NN) return;
  if (key[n] != 0ULL) { int p = atomicAdd(count, 1); list[p] = n; }
}

__global__ void k_pre(const float* __restrict__ W1, const float* __restrict__ W_sp,
                      const float* __restrict__ W_pp, const float* __restrict__ b_sp,
                      const float* __restrict__ b_pp, const float* __restrict__ b1,
                      float* __restrict__ A, float* __restrict__ B, float* __restrict__ c0)
{
  int tid = blockIdx.x*256 + threadIdx.x;
  if (tid < 2048) {
    int o = tid >> 5, j = tid & 31;
    float s = 0.f;
    for (int k = 0; k < 128; ++k) s = fmaf(W1[o*NG + k], W_sp[k*32 + j], s);
    A[tid] = s;
  } else if (tid < 4096) {
    int q = tid - 2048;
    int o = q >> 5, j = q & 31;
    float s = 0.f;
    for (int k = 0; k < 128; ++k)
      s = fmaf(W1[o*NG + 128 + k] + W1[o*NG + 256 + k], W_pp[k*32 + j], s);
    B[q] = s;
  } else if (tid < 4160) {
    int o = tid - 4096;
    float s = b1[o];
    for (int k = 0; k < 128; ++k) {
      s = fmaf(W1[o*NG + k], b_sp[k], s);
      s = fmaf(W1[o*NG + 128 + k] + W1[o*NG + 256 + k], b_pp[k], s);
    }
    c0[o] = s;
  }
}

__global__ void k_prew(const float* __restrict__ W_ih, const float* __restrict__ W_hh,
                       const float* __restrict__ W1, short* __restrict__ Wbf)
{
  int idx = blockIdx.x*256 + threadIdx.x;
  if (idx < 9*384*8) {
    int s   = idx & 7;
    int n   = (idx >> 3) % 384;
    int ch9 = idx / (384*8);
    int k8  = s ^ (n & 7);
    int k   = ch9*64 + k8*8;
    short v[8];
    #pragma unroll
    for (int e = 0; e < 8; ++e) {
      int kk = k + e;
      float f = (kk < 448) ? W_ih[(size_t)n*448 + kk] : W_hh[(size_t)n*HD + (kk-448)];
      v[e] = f2bf(f);
    }
    *reinterpret_cast<bf16x8*>(Wbf + (size_t)ch9*24576 + n*64 + s*8) =
        *reinterpret_cast<bf16x8*>(v);
  } else if (idx < 9*384*8 + 128*16) {
    int idx2 = idx - 9*384*8;
    int s = idx2 & 15, r = idx2 >> 4;
    int k8 = s ^ (r & 15);
    int k = k8*8;
    short v[8];
    #pragma unroll
    for (int e = 0; e < 8; ++e) {
      int kk = k + e;
      float f = (r < 64) ? W1[(size_t)r*NG + kk] : W1[(size_t)(r-64)*NG + 128 + kk];
      v[e] = f2bf(f);
    }
    *reinterpret_cast<bf16x8*>(Wbf + W1OFF + r*128 + s*8) =
        *reinterpret_cast<bf16x8*>(v);
  }
}

// ---------- FUSED GRU + LSTM: 512 thr; longest-job-first: bid<LSTB -> LSTM ----------
__global__ __launch_bounds__(512, 2) void k_gl(
    const u64* __restrict__ key, const int* __restrict__ list, const int* __restrict__ count,
    const int* __restrict__ src, const int* __restrict__ dst, const int* __restrict__ t,
    const float* __restrict__ msg, const float* __restrict__ memory,
    const float* __restrict__ last_update,
    const float* __restrict__ w_t, const float* __restrict__ b_t,
    const short* __restrict__ Wbf, const float* __restrict__ b_ih,
    const float* __restrict__ b_hh, float* __restrict__ uv,
    const float* __restrict__ price, const float* __restrict__ W_ihl,
    const float* __restrict__ W_hhl, const float* __restrict__ b_ihl,
    const float* __restrict__ b_hhl, float* __restrict__ hn_out)
{
  __shared__ char lds[60416];    // arena, carved per role
  int bid = blockIdx.x;
  int tid = threadIdx.x;
  int wid = tid >> 6, lane = tid & 63;
  int lr = lane & 15, lk = lane >> 4;

  if (bid >= LSTB) {
    // ================= GRU role (virtual block g) =================
    int g = bid - LSTB;
    short* Wsb   = reinterpret_cast<short*>(lds);            // 48KB
    short* Xsb   = reinterpret_cast<short*>(lds + 49152);    // 8KB
    float* bias4 = reinterpret_cast<float*>(lds + 57344);    // 2KB
    int*   sn_self  = reinterpret_cast<int*>(lds + 59392);
    int*   sn_other = reinterpret_cast<int*>(lds + 59648);
    int*   sn_e     = reinterpret_cast<int*>(lds + 59904);
    float* sn_dt    = reinterpret_cast<float*>(lds + 60160);
    short* Mn2 = &Wsb[16384];

    int cnt = count[0];
    int base = g * 64;
    if (base >= cnt) return;

    if (tid < 64) {
      int idx = base + tid;
      int cl = idx < cnt ? idx : (cnt - 1);
      int n = list[cl];
      u64 k = key[n];
      int e   = (int)(k & 0x1FFFFULL);
      int isd = (int)((k >> 17) & 1ULL);
      sn_self[tid]  = n;
      sn_other[tid] = isd ? src[e] : dst[e];
      sn_e[tid]     = e;
      sn_dt[tid]    = (float)t[e] - last_update[n];
    }
    if (tid < 128) {
      int h = tid;
      bias4[h]       = b_ih[h]       + b_hh[h];
      bias4[128 + h] = b_ih[128 + h] + b_hh[128 + h];
      bias4[256 + h] = b_ih[256 + h];
      bias4[384 + h] = b_hh[256 + h];
    }
    __syncthreads();

    f32x4 aR[4], aZ[4], aNX[4], aNM[4];
    #pragma unroll
    for (int mt = 0; mt < 4; ++mt) { aR[mt] = (f32x4)0.f; aZ[mt] = (f32x4)0.f;
                                     aNX[mt] = (f32x4)0.f; aNM[mt] = (f32x4)0.f; }

    int node8 = tid >> 3, k8s = tid & 7;

    float4 xA0, xB0, xA1, xB1, xA2, xB2, xA3, xB3, xA4, xB4;
    {
      const float* pSelf  = memory + (size_t)sn_self[node8]*HD  + k8s*8;
      const float* pOther = memory + (size_t)sn_other[node8]*HD + k8s*8;
      const float* pMsg   = msg + (size_t)sn_e[node8]*EFD + k8s*8;
      xA0 = ld4(pSelf);       xB0 = ld4(pSelf+4);
      xA1 = ld4(pSelf+64);    xB1 = ld4(pSelf+68);
      xA2 = ld4(pOther);      xB2 = ld4(pOther+4);
      xA3 = ld4(pOther+64);   xB3 = ld4(pOther+68);
      xA4 = ld4(pMsg);        xB4 = ld4(pMsg+4);
    }

    constexpr int WCH[9] = {0, 7, 1, 8, 2, 3, 4, 5, 6};
    constexpr int XST[9] = {0,-1, 1,-1, 2, 3, 4,-2,-2};

    int hrow = wid*16 + lr;
    int swzH = (hrow & 7);

    #pragma unroll
    for (int p = 0; p < 9; ++p) {
      const int W = WCH[p];
      #pragma unroll
      for (int i = 0; i < 6; ++i) {
        int q = i*512 + tid;
        gl16(Wbf + (size_t)W*24576 + q*8, &Wsb[q*8]);
      }
      if (XST[p] >= 0) {
        float4 fa, fb;
        switch (XST[p]) {
          case 0: fa = xA0; fb = xB0; break;
          case 1: fa = xA1; fb = xB1; break;
          case 2: fa = xA2; fb = xB2; break;
          case 3: fa = xA3; fb = xB3; break;
          default: fa = xA4; fb = xB4; break;
        }
        short xs[8];
        xs[0]=f2bf(fa.x); xs[1]=f2bf(fa.y); xs[2]=f2bf(fa.z); xs[3]=f2bf(fa.w);
        xs[4]=f2bf(fb.x); xs[5]=f2bf(fb.y); xs[6]=f2bf(fb.z); xs[7]=f2bf(fb.w);
        *reinterpret_cast<bf16x8*>(&Xsb[node8*64 + ((k8s ^ (node8&7))<<3)]) =
            *reinterpret_cast<bf16x8*>(xs);
      } else if (XST[p] == -2) {
        int kk = (W == 6 ? 64 : 0) + k8s*8;
        float dt = sn_dt[node8];
        short xs[8];
        #pragma unroll
        for (int q = 0; q < 8; ++q) xs[q] = f2bf(cosf(fmaf(dt, w_t[kk+q], b_t[kk+q])));
        *reinterpret_cast<bf16x8*>(&Xsb[node8*64 + ((k8s ^ (node8&7))<<3)]) =
            *reinterpret_cast<bf16x8*>(xs);
      }
      __syncthreads();

      #pragma unroll
      for (int ks = 0; ks < 2; ++ks) {
        int k8 = ks*4 + lk;
        int so = (k8 ^ swzH) << 3;
        bf16x8 bR = *reinterpret_cast<const bf16x8*>(&Wsb[(size_t)hrow*64 + so]);
        bf16x8 bZ = *reinterpret_cast<const bf16x8*>(&Wsb[(size_t)(128+hrow)*64 + so]);
        bf16x8 bN = *reinterpret_cast<const bf16x8*>(&Wsb[(size_t)(256+hrow)*64 + so]);
        #pragma unroll
        for (int mt = 0; mt < 4; ++mt) {
          int anode = mt*16 + lr;
          bf16x8 a = *reinterpret_cast<const bf16x8*>(&Xsb[anode*64 + ((k8 ^ (anode&7))<<3)]);
          aR[mt] = __builtin_amdgcn_mfma_f32_16x16x32_bf16(a, bR, aR[mt], 0, 0, 0);
          aZ[mt] = __builtin_amdgcn_mfma_f32_16x16x32_bf16(a, bZ, aZ[mt], 0, 0, 0);
          if (W < 7) aNX[mt] = __builtin_amdgcn_mfma_f32_16x16x32_bf16(a, bN, aNX[mt], 0, 0, 0);
          else       aNM[mt] = __builtin_amdgcn_mfma_f32_16x16x32_bf16(a, bN, aNM[mt], 0, 0, 0);
        }
      }
      __syncthreads();
    }

    #pragma unroll
    for (int i = 0; i < 4; ++i) {
      int q = i*512 + tid;
      gl16(Wbf + W1OFF + q*8, &Wsb[q*8]);
    }

    {
      int h = hrow;
      int k8h = h >> 3, eh = h & 7;
      float br_ = bias4[h], bz_ = bias4[128+h], bnx_ = bias4[256+h], bnm_ = bias4[384+h];
      #pragma unroll
      for (int mt = 0; mt < 4; ++mt) {
        #pragma unroll
        for (int i = 0; i < 4; ++i) {
          int node = mt*16 + lk*4 + i;
          float r  = sigf(aR[mt][i] + br_);
          float z  = sigf(aZ[mt][i] + bz_);
          float nv = tanhf_(aNX[mt][i] + bnx_ + r*(aNM[mt][i] + bnm_));
          float m  = memory[(size_t)sn_self[node]*HD + h];
          Mn2[node*128 + ((k8h ^ (node&15))<<3) + eh] = f2bf((1.f - z)*nv + z*m);
        }
      }
    }
    __syncthreads();

    {
      int orow = wid*16 + lr;
      f32x4 acc2[4];
      #pragma unroll
      for (int mt = 0; mt < 4; ++mt) acc2[mt] = (f32x4)0.f;
      #pragma unroll
      for (int kf = 0; kf < 4; ++kf) {
        int k8 = kf*4 + lk;
        bf16x8 b = *reinterpret_cast<const bf16x8*>(&Wsb[orow*128 + ((k8 ^ (orow&15))<<3)]);
        #pragma unroll
        for (int mt = 0; mt < 4; ++mt) {
          int anode = mt*16 + lr;
          bf16x8 a = *reinterpret_cast<const bf16x8*>(&Mn2[anode*128 + ((k8 ^ (anode&15))<<3)]);
          acc2[mt] = __builtin_amdgcn_mfma_f32_16x16x32_bf16(a, b, acc2[mt], 0, 0, 0);
        }
      }
      #pragma unroll
      for (int mt = 0; mt < 4; ++mt) {
        #pragma unroll
        for (int i = 0; i < 4; ++i) {
          int node = mt*16 + lk*4 + i;
          if (base + node < cnt)
            uv[(size_t)sn_self[node]*128 + orow] = acc2[mt][i];
        }
      }
    }
  } else {
    // ================= LSTM role (block l = bid, 128 edges, 8 waves) =================
    int l = bid;
    short* Wb   = reinterpret_cast<short*>(lds);             // 8KB
    float* ps   = reinterpret_cast<float*>(lds + 8192);      // 25.6KB
    float* hbuf = reinterpret_cast<float*>(lds + 33792);     // 18.4KB (8 x 576)

    {
      int base = tid * 8;
      #pragma unroll
      for (int q = 0; q < 4; ++q) {
        unsigned pk = cvtpk(W_hhl[base + q*2], W_hhl[base + q*2 + 1]);
        reinterpret_cast<unsigned*>(Wb)[tid*4 + q] = pk;
      }
    }
    int ebase = l * 128;
    int m = NE - ebase; if (m > 128) m = 128;
    for (int i = tid; i < 128*50; i += 512) {
      int r = i / 50, cidx = i % 50;
      int rr = r < m ? r : m - 1;
      ps[i] = price[(size_t)(ebase + rr)*50 + cidx];
    }
    __syncthreads();

    bf16x8 bw[8];
    float wih8[8], bias8[8];
    #pragma unroll
    for (int tI = 0; tI < 8; ++tI) {
      int row = tI*16 + lr;
      bw[tI] = *reinterpret_cast<const bf16x8*>(&Wb[row*32 + lk*8]);
      wih8[tI] = W_ihl[row];
      bias8[tI] = b_ihl[row] + b_hhl[row];
    }

    int we = wid * 16;
    float* hb = hbuf + wid*576;

    float c8[4][2];
    #pragma unroll
    for (int i = 0; i < 4; ++i) { c8[i][0] = 0.f; c8[i][1] = 0.f; }
    bf16x8 afrag = {0,0,0,0,0,0,0,0};

    #pragma unroll 1
    for (int s = 0; s < 50; ++s) {
      float xv[4];
      #pragma unroll
      for (int i = 0; i < 4; ++i) xv[i] = ps[(we + lk*4 + i)*50 + s];
      f32x4 acc[8];
      #pragma unroll
      for (int tI = 0; tI < 8; ++tI) {
        f32x4 ci;
        #pragma unroll
        for (int i = 0; i < 4; ++i) ci[i] = fmaf(xv[i], wih8[tI], bias8[tI]);
        acc[tI] = __builtin_amdgcn_mfma_f32_16x16x32_bf16(afrag, bw[tI], ci, 0, 0, 0);
      }
      #pragma unroll
      for (int i = 0; i < 4; ++i) {
        #pragma unroll
        for (int p = 0; p < 2; ++p) {
          float ei = __expf(-acc[0+p][i]);
          float ef = __expf(-acc[2+p][i]);
          float eg = __expf(2.f*acc[4+p][i]);
          float eo = __expf(-acc[6+p][i]);
          float di = 1.f + ei, df_ = 1.f + ef, dg = eg + 1.f, do_ = 1.f + eo;
          float m1 = di*df_, m2 = do_*dg;
          float R  = frcp(m1*m2);
          float ig = R*df_*m2;
          float fg = R*di*m2;
          float og = R*m1*dg;
          float gg = fmaf(-2.f, R*m1*do_, 1.f);
          c8[i][p] = fmaf(fg, c8[i][p], ig*gg);
          float th = 1.f - 2.f*frcp(__expf(2.f*c8[i][p]) + 1.f);
          hb[(lk*4 + i)*36 + p*16 + lr] = og*th;
        }
      }
      asm volatile("s_waitcnt lgkmcnt(0)" ::: "memory");
      float4 h0 = *reinterpret_cast<const float4*>(&hb[lr*36 + lk*8]);
      float4 h1 = *reinterpret_cast<const float4*>(&hb[lr*36 + lk*8 + 4]);
      unsigned pk_[4];
      pk_[0] = cvtpk(h0.x, h0.y);
      pk_[1] = cvtpk(h0.z, h0.w);
      pk_[2] = cvtpk(h1.x, h1.y);
      pk_[3] = cvtpk(h1.z, h1.w);
      afrag = *reinterpret_cast<bf16x8*>(pk_);
    }

    int e_g = ebase + we + lr;
    if (e_g < NE) {
      float4 h0 = *reinterpret_cast<const float4*>(&hb[lr*36 + lk*8]);
      float4 h1 = *reinterpret_cast<const float4*>(&hb[lr*36 + lk*8 + 4]);
      *reinterpret_cast<float4*>(hn_out + (size_t)e_g*32 + lk*8)     = h0;
      *reinterpret_cast<float4*>(hn_out + (size_t)e_g*32 + lk*8 + 4) = h1;
    }
  }
}

// ---------- fused output ----------
__global__ __launch_bounds__(256) void k_final(
    const int* __restrict__ src, const int* __restrict__ dst, const int* __restrict__ xst,
    const float* __restrict__ party, const float* __restrict__ state,
    const float* __restrict__ uv, const float* __restrict__ hn,
    const float* __restrict__ A, const float* __restrict__ B, const float* __restrict__ c0,
    const float* __restrict__ W2, const float* __restrict__ b2, float* __restrict__ out)
{
  __shared__ float As[2048], Bs[2048], c0s[64], W2s[64];
  int tid = threadIdx.x;
  for (int i = tid; i < 2048; i += 256) { As[i] = A[i]; Bs[i] = B[i]; }
  if (tid < 64) { c0s[tid] = c0[tid]; W2s[tid] = W2[tid]; }
  __syncthreads();
  int e = blockIdx.x*256 + tid;
  if (e >= NE) return;
  int s = src[e], d = dst[e];
  int p = xst[2*s], stt = xst[2*s + 1];
  float4 sf4[8], hv4[8];
  #pragma unroll
  for (int i = 0; i < 4; ++i) sf4[i]   = ld4(party + p*16 + i*4);
  #pragma unroll
  for (int i = 0; i < 4; ++i) sf4[4+i] = ld4(state + stt*16 + i*4);
  #pragma unroll
  for (int i = 0; i < 8; ++i) hv4[i] = ld4(hn + (size_t)e*32 + i*4);
  const float* urow = uv + (size_t)s*128;
  const float* vrow = uv + (size_t)d*128 + 64;
  float oacc = b2[0];
  #pragma unroll 4
  for (int o4 = 0; o4 < 16; ++o4) {
    float4 u4 = ld4(urow + o4*4);
    float4 v4 = ld4(vrow + o4*4);
    float4 cc = *reinterpret_cast<const float4*>(&c0s[o4*4]);
    float4 w2 = *reinterpret_cast<const float4*>(&W2s[o4*4]);
    float hh[4] = {u4.x+v4.x+cc.x, u4.y+v4.y+cc.y, u4.z+v4.z+cc.z, u4.w+v4.w+cc.w};
    #pragma unroll
    for (int oo = 0; oo < 4; ++oo) {
      int o = o4*4 + oo;
      float acc = hh[oo];
      #pragma unroll
      for (int j4 = 0; j4 < 8; ++j4) {
        float4 a = *reinterpret_cast<const float4*>(&As[o*32 + j4*4]);
        float4 b = *reinterpret_cast<const float4*>(&Bs[o*32 + j4*4]);
        float4 sfv = sf4[j4], hvv = hv4[j4];
        acc = fmaf(a.x,sfv.x, fmaf(a.y,sfv.y, fmaf(a.z,sfv.z, fmaf(a.w,sfv.w, acc))));
        acc = fmaf(b.x,hvv.x, fmaf(b.y,hvv.y, fmaf(b.z,hvv.z, fmaf(b.w,hvv.w, acc))));
      }
      float w2v = (oo==0) ? w2.x : (oo==1) ? w2.y : (oo==2) ? w2.z : w2.w;
      oacc = fmaf(w2v, fmaxf(acc, 0.f), oacc);
    }
  }
  out[e] = oacc;
}

extern "C" void kernel_launch(void* const* d_in, const int* in_sizes, int n_in,
                              void* d_out, int out_size, void* d_ws, size_t ws_size,
                              hipStream_t stream) {
  const int*   src   = (const int*)d_in[0];
  const int*   dst   = (const int*)d_in[1];
  const int*   t     = (const int*)d_in[2];
  const float* msg   = (const float*)d_in[3];
  const float* price = (const float*)d_in[4];
  const int*   xst   = (const int*)d_in[6];
  const float* memory= (const float*)d_in[7];
  const float* lu    = (const float*)d_in[8];
  const float* w_t   = (const float*)d_in[9];
  const float* b_t   = (const float*)d_in[10];
  const float* W_ih  = (const float*)d_in[11];
  const float* b_ih  = (const float*)d_in[12];
  const float* W_hh  = (const float*)d_in[13];
  const float* b_hh  = (const float*)d_in[14];
  const float* party = (const float*)d_in[15];
  const float* state = (const float*)d_in[16];
  const float* W_sp  = (const float*)d_in[17];
  const float* b_sp  = (const float*)d_in[18];
  const float* W_ihl = (const float*)d_in[19];
  const float* W_hhl = (const float*)d_in[20];
  const float* b_ihl = (const float*)d_in[21];
  const float* b_hhl = (const float*)d_in[22];
  const float* W_pp  = (const float*)d_in[23];
  const float* b_pp  = (const float*)d_in[24];
  const float* W1    = (const float*)d_in[25];
  const float* b1    = (const float*)d_in[26];
  const float* W2    = (const float*)d_in[27];
  const float* b2    = (const float*)d_in[28];
  float* out = (float*)d_out;

  if (ws_size < WS_NEED) {
    (void)hipMemsetAsync(d_out, 0, (size_t)out_size*4, stream);
    return;
  }

  char* ws = (char*)d_ws;
  u64*   key  = (u64*)(ws + OFF_KEY);
  int*   cnt  = (int*)(ws + OFF_CNT);
  int*   list = (int*)(ws + OFF_LIST);
  float* uv   = (float*)(ws + OFF_UV);
  float* hn   = (float*)(ws + OFF_HN);
  float* A    = (float*)(ws + OFF_A);
  float* B    = (float*)(ws + OFF_B);
  float* c0   = (float*)(ws + OFF_C0);
  short* Wbf  = (short*)(ws + OFF_WBF);

  (void)hipMemsetAsync(ws, 0, OFF_LIST, stream);
  k_scatter<<<(NE+255)/256, 256, 0, stream>>>(src, dst, t, key);
  k_compact<<<(NN+255)/256, 256, 0, stream>>>(key, list, cnt);
  k_pre<<<17, 256, 0, stream>>>(W1, W_sp, W_pp, b_sp, b_pp, b1, A, B, c0);
  k_prew<<<116, 256, 0, stream>>>(W_ih, W_hh, W1, Wbf);
  k_gl<<<LSTB + GRUB, 512, 0, stream>>>(key, list, cnt, src, dst, t, msg, memory, lu,
                                        w_t, b_t, Wbf, b_ih, b_hh, uv,
                                        price, W_ihl, W_hhl, b_ihl, b_hhl, hn);
  k_final<<<(NE+255)/256, 256, 0, stream>>>(src, dst, xst, party, state, uv, hn,
                                            A, B, c0, W2, b2, out);
}